// Round 2
// baseline (606.588 us; speedup 1.0000x reference)
//
#include <hip/hip_runtime.h>
#include <math.h>

#define NB 2      // batch
#define NN 128    // points
#define NO 12     // orientations
#define NIN 16
#define NH 128
#define NBD 32
#define NL 2
#define NHH 512   // WF*H

typedef __attribute__((ext_vector_type(8))) short bf16x8;
typedef __attribute__((ext_vector_type(4))) float f32x4;

__device__ __forceinline__ float gelu_f(float x){
    float u = 0.7978845608028654f * (x + 0.044715f * x * x * x);
    float t = 1.0f - 2.0f / (__expf(2.0f * u) + 1.0f);   // tanh(u)
    return 0.5f * x * (1.0f + t);
}

__device__ __forceinline__ ushort f2b(float x){
    union { float f; uint u; } v; v.f = x;
    uint r = v.u + 0x7FFF + ((v.u >> 16) & 1);
    return (ushort)(r >> 16);
}

// ---------------------------------------------------------------------------
// k_setup: ori (12x3) + fiber_basis (12x12x32), one block
// ---------------------------------------------------------------------------
__global__ __launch_bounds__(256) void k_setup(const float* __restrict__ W1r,
        const float* __restrict__ b1r, const float* __restrict__ W2r,
        const float* __restrict__ b2r, float* __restrict__ ws_ori,
        float* __restrict__ ws_fiber){
    __shared__ float sori[NO*3];
    __shared__ float shid[NO*NO*NH];
    int tid = threadIdx.x;
    if (tid < NO){
        float fi = (float)tid;
        float th = fmodf(3.14159265358979323846f * fi * 3.23606797749979f,
                         6.28318530717958647692f);
        float ph = acosf(1.0f - 2.0f*(fi + 0.5f)/12.0f);
        float sp = sinf(ph);
        float ox = sp*cosf(th), oy = sp*sinf(th), oz = cosf(ph);
        sori[tid*3+0]=ox; sori[tid*3+1]=oy; sori[tid*3+2]=oz;
        ws_ori[tid*3+0]=ox; ws_ori[tid*3+1]=oy; ws_ori[tid*3+2]=oz;
    }
    __syncthreads();
    for (int e = tid; e < NO*NO*NH; e += 256){
        int t = e & 127, row = e >> 7;
        int p = row / NO, q = row - p*NO;
        float xv = sori[p*3]*sori[q*3] + sori[p*3+1]*sori[q*3+1] + sori[p*3+2]*sori[q*3+2];
        float acc = b1r[t] + xv*W1r[t] + xv*xv*W1r[NH+t] + xv*xv*xv*W1r[2*NH+t];
        shid[e] = gelu_f(acc);
    }
    __syncthreads();
    for (int e = tid; e < NO*NO*NBD; e += 256){
        int d = e & 31, row = e >> 5;
        float acc = b2r[d];
        const float* hr = shid + row*NH;
        for (int t = 0; t < NH; ++t) acc += hr[t]*W2r[t*NBD + d];
        ws_fiber[e] = gelu_f(acc);
    }
}

// ---------------------------------------------------------------------------
// k_rot: rot[i][p][o][c] = sum_d fiber[p][o][d] * Wrot[i][d][c]
// ---------------------------------------------------------------------------
__global__ __launch_bounds__(256) void k_rot(const float* __restrict__ fiber,
        const float* __restrict__ Wrot, float* __restrict__ rot){
    int g = blockIdx.x*256 + threadIdx.x;
    int c = g & 127; int rest = g >> 7;
    int o = rest % NO; rest /= NO;
    int p = rest % NO; int i = rest / NO;
    const float* f = fiber + (p*NO + o)*NBD;
    const float* w = Wrot + (size_t)i*NBD*NH + c;
    float acc = 0.f;
    #pragma unroll
    for (int d = 0; d < NBD; ++d) acc += f[d]*w[d*NH];
    rot[g] = acc;
}

// ---------------------------------------------------------------------------
// k_embed: hA[b][o][n][c] = sum_k x[b,n,k]*We[k,c]   (broadcast over o)
// ---------------------------------------------------------------------------
__global__ __launch_bounds__(256) void k_embed(const float* __restrict__ x,
        const float* __restrict__ We, float* __restrict__ hA){
    int g = blockIdx.x*256 + threadIdx.x;
    int c = g & 127; int n = (g >> 7) & 127; int rest = g >> 14;
    int b = rest / NO;
    const float* xp = x + ((size_t)b*NN + n)*NIN;
    float acc = 0.f;
    #pragma unroll
    for (int k = 0; k < NIN; ++k) acc += xp[k]*We[k*NH + c];
    hA[g] = acc;
}

// ---------------------------------------------------------------------------
// k_kb: kernel_basis[b][o][m][n][d] -> bf16, 64 n-rows per block
// ---------------------------------------------------------------------------
__global__ __launch_bounds__(256) void k_kb(const float* __restrict__ pos,
        const float* __restrict__ W1s, const float* __restrict__ b1s,
        const float* __restrict__ W2s, const float* __restrict__ b2s,
        const float* __restrict__ ori, ushort* __restrict__ kb){
    __shared__ __align__(16) float sW1[14*NH];
    __shared__ float sb1[NH];
    __shared__ __align__(16) float sW2[NH*NBD];
    __shared__ float sb2[NBD];
    __shared__ float spf[64*14];
    __shared__ __align__(16) float shid[64*132];
    int tid = threadIdx.x;
    int bid = blockIdx.x;                 // 6144 = NB*NO*NN*2
    int n0 = (bid & 1)*64;
    int m  = (bid >> 1) & 127;
    int t2 = bid >> 8;
    int o = t2 % NO, b = t2 / NO;

    for (int e = tid; e < 14*NH;  e += 256) sW1[e] = W1s[e];
    for (int e = tid; e < NH*NBD; e += 256) sW2[e] = W2s[e];
    if (tid < NH)  sb1[tid] = b1s[tid];
    if (tid < NBD) sb2[tid] = b2s[tid];
    if (tid < 64){
        int n = n0 + tid;
        float rx = pos[((size_t)b*NN+n)*3+0] - pos[((size_t)b*NN+m)*3+0];
        float ry = pos[((size_t)b*NN+n)*3+1] - pos[((size_t)b*NN+m)*3+1];
        float rz = pos[((size_t)b*NN+n)*3+2] - pos[((size_t)b*NN+m)*3+2];
        float ox = ori[o*3+0], oy = ori[o*3+1], oz = ori[o*3+2];
        float a  = rx*ox + ry*oy + rz*oz;
        float bb = sqrtf(rx*rx+ry*ry+rz*rz) * fabsf(1.0f - a);
        float* p = spf + tid*14;
        p[0]=a;      p[1]=bb;
        p[2]=a*a;    p[3]=a*bb;    p[4]=bb*a;    p[5]=bb*bb;
        p[6]=a*a*a;  p[7]=a*a*bb;  p[8]=a*bb*a;  p[9]=a*bb*bb;
        p[10]=bb*a*a; p[11]=bb*a*bb; p[12]=bb*bb*a; p[13]=bb*bb*bb;
    }
    __syncthreads();
    for (int it = 0; it < 32; ++it){
        int e = it*256 + tid;
        int t = e & 127, r = e >> 7;
        const float* pf = spf + r*14;
        float acc = sb1[t];
        #pragma unroll
        for (int k = 0; k < 14; ++k) acc += pf[k]*sW1[k*NH + t];
        shid[r*132 + t] = gelu_f(acc);
    }
    __syncthreads();
    int dg = tid & 7, rr = tid >> 3;
    int r0 = rr*2, d0 = dg*4;
    float4 a0, a1;
    a0.x = a1.x = sb2[d0+0]; a0.y = a1.y = sb2[d0+1];
    a0.z = a1.z = sb2[d0+2]; a0.w = a1.w = sb2[d0+3];
    for (int t4 = 0; t4 < NH; t4 += 4){
        float4 h0 = *(const float4*)&shid[ r0     *132 + t4];
        float4 h1 = *(const float4*)&shid[(r0+1)*132 + t4];
        float4 w0 = *(const float4*)&sW2[(t4+0)*NBD + d0];
        float4 w1 = *(const float4*)&sW2[(t4+1)*NBD + d0];
        float4 w2 = *(const float4*)&sW2[(t4+2)*NBD + d0];
        float4 w3 = *(const float4*)&sW2[(t4+3)*NBD + d0];
        a0.x += h0.x*w0.x + h0.y*w1.x + h0.z*w2.x + h0.w*w3.x;
        a0.y += h0.x*w0.y + h0.y*w1.y + h0.z*w2.y + h0.w*w3.y;
        a0.z += h0.x*w0.z + h0.y*w1.z + h0.z*w2.z + h0.w*w3.z;
        a0.w += h0.x*w0.w + h0.y*w1.w + h0.z*w2.w + h0.w*w3.w;
        a1.x += h1.x*w0.x + h1.y*w1.x + h1.z*w2.x + h1.w*w3.x;
        a1.y += h1.x*w0.y + h1.y*w1.y + h1.z*w2.y + h1.w*w3.y;
        a1.z += h1.x*w0.z + h1.y*w1.z + h1.z*w2.z + h1.w*w3.z;
        a1.w += h1.x*w0.w + h1.y*w1.w + h1.z*w2.w + h1.w*w3.w;
    }
    size_t base = (((size_t)(b*NO + o)*NN + m)*NN + n0)*NBD;
    uint2 p0, p1;
    p0.x = (uint)f2b(gelu_f(a0.x)) | ((uint)f2b(gelu_f(a0.y)) << 16);
    p0.y = (uint)f2b(gelu_f(a0.z)) | ((uint)f2b(gelu_f(a0.w)) << 16);
    p1.x = (uint)f2b(gelu_f(a1.x)) | ((uint)f2b(gelu_f(a1.y)) << 16);
    p1.y = (uint)f2b(gelu_f(a1.z)) | ((uint)f2b(gelu_f(a1.w)) << 16);
    *(uint2*)&kb[base + (size_t)r0*NBD + d0]     = p0;
    *(uint2*)&kb[base + (size_t)(r0+1)*NBD + d0] = p1;
}

// ---------------------------------------------------------------------------
// k_convm: MFMA conv.  Per (b,o):  out[m,c] = sum_{k=n*32+d} A[m,k]*W[k,c]
//   A[m,k] = kb[b,o,m,n,d] (bf16),  W[k,c] = hIn[b,o,n,c]*mask[b,n]*Wsp[d,c]
// block = (b, o, m-half): M=64, N=128, K=4096 in chunks of 128 (4 n-rows).
// 4 waves as 2x2; per wave 32x64 output = 2x4 16x16 tiles.
// ---------------------------------------------------------------------------
__global__ __launch_bounds__(256) void k_convm(const float* __restrict__ hIn,
        const ushort* __restrict__ kb, const float* __restrict__ wsp_i,
        const float* __restrict__ mask, float* __restrict__ hOut){
    __shared__ __align__(16) ushort sA[64*128];    // swizzled A tile, 16KB
    __shared__ __align__(16) ushort sW[128*128];   // swizzled Wt[c][k], 32KB
    __shared__ float sg[4*NH];                     // g rows for chunk, 2KB

    int tid = threadIdx.x;
    int bid = blockIdx.x;            // 48 = NB*NO*2
    int mh = bid & 1;
    int o  = (bid >> 1) % NO;
    int b  = bid / (2*NO);

    int w = tid >> 6, lane = tid & 63;
    int lr = lane & 15, lg = lane >> 4;
    int wm = (w >> 1)*32, wc = (w & 1)*64;

    // per-thread Wsp column cache: c_w = column this thread builds W for
    int c_w = w*32 + (lane & 31);
    int khalf = lane >> 5;                  // which K-half of the chunk
    float wv[NBD];
    #pragma unroll
    for (int d = 0; d < NBD; ++d) wv[d] = wsp_i[d*NH + c_w];

    f32x4 acc[2][4];
    #pragma unroll
    for (int i = 0; i < 2; ++i)
        #pragma unroll
        for (int j = 0; j < 4; ++j)
            acc[i][j] = (f32x4){0.f,0.f,0.f,0.f};

    const float* mbase = mask + b*NN;
    const float* hbase = hIn + ((size_t)(b*NO + o)*NN)*NH;
    const ushort* abase = kb + (((size_t)(b*NO + o)*NN + mh*64)*NN)*NBD;

    for (int ch = 0; ch < 32; ++ch){
        // ---- stage g: 4 rows x 128 (float2 per thread)
        {
            int n = tid >> 6, c0 = (tid & 63)*2;
            float mk = mbase[ch*4 + n];
            float2 hv = *(const float2*)&hbase[(size_t)(ch*4 + n)*NH + c0];
            sg[n*NH + c0]     = hv.x*mk;
            sg[n*NH + c0 + 1] = hv.y*mk;
        }
        // ---- stage A tile: 64 rows x 128 k (bf16), swizzled
        #pragma unroll
        for (int r = 0; r < 4; ++r){
            int flat = r*256 + tid;
            int ml = flat >> 4, seg = flat & 15;
            uint4 v = *(const uint4*)(abase + (size_t)ml*4096 + ch*128 + seg*8);
            *(uint4*)((char*)sA + ml*256 + ((seg*16) ^ ((ml & 7) << 4))) = v;
        }
        __syncthreads();
        // ---- build Wt[c][k] for this chunk (after barrier so sg is ready)
        // NOTE: sg written above, also need barrier before reading sg -> the
        // barrier above covers it; but sW writes race with MFMA reads of the
        // PREVIOUS chunk -- the barrier above also covers that.
        {
            #pragma unroll
            for (int jj = 0; jj < 4; ++jj){
                int k0 = khalf*64 + jj*16;
                int nn = k0 >> 5;
                const int d0 = (jj & 1)*16;
                float gv = sg[nn*NH + c_w];
                #pragma unroll
                for (int t = 0; t < 2; ++t){
                    uint4 pk;
                    uint r0 = (uint)f2b(gv*wv[d0 + t*8 + 0]) | ((uint)f2b(gv*wv[d0 + t*8 + 1]) << 16);
                    uint r1 = (uint)f2b(gv*wv[d0 + t*8 + 2]) | ((uint)f2b(gv*wv[d0 + t*8 + 3]) << 16);
                    uint r2 = (uint)f2b(gv*wv[d0 + t*8 + 4]) | ((uint)f2b(gv*wv[d0 + t*8 + 5]) << 16);
                    uint r3 = (uint)f2b(gv*wv[d0 + t*8 + 6]) | ((uint)f2b(gv*wv[d0 + t*8 + 7]) << 16);
                    pk.x = r0; pk.y = r1; pk.z = r2; pk.w = r3;
                    int kbyte = (k0 + t*8)*2;
                    *(uint4*)((char*)sW + c_w*256 + (kbyte ^ ((c_w & 7) << 4))) = pk;
                }
            }
        }
        __syncthreads();
        // ---- MFMA over the chunk: 4 k-steps of 32
        #pragma unroll
        for (int kk = 0; kk < 4; ++kk){
            int kbyte = (kk*32 + lg*8)*2;
            bf16x8 a0 = *(const bf16x8*)((const char*)sA + (wm + lr)*256      + (kbyte ^ ((lr & 7) << 4)));
            bf16x8 a1 = *(const bf16x8*)((const char*)sA + (wm + 16 + lr)*256 + (kbyte ^ ((lr & 7) << 4)));
            bf16x8 bf[4];
            #pragma unroll
            for (int j = 0; j < 4; ++j){
                int c = wc + j*16 + lr;
                bf[j] = *(const bf16x8*)((const char*)sW + c*256 + (kbyte ^ ((c & 7) << 4)));
            }
            #pragma unroll
            for (int j = 0; j < 4; ++j){
                acc[0][j] = __builtin_amdgcn_mfma_f32_16x16x32_bf16(a0, bf[j], acc[0][j], 0, 0, 0);
                acc[1][j] = __builtin_amdgcn_mfma_f32_16x16x32_bf16(a1, bf[j], acc[1][j], 0, 0, 0);
            }
        }
        __syncthreads();
    }
    // ---- epilogue: D lane mapping row=(lane>>4)*4+reg, col=lane&15
    float* obase = hOut + (((size_t)(b*NO + o)*NN) + mh*64)*NH;
    #pragma unroll
    for (int i = 0; i < 2; ++i)
        #pragma unroll
        for (int j = 0; j < 4; ++j)
            #pragma unroll
            for (int r = 0; r < 4; ++r){
                int m = wm + i*16 + lg*4 + r;
                int c = wc + j*16 + lr;
                obase[(size_t)m*NH + c] = acc[i][j][r];
            }
}

// ---------------------------------------------------------------------------
// k_mlp: rot-mix + conv bias + LN + MLP(128->512->128) + residual. block=(b,m)
// ---------------------------------------------------------------------------
__global__ __launch_bounds__(512) void k_mlp(const float* __restrict__ hConv,
        const float* __restrict__ hIn, float* __restrict__ hOut,
        const float* __restrict__ rot_i, const float* __restrict__ convb_i,
        const float* __restrict__ lns_i, const float* __restrict__ lnb_i,
        const float* __restrict__ Wl1_i, const float* __restrict__ bl1_i,
        const float* __restrict__ Wl2_i, const float* __restrict__ bl2_i){
    __shared__ float shcv[NO*NH];
    __shared__ float sy[NO*NH];
    __shared__ float sU[NO*NHH];
    __shared__ float sred[4*NO*NH];
    int tid = threadIdx.x;
    int bid = blockIdx.x;
    int m = bid & 127, b = bid >> 7;
    for (int e = tid; e < NO*NH; e += 512){
        int o = e >> 7, c = e & 127;
        shcv[e] = hConv[(((size_t)b*NO + o)*NN + m)*NH + c];
    }
    __syncthreads();
    for (int e = tid; e < NO*NH; e += 512){
        int p = e >> 7, c = e & 127;
        float acc = 0.f;
        #pragma unroll
        for (int o = 0; o < NO; ++o)
            acc += shcv[o*NH + c]*rot_i[(p*NO + o)*NH + c];
        sy[e] = acc*(1.0f/12.0f) + convb_i[c];
    }
    __syncthreads();
    int wid = tid >> 6, lane = tid & 63;
    for (int row = wid; row < NO; row += 8){
        float x0 = sy[row*NH + lane], x1 = sy[row*NH + 64 + lane];
        float s = x0 + x1, ss = x0*x0 + x1*x1;
        for (int off = 32; off; off >>= 1){
            s  += __shfl_xor(s,  off);
            ss += __shfl_xor(ss, off);
        }
        float mn  = s*(1.0f/128.0f);
        float var = ss*(1.0f/128.0f) - mn*mn;
        float r = rsqrtf(var + 1e-6f);
        sy[row*NH + lane]      = (x0 - mn)*r*lns_i[lane]      + lnb_i[lane];
        sy[row*NH + 64 + lane] = (x1 - mn)*r*lns_i[64 + lane] + lnb_i[64 + lane];
    }
    __syncthreads();
    {
        int j = tid;
        float acc[NO];
        float bj = bl1_i[j];
        #pragma unroll
        for (int p = 0; p < NO; ++p) acc[p] = bj;
        for (int c = 0; c < NH; ++c){
            float w = Wl1_i[(size_t)c*NHH + j];
            #pragma unroll
            for (int p = 0; p < NO; ++p) acc[p] += sy[p*NH + c]*w;
        }
        #pragma unroll
        for (int p = 0; p < NO; ++p) sU[p*NHH + j] = gelu_f(acc[p]);
    }
    __syncthreads();
    {
        int q = tid >> 7, c = tid & 127;
        float acc[NO];
        #pragma unroll
        for (int p = 0; p < NO; ++p) acc[p] = 0.f;
        for (int j = q*128; j < q*128 + 128; ++j){
            float w = Wl2_i[(size_t)j*NH + c];
            #pragma unroll
            for (int p = 0; p < NO; ++p) acc[p] += sU[p*NHH + j]*w;
        }
        #pragma unroll
        for (int p = 0; p < NO; ++p) sred[(q*NO + p)*NH + c] = acc[p];
    }
    __syncthreads();
    for (int e = tid; e < NO*NH; e += 512){
        int p = e >> 7, c = e & 127;
        float v = sred[(0*NO+p)*NH + c] + sred[(1*NO+p)*NH + c]
                + sred[(2*NO+p)*NH + c] + sred[(3*NO+p)*NH + c];
        size_t gi = (((size_t)b*NO + p)*NN + m)*NH + c;
        hOut[gi] = v + bl2_i[c] + hIn[gi];
    }
}

// ---------------------------------------------------------------------------
// k_readout
// ---------------------------------------------------------------------------
__global__ __launch_bounds__(256) void k_readout(const float* __restrict__ h,
        const float* __restrict__ Wro, const float* __restrict__ bro,
        const float* __restrict__ mask, float* __restrict__ out){
    __shared__ float sw[NH];
    __shared__ float sacc[4], smsk[4];
    int tid = threadIdx.x, b = blockIdx.x;
    if (tid < NH) sw[tid] = Wro[tid];
    __syncthreads();
    float br = bro[0];
    float acc = 0.f;
    for (int e = tid; e < NN*NO; e += 256){
        int o = e % NO, mm = e / NO;
        const float* hp = h + (((size_t)b*NO + o)*NN + mm)*NH;
        float dot = 0.f;
        for (int c = 0; c < NH; ++c) dot += hp[c]*sw[c];
        acc += (dot + br)*mask[b*NN + mm];
    }
    float msum = (tid < NN) ? mask[b*NN + tid] : 0.f;
    for (int off = 32; off; off >>= 1){
        acc  += __shfl_xor(acc,  off);
        msum += __shfl_xor(msum, off);
    }
    if ((tid & 63) == 0){ sacc[tid>>6] = acc; smsk[tid>>6] = msum; }
    __syncthreads();
    if (tid == 0){
        float a = sacc[0]+sacc[1]+sacc[2]+sacc[3];
        float mm2 = smsk[0]+smsk[1]+smsk[2]+smsk[3];
        out[b] = a/(12.0f*mm2);
    }
}

// ---------------------------------------------------------------------------
extern "C" void kernel_launch(void* const* d_in, const int* in_sizes, int n_in,
                              void* d_out, int out_size, void* d_ws, size_t ws_size,
                              hipStream_t stream){
    const float* pos  = (const float*)d_in[0];
    const float* x    = (const float*)d_in[1];
    const float* mask = (const float*)d_in[2];
    const float* W1s  = (const float*)d_in[3];
    const float* b1s  = (const float*)d_in[4];
    const float* W2s  = (const float*)d_in[5];
    const float* b2s  = (const float*)d_in[6];
    const float* W1r  = (const float*)d_in[7];
    const float* b1r  = (const float*)d_in[8];
    const float* W2r  = (const float*)d_in[9];
    const float* b2r  = (const float*)d_in[10];
    const float* We   = (const float*)d_in[11];
    const float* Wsp  = (const float*)d_in[12];
    const float* Wrot = (const float*)d_in[13];
    const float* convb= (const float*)d_in[14];
    const float* lns  = (const float*)d_in[15];
    const float* lnb  = (const float*)d_in[16];
    const float* Wl1  = (const float*)d_in[17];
    const float* bl1  = (const float*)d_in[18];
    const float* Wl2  = (const float*)d_in[19];
    const float* bl2  = (const float*)d_in[20];
    const float* Wro  = (const float*)d_in[21];
    const float* bro  = (const float*)d_in[22];

    float* ws = (float*)d_ws;
    float* ws_ori = ws;
    float* ws_fib = ws + 64;
    float* ws_rot = ws + 64 + 4608;
    float* hA = ws_rot + NL*NO*NO*NH;
    float* hB = hA + NB*NO*NN*NH;
    float* hC = hB + NB*NO*NN*NH;
    ushort* kb = (ushort*)(hC + NB*NO*NN*NH);   // bf16, NB*NO*NN*NN*NBD elems

    k_setup<<<1, 256, 0, stream>>>(W1r, b1r, W2r, b2r, ws_ori, ws_fib);
    k_rot<<<NL*NO*NO*NH/256, 256, 0, stream>>>(ws_fib, Wrot, ws_rot);
    k_embed<<<NB*NO*NN*NH/256, 256, 0, stream>>>(x, We, hA);
    k_kb<<<NB*NO*NN*2, 256, 0, stream>>>(pos, W1s, b1s, W2s, b2s, ws_ori, kb);

    // layer 0
    k_convm<<<NB*NO*2, 256, 0, stream>>>(hA, kb, Wsp, mask, hC);
    k_mlp<<<NB*NN, 512, 0, stream>>>(hC, hA, hB,
            ws_rot, convb, lns, lnb,
            Wl1, bl1, Wl2, bl2);
    // layer 1
    k_convm<<<NB*NO*2, 256, 0, stream>>>(hB, kb, Wsp + NBD*NH, mask, hC);
    k_mlp<<<NB*NN, 512, 0, stream>>>(hC, hB, hA,
            ws_rot + NO*NO*NH, convb + NH, lns + NH, lnb + NH,
            Wl1 + NH*NHH, bl1 + NHH, Wl2 + NHH*NH, bl2 + NH);

    k_readout<<<NB, 256, 0, stream>>>(hA, Wro, bro, mask, (float*)d_out);
}

// Round 3
// 402.782 us; speedup vs baseline: 1.5060x; 1.5060x over previous
//
#include <hip/hip_runtime.h>
#include <math.h>

#define NB 2      // batch
#define NN 128    // points
#define NO 12     // orientations
#define NIN 16
#define NH 128
#define NBD 32
#define NL 2
#define NHH 512   // WF*H
#define NSPLIT 8  // conv K-split

typedef __attribute__((ext_vector_type(8))) short bf16x8;
typedef __attribute__((ext_vector_type(4))) float f32x4;

__device__ __forceinline__ float gelu_f(float x){
    float u = 0.7978845608028654f * (x + 0.044715f * x * x * x);
    float t = 1.0f - 2.0f / (__expf(2.0f * u) + 1.0f);   // tanh(u)
    return 0.5f * x * (1.0f + t);
}

__device__ __forceinline__ ushort f2b(float x){
    union { float f; uint u; } v; v.f = x;
    uint r = v.u + 0x7FFF + ((v.u >> 16) & 1);
    return (ushort)(r >> 16);
}

#define MFMA_BF16(A,B,C) __builtin_amdgcn_mfma_f32_16x16x32_bf16(A,B,C,0,0,0)

// ---------------------------------------------------------------------------
// k_setup: ori (12x3) + fiber_basis (12x12x32), one block
// ---------------------------------------------------------------------------
__global__ __launch_bounds__(256) void k_setup(const float* __restrict__ W1r,
        const float* __restrict__ b1r, const float* __restrict__ W2r,
        const float* __restrict__ b2r, float* __restrict__ ws_ori,
        float* __restrict__ ws_fiber){
    __shared__ float sori[NO*3];
    __shared__ float shid[NO*NO*NH];
    int tid = threadIdx.x;
    if (tid < NO){
        float fi = (float)tid;
        float th = fmodf(3.14159265358979323846f * fi * 3.23606797749979f,
                         6.28318530717958647692f);
        float ph = acosf(1.0f - 2.0f*(fi + 0.5f)/12.0f);
        float sp = sinf(ph);
        float ox = sp*cosf(th), oy = sp*sinf(th), oz = cosf(ph);
        sori[tid*3+0]=ox; sori[tid*3+1]=oy; sori[tid*3+2]=oz;
        ws_ori[tid*3+0]=ox; ws_ori[tid*3+1]=oy; ws_ori[tid*3+2]=oz;
    }
    __syncthreads();
    for (int e = tid; e < NO*NO*NH; e += 256){
        int t = e & 127, row = e >> 7;
        int p = row / NO, q = row - p*NO;
        float xv = sori[p*3]*sori[q*3] + sori[p*3+1]*sori[q*3+1] + sori[p*3+2]*sori[q*3+2];
        float acc = b1r[t] + xv*W1r[t] + xv*xv*W1r[NH+t] + xv*xv*xv*W1r[2*NH+t];
        shid[e] = gelu_f(acc);
    }
    __syncthreads();
    for (int e = tid; e < NO*NO*NBD; e += 256){
        int d = e & 31, row = e >> 5;
        float acc = b2r[d];
        const float* hr = shid + row*NH;
        for (int t = 0; t < NH; ++t) acc += hr[t]*W2r[t*NBD + d];
        ws_fiber[e] = gelu_f(acc);
    }
}

// ---------------------------------------------------------------------------
// k_rot: rot[i][p][o][c] = sum_d fiber[p][o][d] * Wrot[i][d][c]
// ---------------------------------------------------------------------------
__global__ __launch_bounds__(256) void k_rot(const float* __restrict__ fiber,
        const float* __restrict__ Wrot, float* __restrict__ rot){
    int g = blockIdx.x*256 + threadIdx.x;
    int c = g & 127; int rest = g >> 7;
    int o = rest % NO; rest /= NO;
    int p = rest % NO; int i = rest / NO;
    const float* f = fiber + (p*NO + o)*NBD;
    const float* w = Wrot + (size_t)i*NBD*NH + c;
    float acc = 0.f;
    #pragma unroll
    for (int d = 0; d < NBD; ++d) acc += f[d]*w[d*NH];
    rot[g] = acc;
}

// ---------------------------------------------------------------------------
// k_embed: hA[b][o][n][c] = sum_k x[b,n,k]*We[k,c]   (broadcast over o)
// ---------------------------------------------------------------------------
__global__ __launch_bounds__(256) void k_embed(const float* __restrict__ x,
        const float* __restrict__ We, float* __restrict__ hA){
    int g = blockIdx.x*256 + threadIdx.x;
    int c = g & 127; int n = (g >> 7) & 127; int rest = g >> 14;
    int b = rest / NO;
    const float* xp = x + ((size_t)b*NN + n)*NIN;
    float acc = 0.f;
    #pragma unroll
    for (int k = 0; k < NIN; ++k) acc += xp[k]*We[k*NH + c];
    hA[g] = acc;
}

// ---------------------------------------------------------------------------
// k_kb: block = (b,o,m); 128 n-rows.
//   layer1 (14->128) fp32 VALU, combined monomial weights, -> bf16 LDS A-tile
//   layer2 (128->32) bf16 MFMA from swizzled LDS
// ---------------------------------------------------------------------------
__global__ __launch_bounds__(256) void k_kb(const float* __restrict__ pos,
        const float* __restrict__ W1s, const float* __restrict__ b1s,
        const float* __restrict__ W2s, const float* __restrict__ b2s,
        const float* __restrict__ ori, ushort* __restrict__ kb){
    __shared__ float spab[NN*2];
    __shared__ float sb2[NBD];
    __shared__ __align__(16) ushort sA[NN*NH];     // swizzled hidden, 32KB
    __shared__ __align__(16) ushort sW2t[NBD*NH];  // swizzled W2^T [c][k], 8KB
    __shared__ __align__(16) ushort sOut[NN*NBD];  // 8KB

    int tid = threadIdx.x;
    int bid = blockIdx.x;                 // 3072 = NB*NO*NN
    int m = bid & 127; int t2 = bid >> 7;
    int o = t2 % NO, b = t2 / NO;

    // W1 column for this thread's t (fp32, registers), combined duplicates:
    // acc = b1 + a*w0 + bb*w1 + a2*w2 + a*bb*(w3+w4) + bb2*w5 + a3*w6
    //       + a2*bb*(w7+w8+w10) + a*bb2*(w9+w11+w12) + bb3*w13
    int t = tid & 127, rh = tid >> 7;
    float w0 = W1s[0*NH+t], w1 = W1s[1*NH+t], w2 = W1s[2*NH+t];
    float wc3 = W1s[3*NH+t] + W1s[4*NH+t];
    float w5 = W1s[5*NH+t], w6 = W1s[6*NH+t];
    float wc7 = W1s[7*NH+t] + W1s[8*NH+t] + W1s[10*NH+t];
    float wc9 = W1s[9*NH+t] + W1s[11*NH+t] + W1s[12*NH+t];
    float w13 = W1s[13*NH+t];
    float b1v = b1s[t];

    if (tid < NBD) sb2[tid] = b2s[tid];
    // stage W2^T bf16 swizzled: row c (32), col k (128)
    for (int e = tid; e < NBD*NH; e += 256){
        int c = e >> 7, k = e & 127;
        *(ushort*)((char*)sW2t + c*256 + ((k*2) ^ ((c & 7) << 4))) = f2b(W2s[k*NBD + c]);
    }
    // invariants per row n
    if (tid < NN){
        int n = tid;
        float rx = pos[((size_t)b*NN+n)*3+0] - pos[((size_t)b*NN+m)*3+0];
        float ry = pos[((size_t)b*NN+n)*3+1] - pos[((size_t)b*NN+m)*3+1];
        float rz = pos[((size_t)b*NN+n)*3+2] - pos[((size_t)b*NN+m)*3+2];
        float ox = ori[o*3+0], oy = ori[o*3+1], oz = ori[o*3+2];
        float a  = rx*ox + ry*oy + rz*oz;
        float bb = sqrtf(rx*rx+ry*ry+rz*rz) * fabsf(1.0f - a);
        spab[n*2]   = a;
        spab[n*2+1] = bb;
    }
    __syncthreads();
    // layer1: each thread: column t, 64 rows
    for (int r = rh*64; r < rh*64 + 64; ++r){
        float2 ab = *(const float2*)&spab[r*2];
        float a = ab.x, bb = ab.y;
        float a2 = a*a, b2v = bb*bb, abv = a*bb;
        float a3 = a2*a, a2b = a2*bb, ab2 = a*b2v, b3 = b2v*bb;
        float acc = b1v + a*w0 + bb*w1 + a2*w2 + abv*wc3 + b2v*w5
                  + a3*w6 + a2b*wc7 + ab2*wc9 + b3*w13;
        *(ushort*)((char*)sA + r*256 + ((t*2) ^ ((r & 7) << 4))) = f2b(gelu_f(acc));
    }
    __syncthreads();
    // layer2 MFMA: wave w: rows w*32..+32 (2 tiles), cols 0..31 (2 tiles), K=128
    int w = tid >> 6, lane = tid & 63, lr = lane & 15, lg = lane >> 4;
    f32x4 acc[2][2];
    #pragma unroll
    for (int i = 0; i < 2; ++i)
        #pragma unroll
        for (int j = 0; j < 2; ++j){
            float bv = sb2[j*16 + lr];
            acc[i][j] = (f32x4){bv,bv,bv,bv};
        }
    #pragma unroll
    for (int kk = 0; kk < 4; ++kk){
        int kbyte = (kk*32 + lg*8)*2;
        int r0 = w*32 + lr, r1 = w*32 + 16 + lr;
        bf16x8 a0 = *(const bf16x8*)((const char*)sA + r0*256 + (kbyte ^ ((r0 & 7) << 4)));
        bf16x8 a1 = *(const bf16x8*)((const char*)sA + r1*256 + (kbyte ^ ((r1 & 7) << 4)));
        bf16x8 bb0 = *(const bf16x8*)((const char*)sW2t + lr*256      + (kbyte ^ ((lr & 7) << 4)));
        bf16x8 bb1 = *(const bf16x8*)((const char*)sW2t + (16+lr)*256 + (kbyte ^ ((lr & 7) << 4)));
        acc[0][0] = MFMA_BF16(a0, bb0, acc[0][0]);
        acc[0][1] = MFMA_BF16(a0, bb1, acc[0][1]);
        acc[1][0] = MFMA_BF16(a1, bb0, acc[1][0]);
        acc[1][1] = MFMA_BF16(a1, bb1, acc[1][1]);
    }
    // epilogue: gelu -> sOut[n][d]
    #pragma unroll
    for (int i = 0; i < 2; ++i)
        #pragma unroll
        for (int j = 0; j < 2; ++j)
            #pragma unroll
            for (int r = 0; r < 4; ++r){
                int n = w*32 + i*16 + lg*4 + r, d = j*16 + lr;
                sOut[n*NBD + d] = f2b(gelu_f(acc[i][j][r]));
            }
    __syncthreads();
    size_t base = ((size_t)((b*NO + o)*NN + m))*(NN*NBD);
    uint4* dst = (uint4*)(kb + base);
    const uint4* src = (const uint4*)sOut;
    dst[tid] = src[tid];
    dst[256 + tid] = src[256 + tid];
}

// ---------------------------------------------------------------------------
// k_wbuild: Wt[b,o][c][k=(n*32+d)] = h[b,o,n,c]*mask[b,n]*Wsp[d,c]  (bf16)
// block = (b,o,n-slice of 8): grid NB*NO*16 = 384
// ---------------------------------------------------------------------------
__global__ __launch_bounds__(256) void k_wbuild(const float* __restrict__ h,
        const float* __restrict__ wsp_i, const float* __restrict__ mask,
        ushort* __restrict__ Wt){
    __shared__ float sWspT[NH*33];     // [c][d] padded
    __shared__ float sg[8*130];        // [n][c] padded
    int tid = threadIdx.x;
    int bid = blockIdx.x;              // 384
    int ns = bid & 15; int rest = bid >> 4;
    int o = rest % NO, b = rest / NO;

    for (int e = tid; e < NBD*NH; e += 256){
        int c = e & 127, d = e >> 7;
        sWspT[c*33 + d] = wsp_i[d*NH + c];
    }
    for (int e = tid; e < 8*NH; e += 256){
        int n = e >> 7, c = e & 127;
        int ng = ns*8 + n;
        sg[n*130 + c] = h[((size_t)(b*NO + o)*NN + ng)*NH + c] * mask[b*NN + ng];
    }
    __syncthreads();
    size_t obase = ((size_t)(b*NO + o)*NH)*(NN*NBD);
    #pragma unroll
    for (int it = 0; it < 16; ++it){
        int flat = it*256 + tid;       // 4096
        int o8 = flat & 3, n = (flat >> 2) & 7, c = flat >> 5;
        float gv = sg[n*130 + c];
        ushort pk[8];
        #pragma unroll
        for (int dd = 0; dd < 8; ++dd)
            pk[dd] = f2b(gv * sWspT[c*33 + o8*8 + dd]);
        uint4 v;
        v.x = (uint)pk[0] | ((uint)pk[1] << 16);
        v.y = (uint)pk[2] | ((uint)pk[3] << 16);
        v.z = (uint)pk[4] | ((uint)pk[5] << 16);
        v.w = (uint)pk[6] | ((uint)pk[7] << 16);
        *(uint4*)(Wt + obase + (size_t)c*(NN*NBD) + (ns*8 + n)*NBD + o8*8) = v;
    }
}

// ---------------------------------------------------------------------------
// k_convg: partial[s][b][o][m][c] = A[m, k-slice] @ Wt[c, k-slice]^T
// block = (b,o,mh,s): M=64, N=128, K=512 (chunks of 128). 4 waves 2x2.
// ---------------------------------------------------------------------------
__global__ __launch_bounds__(256) void k_convg(const ushort* __restrict__ kb,
        const ushort* __restrict__ Wt, float* __restrict__ part){
    __shared__ __align__(16) ushort sA[64*NH];     // 16KB swizzled
    __shared__ __align__(16) ushort sW[NH*NH];     // 32KB swizzled
    int tid = threadIdx.x;
    int bid = blockIdx.x;              // 384
    int s = bid & 7, mh = (bid >> 3) & 1;
    int rest = bid >> 4;
    int o = rest % NO, b = rest / NO;

    int w = tid >> 6, lane = tid & 63, lr = lane & 15, lg = lane >> 4;
    int wm = (w >> 1)*32, wc = (w & 1)*64;

    const ushort* abase = kb + ((size_t)(b*NO + o)*NN + mh*64)*(NN*NBD) + s*512;
    const ushort* wbase = Wt + ((size_t)(b*NO + o)*NH)*(NN*NBD) + s*512;

    f32x4 acc[2][4];
    #pragma unroll
    for (int i = 0; i < 2; ++i)
        #pragma unroll
        for (int j = 0; j < 4; ++j)
            acc[i][j] = (f32x4){0.f,0.f,0.f,0.f};

    for (int ch = 0; ch < 4; ++ch){
        // stage A: 64 rows x 128 k
        #pragma unroll
        for (int it = 0; it < 4; ++it){
            int flat = it*256 + tid;
            int row = flat >> 4, seg = flat & 15;
            uint4 v = *(const uint4*)(abase + (size_t)row*(NN*NBD) + ch*128 + seg*8);
            *(uint4*)((char*)sA + row*256 + ((seg*16) ^ ((row & 7) << 4))) = v;
        }
        // stage W: 128 rows(c) x 128 k
        #pragma unroll
        for (int it = 0; it < 8; ++it){
            int flat = it*256 + tid;
            int row = flat >> 4, seg = flat & 15;
            uint4 v = *(const uint4*)(wbase + (size_t)row*(NN*NBD) + ch*128 + seg*8);
            *(uint4*)((char*)sW + row*256 + ((seg*16) ^ ((row & 7) << 4))) = v;
        }
        __syncthreads();
        #pragma unroll
        for (int kk = 0; kk < 4; ++kk){
            int kbyte = (kk*32 + lg*8)*2;
            int r0 = wm + lr, r1 = wm + 16 + lr;
            bf16x8 a0 = *(const bf16x8*)((const char*)sA + r0*256 + (kbyte ^ ((r0 & 7) << 4)));
            bf16x8 a1 = *(const bf16x8*)((const char*)sA + r1*256 + (kbyte ^ ((r1 & 7) << 4)));
            bf16x8 bf[4];
            #pragma unroll
            for (int j = 0; j < 4; ++j){
                int c = wc + j*16 + lr;
                bf[j] = *(const bf16x8*)((const char*)sW + c*256 + (kbyte ^ ((c & 7) << 4)));
            }
            #pragma unroll
            for (int j = 0; j < 4; ++j){
                acc[0][j] = MFMA_BF16(a0, bf[j], acc[0][j]);
                acc[1][j] = MFMA_BF16(a1, bf[j], acc[1][j]);
            }
        }
        __syncthreads();
    }
    float* pbase = part + ((size_t)((s*NB + b)*NO + o)*NN + mh*64)*NH;
    #pragma unroll
    for (int i = 0; i < 2; ++i)
        #pragma unroll
        for (int j = 0; j < 4; ++j)
            #pragma unroll
            for (int r = 0; r < 4; ++r){
                int mm = wm + i*16 + lg*4 + r;
                int c = wc + j*16 + lr;
                pbase[(size_t)mm*NH + c] = acc[i][j][r];
            }
}

// ---------------------------------------------------------------------------
// k_mlp: partial-reduce + rot-mix + conv bias + LN + MLP + residual. block=(b,m)
// ---------------------------------------------------------------------------
__global__ __launch_bounds__(512) void k_mlp(const float* __restrict__ part,
        const float* __restrict__ hIn, float* __restrict__ hOut,
        const float* __restrict__ rot_i, const float* __restrict__ convb_i,
        const float* __restrict__ lns_i, const float* __restrict__ lnb_i,
        const float* __restrict__ Wl1_i, const float* __restrict__ bl1_i,
        const float* __restrict__ Wl2_i, const float* __restrict__ bl2_i){
    __shared__ float shcv[NO*NH];
    __shared__ float sy[NO*NH];
    __shared__ float sU[NO*NHH];
    __shared__ float sred[4*NO*NH];
    int tid = threadIdx.x;
    int bid = blockIdx.x;
    int m = bid & 127, b = bid >> 7;
    for (int e = tid; e < NO*NH; e += 512){
        int o = e >> 7, c = e & 127;
        float sv = 0.f;
        #pragma unroll
        for (int sl = 0; sl < NSPLIT; ++sl)
            sv += part[((size_t)((sl*NB + b)*NO + o)*NN + m)*NH + c];
        shcv[e] = sv;
    }
    __syncthreads();
    for (int e = tid; e < NO*NH; e += 512){
        int p = e >> 7, c = e & 127;
        float acc = 0.f;
        #pragma unroll
        for (int o = 0; o < NO; ++o)
            acc += shcv[o*NH + c]*rot_i[(p*NO + o)*NH + c];
        sy[e] = acc*(1.0f/12.0f) + convb_i[c];
    }
    __syncthreads();
    int wid = tid >> 6, lane = tid & 63;
    for (int row = wid; row < NO; row += 8){
        float x0 = sy[row*NH + lane], x1 = sy[row*NH + 64 + lane];
        float s = x0 + x1, ss = x0*x0 + x1*x1;
        for (int off = 32; off; off >>= 1){
            s  += __shfl_xor(s,  off);
            ss += __shfl_xor(ss, off);
        }
        float mn  = s*(1.0f/128.0f);
        float var = ss*(1.0f/128.0f) - mn*mn;
        float r = rsqrtf(var + 1e-6f);
        sy[row*NH + lane]      = (x0 - mn)*r*lns_i[lane]      + lnb_i[lane];
        sy[row*NH + 64 + lane] = (x1 - mn)*r*lns_i[64 + lane] + lnb_i[64 + lane];
    }
    __syncthreads();
    {
        int j = tid;
        float acc[NO];
        float bj = bl1_i[j];
        #pragma unroll
        for (int p = 0; p < NO; ++p) acc[p] = bj;
        for (int c = 0; c < NH; ++c){
            float w = Wl1_i[(size_t)c*NHH + j];
            #pragma unroll
            for (int p = 0; p < NO; ++p) acc[p] += sy[p*NH + c]*w;
        }
        #pragma unroll
        for (int p = 0; p < NO; ++p) sU[p*NHH + j] = gelu_f(acc[p]);
    }
    __syncthreads();
    {
        int q = tid >> 7, c = tid & 127;
        float acc[NO];
        #pragma unroll
        for (int p = 0; p < NO; ++p) acc[p] = 0.f;
        for (int j = q*128; j < q*128 + 128; ++j){
            float w = Wl2_i[(size_t)j*NH + c];
            #pragma unroll
            for (int p = 0; p < NO; ++p) acc[p] += sU[p*NHH + j]*w;
        }
        #pragma unroll
        for (int p = 0; p < NO; ++p) sred[(q*NO + p)*NH + c] = acc[p];
    }
    __syncthreads();
    for (int e = tid; e < NO*NH; e += 512){
        int p = e >> 7, c = e & 127;
        float v = sred[(0*NO+p)*NH + c] + sred[(1*NO+p)*NH + c]
                + sred[(2*NO+p)*NH + c] + sred[(3*NO+p)*NH + c];
        size_t gi = (((size_t)b*NO + p)*NN + m)*NH + c;
        hOut[gi] = v + bl2_i[c] + hIn[gi];
    }
}

// ---------------------------------------------------------------------------
// k_readout
// ---------------------------------------------------------------------------
__global__ __launch_bounds__(256) void k_readout(const float* __restrict__ h,
        const float* __restrict__ Wro, const float* __restrict__ bro,
        const float* __restrict__ mask, float* __restrict__ out){
    __shared__ float sw[NH];
    __shared__ float sacc[4], smsk[4];
    int tid = threadIdx.x, b = blockIdx.x;
    if (tid < NH) sw[tid] = Wro[tid];
    __syncthreads();
    float br = bro[0];
    float acc = 0.f;
    for (int e = tid; e < NN*NO; e += 256){
        int o = e % NO, mm = e / NO;
        const float4* hp = (const float4*)(h + (((size_t)b*NO + o)*NN + mm)*NH);
        const float4* swp = (const float4*)sw;
        float dot = 0.f;
        #pragma unroll
        for (int c = 0; c < NH/4; ++c){
            float4 hv = hp[c], wv = swp[c];
            dot += hv.x*wv.x + hv.y*wv.y + hv.z*wv.z + hv.w*wv.w;
        }
        acc += (dot + br)*mask[b*NN + mm];
    }
    float msum = (tid < NN) ? mask[b*NN + tid] : 0.f;
    for (int off = 32; off; off >>= 1){
        acc  += __shfl_xor(acc,  off);
        msum += __shfl_xor(msum, off);
    }
    if ((tid & 63) == 0){ sacc[tid>>6] = acc; smsk[tid>>6] = msum; }
    __syncthreads();
    if (tid == 0){
        float a = sacc[0]+sacc[1]+sacc[2]+sacc[3];
        float mm2 = smsk[0]+smsk[1]+smsk[2]+smsk[3];
        out[b] = a/(12.0f*mm2);
    }
}

// ---------------------------------------------------------------------------
extern "C" void kernel_launch(void* const* d_in, const int* in_sizes, int n_in,
                              void* d_out, int out_size, void* d_ws, size_t ws_size,
                              hipStream_t stream){
    const float* pos  = (const float*)d_in[0];
    const float* x    = (const float*)d_in[1];
    const float* mask = (const float*)d_in[2];
    const float* W1s  = (const float*)d_in[3];
    const float* b1s  = (const float*)d_in[4];
    const float* W2s  = (const float*)d_in[5];
    const float* b2s  = (const float*)d_in[6];
    const float* W1r  = (const float*)d_in[7];
    const float* b1r  = (const float*)d_in[8];
    const float* W2r  = (const float*)d_in[9];
    const float* b2r  = (const float*)d_in[10];
    const float* We   = (const float*)d_in[11];
    const float* Wsp  = (const float*)d_in[12];
    const float* Wrot = (const float*)d_in[13];
    const float* convb= (const float*)d_in[14];
    const float* lns  = (const float*)d_in[15];
    const float* lnb  = (const float*)d_in[16];
    const float* Wl1  = (const float*)d_in[17];
    const float* bl1  = (const float*)d_in[18];
    const float* Wl2  = (const float*)d_in[19];
    const float* bl2  = (const float*)d_in[20];
    const float* Wro  = (const float*)d_in[21];
    const float* bro  = (const float*)d_in[22];

    float* ws = (float*)d_ws;
    float* ws_ori = ws;                         // 64
    float* ws_fib = ws + 64;                    // 4608
    float* ws_rot = ws + 64 + 4608;             // NL*NO*NO*NH
    float* hA   = ws_rot + NL*NO*NO*NH;         // 393216
    float* hB   = hA + NB*NO*NN*NH;             // 393216
    float* part = hB + NB*NO*NN*NH;             // NSPLIT*393216
    ushort* kb  = (ushort*)(part + NSPLIT*NB*NO*NN*NH);   // 12582912 bf16
    ushort* Wt  = kb + (size_t)NB*NO*NN*NN*NBD;           // 12582912 bf16

    k_setup<<<1, 256, 0, stream>>>(W1r, b1r, W2r, b2r, ws_ori, ws_fib);
    k_rot<<<NL*NO*NO*NH/256, 256, 0, stream>>>(ws_fib, Wrot, ws_rot);
    k_embed<<<NB*NO*NN*NH/256, 256, 0, stream>>>(x, We, hA);
    k_kb<<<NB*NO*NN, 256, 0, stream>>>(pos, W1s, b1s, W2s, b2s, ws_ori, kb);

    // layer 0
    k_wbuild<<<NB*NO*16, 256, 0, stream>>>(hA, Wsp, mask, Wt);
    k_convg<<<NB*NO*2*NSPLIT, 256, 0, stream>>>(kb, Wt, part);
    k_mlp<<<NB*NN, 512, 0, stream>>>(part, hA, hB,
            ws_rot, convb, lns, lnb,
            Wl1, bl1, Wl2, bl2);
    // layer 1
    k_wbuild<<<NB*NO*16, 256, 0, stream>>>(hB, Wsp + NBD*NH, mask, Wt);
    k_convg<<<NB*NO*2*NSPLIT, 256, 0, stream>>>(kb, Wt, part);
    k_mlp<<<NB*NN, 512, 0, stream>>>(part, hB, hA,
            ws_rot + NO*NO*NH, convb + NH, lns + NH, lnb + NH,
            Wl1 + NH*NHH, bl1 + NHH, Wl2 + NHH*NH, bl2 + NH);

    k_readout<<<NB, 256, 0, stream>>>(hA, Wro, bro, mask, (float*)d_out);
}

// Round 4
// 314.274 us; speedup vs baseline: 1.9301x; 1.2816x over previous
//
#include <hip/hip_runtime.h>
#include <math.h>

#define NB 2      // batch
#define NN 128    // points
#define NO 12     // orientations
#define NIN 16
#define NH 128
#define NBD 32
#define NL 2
#define NHH 512   // WF*H
#define NSPLIT 8  // conv K-split

typedef __attribute__((ext_vector_type(8))) short bf16x8;
typedef __attribute__((ext_vector_type(4))) float f32x4;

// gelu (tanh approx) in sigmoid form, division-free:
// gelu(x) = x * sigmoid(2u), 2u*log2e = x*(2.3022077 + 0.1029435 x^2)
__device__ __forceinline__ float gelu_f(float x){
    float x2 = x*x;
    float t = x*(2.3022077f + 0.1029435f*x2);
    float e = __builtin_amdgcn_exp2f(t);
    float r = __builtin_amdgcn_rcpf(e + 1.0f);
    return __builtin_fmaf(-x, r, x);
}

__device__ __forceinline__ ushort f2b(float x){
    union { float f; uint u; } v; v.f = x;
    uint r = v.u + 0x7FFF + ((v.u >> 16) & 1);
    return (ushort)(r >> 16);
}

#define MFMA_BF16(A,B,C) __builtin_amdgcn_mfma_f32_16x16x32_bf16(A,B,C,0,0,0)

// ---------------------------------------------------------------------------
// k_setup: ori + fiber_basis + combined W1 (w1ct, 128c x 32k bf16) + W2^T
// ---------------------------------------------------------------------------
__global__ __launch_bounds__(256) void k_setup(const float* __restrict__ W1r,
        const float* __restrict__ b1r, const float* __restrict__ W2r,
        const float* __restrict__ b2r, const float* __restrict__ W1s,
        const float* __restrict__ b1s, const float* __restrict__ W2s,
        float* __restrict__ ws_ori, float* __restrict__ ws_fiber,
        ushort* __restrict__ w1ct, ushort* __restrict__ w2ct){
    __shared__ float sori[NO*3];
    __shared__ float shid[NO*NO*NH];
    int tid = threadIdx.x;
    if (tid < NO){
        float fi = (float)tid;
        float th = fmodf(3.14159265358979323846f * fi * 3.23606797749979f,
                         6.28318530717958647692f);
        float ph = acosf(1.0f - 2.0f*(fi + 0.5f)/12.0f);
        float sp = sinf(ph);
        float ox = sp*cosf(th), oy = sp*sinf(th), oz = cosf(ph);
        sori[tid*3+0]=ox; sori[tid*3+1]=oy; sori[tid*3+2]=oz;
        ws_ori[tid*3+0]=ox; ws_ori[tid*3+1]=oy; ws_ori[tid*3+2]=oz;
    }
    // combined W1 (duplicate monomials summed), row k, col c; rows>=10 zero
    if (tid < NH){
        int c = tid;
        float r0 = b1s[c];
        float r1 = W1s[c], r2 = W1s[NH+c], r3 = W1s[2*NH+c];
        float r4 = W1s[3*NH+c] + W1s[4*NH+c];
        float r5 = W1s[5*NH+c], r6 = W1s[6*NH+c];
        float r7 = W1s[7*NH+c] + W1s[8*NH+c] + W1s[10*NH+c];
        float r8 = W1s[9*NH+c] + W1s[11*NH+c] + W1s[12*NH+c];
        float r9 = W1s[13*NH+c];
        ushort* p = w1ct + c*32;
        p[0]=f2b(r0); p[1]=f2b(r1); p[2]=f2b(r2); p[3]=f2b(r3); p[4]=f2b(r4);
        p[5]=f2b(r5); p[6]=f2b(r6); p[7]=f2b(r7); p[8]=f2b(r8); p[9]=f2b(r9);
        #pragma unroll
        for (int k = 10; k < 32; ++k) p[k] = 0;
    }
    for (int e = tid; e < NBD*NH; e += 256){
        int c = e >> 7, k = e & 127;
        w2ct[c*NH + k] = f2b(W2s[k*NBD + c]);
    }
    __syncthreads();
    for (int e = tid; e < NO*NO*NH; e += 256){
        int t = e & 127, row = e >> 7;
        int p = row / NO, q = row - p*NO;
        float xv = sori[p*3]*sori[q*3] + sori[p*3+1]*sori[q*3+1] + sori[p*3+2]*sori[q*3+2];
        float acc = b1r[t] + xv*W1r[t] + xv*xv*W1r[NH+t] + xv*xv*xv*W1r[2*NH+t];
        shid[e] = gelu_f(acc);
    }
    __syncthreads();
    for (int e = tid; e < NO*NO*NBD; e += 256){
        int d = e & 31, row = e >> 5;
        float acc = b2r[d];
        const float* hr = shid + row*NH;
        for (int t = 0; t < NH; ++t) acc += hr[t]*W2r[t*NBD + d];
        ws_fiber[e] = gelu_f(acc);
    }
}

// ---------------------------------------------------------------------------
// k_rot
// ---------------------------------------------------------------------------
__global__ __launch_bounds__(256) void k_rot(const float* __restrict__ fiber,
        const float* __restrict__ Wrot, float* __restrict__ rot){
    int g = blockIdx.x*256 + threadIdx.x;
    int c = g & 127; int rest = g >> 7;
    int o = rest % NO; rest /= NO;
    int p = rest % NO; int i = rest / NO;
    const float* f = fiber + (p*NO + o)*NBD;
    const float* w = Wrot + (size_t)i*NBD*NH + c;
    float acc = 0.f;
    #pragma unroll
    for (int d = 0; d < NBD; ++d) acc += f[d]*w[d*NH];
    rot[g] = acc;
}

// ---------------------------------------------------------------------------
// k_embed
// ---------------------------------------------------------------------------
__global__ __launch_bounds__(256) void k_embed(const float* __restrict__ x,
        const float* __restrict__ We, float* __restrict__ hA){
    int g = blockIdx.x*256 + threadIdx.x;
    int c = g & 127; int n = (g >> 7) & 127; int rest = g >> 14;
    int b = rest / NO;
    const float* xp = x + ((size_t)b*NN + n)*NIN;
    float acc = 0.f;
    #pragma unroll
    for (int k = 0; k < NIN; ++k) acc += xp[k]*We[k*NH + c];
    hA[g] = acc;
}

// ---------------------------------------------------------------------------
// k_kb: block=(b,o,m), both MLP layers via MFMA.
//   L1: A=[128 n][32 k] bf16 poly feats (k0=1 bias), B=w1ct -> hidden 128x128
//   L2: hidden @ W2 (32 cols) -> gelu -> kb
// ---------------------------------------------------------------------------
__global__ __launch_bounds__(256) void k_kb(const float* __restrict__ pos,
        const ushort* __restrict__ w1ct, const ushort* __restrict__ w2ct,
        const float* __restrict__ b2s, const float* __restrict__ ori,
        ushort* __restrict__ kb){
    __shared__ __align__(16) char smem[49152];
    ushort* sF  = (ushort*)smem;            // 8KB: features [128][32] swz; later sOut
    char*  sWT  = smem + 8192;              // 8KB: w1ct then w2t, swizzled
    char*  sH   = smem + 16384;             // 32KB: hidden [128][128] bf16 swz

    int tid = threadIdx.x;
    int bid = blockIdx.x;                 // 3072
    int m = bid & 127; int t2 = bid >> 7;
    int o = t2 % NO, b = t2 / NO;
    int w = tid >> 6, lane = tid & 63, lr = lane & 15, lg = lane >> 4;

    // stage W1cT: rows(c) 64B, XOR (c&3)<<4
    {
        const uint* src = (const uint*)w1ct;     // 2048 u32
        for (int e = tid; e < 2048; e += 256){
            int c = e >> 4, kk = e & 15;
            *(uint*)(sWT + c*64 + ((kk*4) ^ ((c & 3) << 4))) = src[e];
        }
    }
    // features
    if (tid < NN){
        int n = tid;
        float rx = pos[((size_t)b*NN+n)*3+0] - pos[((size_t)b*NN+m)*3+0];
        float ry = pos[((size_t)b*NN+n)*3+1] - pos[((size_t)b*NN+m)*3+1];
        float rz = pos[((size_t)b*NN+n)*3+2] - pos[((size_t)b*NN+m)*3+2];
        float ox = ori[o*3+0], oy = ori[o*3+1], oz = ori[o*3+2];
        float a  = rx*ox + ry*oy + rz*oz;
        float bb = sqrtf(rx*rx+ry*ry+rz*rz) * fabsf(1.0f - a);
        float a2 = a*a, b2 = bb*bb, ab = a*bb;
        float fv[10] = {1.0f, a, bb, a2, ab, b2, a2*a, a2*bb, a*b2, b2*bb};
        char* rowp = (char*)sF + n*64;
        int sw = (n & 3) << 4;
        #pragma unroll
        for (int kk = 0; kk < 5; ++kk){
            uint pk = (uint)f2b(fv[kk*2]) | ((uint)f2b(fv[kk*2+1]) << 16);
            *(uint*)(rowp + ((kk*4) ^ sw)) = pk;
        }
        #pragma unroll
        for (int kk = 5; kk < 16; ++kk)
            *(uint*)(rowp + ((kk*4) ^ sw)) = 0u;
    }
    __syncthreads();
    // layer1 MFMA: wave w -> rows w*32..+32, cols 0..127, K=32
    f32x4 hacc[2][8];
    {
        int rA0 = w*32 + lr, rA1 = rA0 + 16;
        bf16x8 fa0 = *(const bf16x8*)((char*)sF + rA0*64 + ((lg*16) ^ ((rA0 & 3) << 4)));
        bf16x8 fa1 = *(const bf16x8*)((char*)sF + rA1*64 + ((lg*16) ^ ((rA1 & 3) << 4)));
        #pragma unroll
        for (int j = 0; j < 8; ++j){
            int cB = j*16 + lr;
            bf16x8 fb = *(const bf16x8*)(sWT + cB*64 + ((lg*16) ^ ((cB & 3) << 4)));
            f32x4 z = (f32x4){0.f,0.f,0.f,0.f};
            hacc[0][j] = MFMA_BF16(fa0, fb, z);
            hacc[1][j] = MFMA_BF16(fa1, fb, z);
        }
    }
    // epi1: gelu -> bf16 -> sH (rows 256B, XOR (n&7)<<4)
    #pragma unroll
    for (int i = 0; i < 2; ++i)
        #pragma unroll
        for (int j = 0; j < 8; ++j)
            #pragma unroll
            for (int r = 0; r < 4; ++r){
                int n = w*32 + i*16 + lg*4 + r;
                int c = j*16 + lr;
                *(ushort*)(sH + n*256 + ((c*2) ^ ((n & 7) << 4))) = f2b(gelu_f(hacc[i][j][r]));
            }
    __syncthreads();
    // restage sWT with W2^T: 32 rows(c) x 128 k, rows 256B, XOR (c&7)<<4
    {
        const uint* src = (const uint*)w2ct;   // 2048 u32
        for (int e = tid; e < 2048; e += 256){
            int c = e >> 6, kk = e & 63;
            *(uint*)(sWT + c*256 + ((kk*4) ^ ((c & 7) << 4))) = src[e];
        }
    }
    __syncthreads();
    // layer2 MFMA: rows w*32..+32, cols 0..31, K=128
    float bv0 = b2s[lr], bv1 = b2s[16 + lr];
    f32x4 acc2[2][2];
    acc2[0][0] = (f32x4){bv0,bv0,bv0,bv0}; acc2[0][1] = (f32x4){bv1,bv1,bv1,bv1};
    acc2[1][0] = acc2[0][0]; acc2[1][1] = acc2[0][1];
    #pragma unroll
    for (int kk = 0; kk < 4; ++kk){
        int kbyte = (kk*32 + lg*8)*2;
        int r0 = w*32 + lr, r1 = r0 + 16;
        bf16x8 a0 = *(const bf16x8*)(sH + r0*256 + (kbyte ^ ((r0 & 7) << 4)));
        bf16x8 a1 = *(const bf16x8*)(sH + r1*256 + (kbyte ^ ((r1 & 7) << 4)));
        bf16x8 b0 = *(const bf16x8*)(sWT + lr*256 + (kbyte ^ ((lr & 7) << 4)));
        bf16x8 b1 = *(const bf16x8*)(sWT + (16+lr)*256 + (kbyte ^ ((lr & 7) << 4)));
        acc2[0][0] = MFMA_BF16(a0, b0, acc2[0][0]);
        acc2[0][1] = MFMA_BF16(a0, b1, acc2[0][1]);
        acc2[1][0] = MFMA_BF16(a1, b0, acc2[1][0]);
        acc2[1][1] = MFMA_BF16(a1, b1, acc2[1][1]);
    }
    ushort* sOut = (ushort*)smem;   // aliases sF (dead after layer1)
    #pragma unroll
    for (int i = 0; i < 2; ++i)
        #pragma unroll
        for (int j = 0; j < 2; ++j)
            #pragma unroll
            for (int r = 0; r < 4; ++r){
                int n = w*32 + i*16 + lg*4 + r, d = j*16 + lr;
                sOut[n*NBD + d] = f2b(gelu_f(acc2[i][j][r]));
            }
    __syncthreads();
    size_t base = ((size_t)((b*NO + o)*NN + m))*(NN*NBD);
    uint4* dst = (uint4*)(kb + base);
    const uint4* src = (const uint4*)sOut;
    dst[tid] = src[tid];
    dst[256 + tid] = src[256 + tid];
}

// ---------------------------------------------------------------------------
// k_wbuild: Wt[b,o][c][k=(n*32+d)] = h[b,o,n,c]*mask[b,n]*Wsp[d,c]  (bf16)
// ---------------------------------------------------------------------------
__global__ __launch_bounds__(256) void k_wbuild(const float* __restrict__ h,
        const float* __restrict__ wsp_i, const float* __restrict__ mask,
        ushort* __restrict__ Wt){
    __shared__ float sWspT[NH*33];
    __shared__ float sg[8*130];
    int tid = threadIdx.x;
    int bid = blockIdx.x;              // 384
    int ns = bid & 15; int rest = bid >> 4;
    int o = rest % NO, b = rest / NO;

    for (int e = tid; e < NBD*NH; e += 256){
        int c = e & 127, d = e >> 7;
        sWspT[c*33 + d] = wsp_i[d*NH + c];
    }
    for (int e = tid; e < 8*NH; e += 256){
        int n = e >> 7, c = e & 127;
        int ng = ns*8 + n;
        sg[n*130 + c] = h[((size_t)(b*NO + o)*NN + ng)*NH + c] * mask[b*NN + ng];
    }
    __syncthreads();
    size_t obase = ((size_t)(b*NO + o)*NH)*(NN*NBD);
    #pragma unroll
    for (int it = 0; it < 16; ++it){
        int flat = it*256 + tid;
        int o8 = flat & 3, n = (flat >> 2) & 7, c = flat >> 5;
        float gv = sg[n*130 + c];
        ushort pk[8];
        #pragma unroll
        for (int dd = 0; dd < 8; ++dd)
            pk[dd] = f2b(gv * sWspT[c*33 + o8*8 + dd]);
        uint4 v;
        v.x = (uint)pk[0] | ((uint)pk[1] << 16);
        v.y = (uint)pk[2] | ((uint)pk[3] << 16);
        v.z = (uint)pk[4] | ((uint)pk[5] << 16);
        v.w = (uint)pk[6] | ((uint)pk[7] << 16);
        *(uint4*)(Wt + obase + (size_t)c*(NN*NBD) + (ns*8 + n)*NBD + o8*8) = v;
    }
}

// ---------------------------------------------------------------------------
// k_convg: partial[s][b][o][m][c] = A[m,k-slice] @ Wt[c,k-slice]^T
// ---------------------------------------------------------------------------
__global__ __launch_bounds__(256) void k_convg(const ushort* __restrict__ kb,
        const ushort* __restrict__ Wt, float* __restrict__ part){
    __shared__ __align__(16) ushort sA[64*NH];
    __shared__ __align__(16) ushort sW[NH*NH];
    int tid = threadIdx.x;
    int bid = blockIdx.x;              // 384
    int s = bid & 7, mh = (bid >> 3) & 1;
    int rest = bid >> 4;
    int o = rest % NO, b = rest / NO;

    int w = tid >> 6, lane = tid & 63, lr = lane & 15, lg = lane >> 4;
    int wm = (w >> 1)*32, wc = (w & 1)*64;

    const ushort* abase = kb + ((size_t)(b*NO + o)*NN + mh*64)*(NN*NBD) + s*512;
    const ushort* wbase = Wt + ((size_t)(b*NO + o)*NH)*(NN*NBD) + s*512;

    f32x4 acc[2][4];
    #pragma unroll
    for (int i = 0; i < 2; ++i)
        #pragma unroll
        for (int j = 0; j < 4; ++j)
            acc[i][j] = (f32x4){0.f,0.f,0.f,0.f};

    for (int ch = 0; ch < 4; ++ch){
        #pragma unroll
        for (int it = 0; it < 4; ++it){
            int flat = it*256 + tid;
            int row = flat >> 4, seg = flat & 15;
            uint4 v = *(const uint4*)(abase + (size_t)row*(NN*NBD) + ch*128 + seg*8);
            *(uint4*)((char*)sA + row*256 + ((seg*16) ^ ((row & 7) << 4))) = v;
        }
        #pragma unroll
        for (int it = 0; it < 8; ++it){
            int flat = it*256 + tid;
            int row = flat >> 4, seg = flat & 15;
            uint4 v = *(const uint4*)(wbase + (size_t)row*(NN*NBD) + ch*128 + seg*8);
            *(uint4*)((char*)sW + row*256 + ((seg*16) ^ ((row & 7) << 4))) = v;
        }
        __syncthreads();
        #pragma unroll
        for (int kk = 0; kk < 4; ++kk){
            int kbyte = (kk*32 + lg*8)*2;
            int r0 = wm + lr, r1 = wm + 16 + lr;
            bf16x8 a0 = *(const bf16x8*)((const char*)sA + r0*256 + (kbyte ^ ((r0 & 7) << 4)));
            bf16x8 a1 = *(const bf16x8*)((const char*)sA + r1*256 + (kbyte ^ ((r1 & 7) << 4)));
            bf16x8 bf[4];
            #pragma unroll
            for (int j = 0; j < 4; ++j){
                int c = wc + j*16 + lr;
                bf[j] = *(const bf16x8*)((const char*)sW + c*256 + (kbyte ^ ((c & 7) << 4)));
            }
            #pragma unroll
            for (int j = 0; j < 4; ++j){
                acc[0][j] = MFMA_BF16(a0, bf[j], acc[0][j]);
                acc[1][j] = MFMA_BF16(a1, bf[j], acc[1][j]);
            }
        }
        __syncthreads();
    }
    float* pbase = part + ((size_t)((s*NB + b)*NO + o)*NN + mh*64)*NH;
    #pragma unroll
    for (int i = 0; i < 2; ++i)
        #pragma unroll
        for (int j = 0; j < 4; ++j)
            #pragma unroll
            for (int r = 0; r < 4; ++r){
                int mm = wm + i*16 + lg*4 + r;
                int c = wc + j*16 + lr;
                pbase[(size_t)mm*NH + c] = acc[i][j][r];
            }
}

// ---------------------------------------------------------------------------
// k_mlp: partial-reduce + rot-mix + conv bias + LN + MLP + residual
// ---------------------------------------------------------------------------
__global__ __launch_bounds__(512) void k_mlp(const float* __restrict__ part,
        const float* __restrict__ hIn, float* __restrict__ hOut,
        const float* __restrict__ rot_i, const float* __restrict__ convb_i,
        const float* __restrict__ lns_i, const float* __restrict__ lnb_i,
        const float* __restrict__ Wl1_i, const float* __restrict__ bl1_i,
        const float* __restrict__ Wl2_i, const float* __restrict__ bl2_i){
    __shared__ float shcv[NO*NH];
    __shared__ float sy[NO*NH];
    __shared__ float sU[NO*NHH];
    __shared__ float sred[4*NO*NH];
    int tid = threadIdx.x;
    int bid = blockIdx.x;
    int m = bid & 127, b = bid >> 7;
    for (int e = tid; e < NO*NH; e += 512){
        int o = e >> 7, c = e & 127;
        float sv = 0.f;
        #pragma unroll
        for (int sl = 0; sl < NSPLIT; ++sl)
            sv += part[((size_t)((sl*NB + b)*NO + o)*NN + m)*NH + c];
        shcv[e] = sv;
    }
    __syncthreads();
    for (int e = tid; e < NO*NH; e += 512){
        int p = e >> 7, c = e & 127;
        float acc = 0.f;
        #pragma unroll
        for (int o = 0; o < NO; ++o)
            acc += shcv[o*NH + c]*rot_i[(p*NO + o)*NH + c];
        sy[e] = acc*(1.0f/12.0f) + convb_i[c];
    }
    __syncthreads();
    int wid = tid >> 6, lane = tid & 63;
    for (int row = wid; row < NO; row += 8){
        float x0 = sy[row*NH + lane], x1 = sy[row*NH + 64 + lane];
        float s = x0 + x1, ss = x0*x0 + x1*x1;
        for (int off = 32; off; off >>= 1){
            s  += __shfl_xor(s,  off);
            ss += __shfl_xor(ss, off);
        }
        float mn  = s*(1.0f/128.0f);
        float var = ss*(1.0f/128.0f) - mn*mn;
        float r = rsqrtf(var + 1e-6f);
        sy[row*NH + lane]      = (x0 - mn)*r*lns_i[lane]      + lnb_i[lane];
        sy[row*NH + 64 + lane] = (x1 - mn)*r*lns_i[64 + lane] + lnb_i[64 + lane];
    }
    __syncthreads();
    // layer1: thread j, f32x4 broadcast chunks of sy
    {
        int j = tid;
        float acc[NO];
        float bj = bl1_i[j];
        #pragma unroll
        for (int p = 0; p < NO; ++p) acc[p] = bj;
        for (int c0 = 0; c0 < NH; c0 += 4){
            f32x4 syv[NO];
            #pragma unroll
            for (int p = 0; p < NO; ++p) syv[p] = *(const f32x4*)&sy[p*NH + c0];
            #pragma unroll
            for (int cc = 0; cc < 4; ++cc){
                float wv = Wl1_i[(size_t)(c0+cc)*NHH + j];
                #pragma unroll
                for (int p = 0; p < NO; ++p) acc[p] += syv[p][cc]*wv;
            }
        }
        #pragma unroll
        for (int p = 0; p < NO; ++p) sU[p*NHH + j] = gelu_f(acc[p]);
    }
    __syncthreads();
    // layer2: (c, j-quarter), f32x4 broadcast chunks of sU
    {
        int q = tid >> 7, c = tid & 127;
        float acc[NO];
        #pragma unroll
        for (int p = 0; p < NO; ++p) acc[p] = 0.f;
        for (int j0 = q*128; j0 < q*128 + 128; j0 += 4){
            f32x4 uv[NO];
            #pragma unroll
            for (int p = 0; p < NO; ++p) uv[p] = *(const f32x4*)&sU[p*NHH + j0];
            #pragma unroll
            for (int jj = 0; jj < 4; ++jj){
                float wv = Wl2_i[(size_t)(j0+jj)*NH + c];
                #pragma unroll
                for (int p = 0; p < NO; ++p) acc[p] += uv[p][jj]*wv;
            }
        }
        #pragma unroll
        for (int p = 0; p < NO; ++p) sred[(q*NO + p)*NH + c] = acc[p];
    }
    __syncthreads();
    for (int e = tid; e < NO*NH; e += 512){
        int p = e >> 7, c = e & 127;
        float v = sred[(0*NO+p)*NH + c] + sred[(1*NO+p)*NH + c]
                + sred[(2*NO+p)*NH + c] + sred[(3*NO+p)*NH + c];
        size_t gi = (((size_t)b*NO + p)*NN + m)*NH + c;
        hOut[gi] = v + bl2_i[c] + hIn[gi];
    }
}

// ---------------------------------------------------------------------------
// k_readout
// ---------------------------------------------------------------------------
__global__ __launch_bounds__(1024) void k_readout(const float* __restrict__ h,
        const float* __restrict__ Wro, const float* __restrict__ bro,
        const float* __restrict__ mask, float* __restrict__ out){
    __shared__ float sw[NH];
    __shared__ float sacc[16], smsk[16];
    int tid = threadIdx.x, b = blockIdx.x;
    if (tid < NH) sw[tid] = Wro[tid];
    __syncthreads();
    float br = bro[0];
    float acc = 0.f;
    for (int e = tid; e < NN*NO; e += 1024){
        int o = e % NO, mm = e / NO;
        const float4* hp = (const float4*)(h + (((size_t)b*NO + o)*NN + mm)*NH);
        const float4* swp = (const float4*)sw;
        float dot = 0.f;
        #pragma unroll
        for (int c = 0; c < NH/4; ++c){
            float4 hv = hp[c], wv = swp[c];
            dot += hv.x*wv.x + hv.y*wv.y + hv.z*wv.z + hv.w*wv.w;
        }
        acc += (dot + br)*mask[b*NN + mm];
    }
    float msum = (tid < NN) ? mask[b*NN + tid] : 0.f;
    for (int off = 32; off; off >>= 1){
        acc  += __shfl_xor(acc,  off);
        msum += __shfl_xor(msum, off);
    }
    if ((tid & 63) == 0){ sacc[tid>>6] = acc; smsk[tid>>6] = msum; }
    __syncthreads();
    if (tid == 0){
        float a = 0.f, mm2 = 0.f;
        #pragma unroll
        for (int i = 0; i < 16; ++i){ a += sacc[i]; mm2 += smsk[i]; }
        out[b] = a/(12.0f*mm2);
    }
}

// ---------------------------------------------------------------------------
extern "C" void kernel_launch(void* const* d_in, const int* in_sizes, int n_in,
                              void* d_out, int out_size, void* d_ws, size_t ws_size,
                              hipStream_t stream){
    const float* pos  = (const float*)d_in[0];
    const float* x    = (const float*)d_in[1];
    const float* mask = (const float*)d_in[2];
    const float* W1s  = (const float*)d_in[3];
    const float* b1s  = (const float*)d_in[4];
    const float* W2s  = (const float*)d_in[5];
    const float* b2s  = (const float*)d_in[6];
    const float* W1r  = (const float*)d_in[7];
    const float* b1r  = (const float*)d_in[8];
    const float* W2r  = (const float*)d_in[9];
    const float* b2r  = (const float*)d_in[10];
    const float* We   = (const float*)d_in[11];
    const float* Wsp  = (const float*)d_in[12];
    const float* Wrot = (const float*)d_in[13];
    const float* convb= (const float*)d_in[14];
    const float* lns  = (const float*)d_in[15];
    const float* lnb  = (const float*)d_in[16];
    const float* Wl1  = (const float*)d_in[17];
    const float* bl1  = (const float*)d_in[18];
    const float* Wl2  = (const float*)d_in[19];
    const float* bl2  = (const float*)d_in[20];
    const float* Wro  = (const float*)d_in[21];
    const float* bro  = (const float*)d_in[22];

    float* ws = (float*)d_ws;
    float* ws_ori = ws;                         // 64
    float* ws_fib = ws + 64;                    // 4608
    float* ws_rot = ws + 64 + 4608;             // NL*NO*NO*NH ends at 41536
    ushort* w1ct = (ushort*)(ws + 41536);       // 4096 ushort (2048 fl)
    ushort* w2ct = (ushort*)(ws + 43584);       // 4096 ushort (2048 fl)
    float* hA   = ws + 45632;                   // 393216
    float* hB   = hA + NB*NO*NN*NH;
    float* part = hB + NB*NO*NN*NH;             // NSPLIT*393216
    ushort* kb  = (ushort*)(part + NSPLIT*NB*NO*NN*NH);   // 12582912 bf16
    ushort* Wt  = kb + (size_t)NB*NO*NN*NN*NBD;           // 12582912 bf16

    k_setup<<<1, 256, 0, stream>>>(W1r, b1r, W2r, b2r, W1s, b1s, W2s,
                                   ws_ori, ws_fib, w1ct, w2ct);
    k_rot<<<NL*NO*NO*NH/256, 256, 0, stream>>>(ws_fib, Wrot, ws_rot);
    k_embed<<<NB*NO*NN*NH/256, 256, 0, stream>>>(x, We, hA);
    k_kb<<<NB*NO*NN, 256, 0, stream>>>(pos, w1ct, w2ct, b2s, ws_ori, kb);

    // layer 0
    k_wbuild<<<NB*NO*16, 256, 0, stream>>>(hA, Wsp, mask, Wt);
    k_convg<<<NB*NO*2*NSPLIT, 256, 0, stream>>>(kb, Wt, part);
    k_mlp<<<NB*NN, 512, 0, stream>>>(part, hA, hB,
            ws_rot, convb, lns, lnb,
            Wl1, bl1, Wl2, bl2);
    // layer 1
    k_wbuild<<<NB*NO*16, 256, 0, stream>>>(hB, Wsp + NBD*NH, mask, Wt);
    k_convg<<<NB*NO*2*NSPLIT, 256, 0, stream>>>(kb, Wt, part);
    k_mlp<<<NB*NN, 512, 0, stream>>>(part, hB, hA,
            ws_rot + NO*NO*NH, convb + NH, lns + NH, lnb + NH,
            Wl1 + NH*NHH, bl1 + NHH, Wl2 + NHH*NH, bl2 + NH);

    k_readout<<<NB, 1024, 0, stream>>>(hA, Wro, bro, mask, (float*)d_out);
}

// Round 5
// 278.529 us; speedup vs baseline: 2.1778x; 1.1283x over previous
//
#include <hip/hip_runtime.h>
#include <math.h>

#define NB 2      // batch
#define NN 128    // points
#define NO 12     // orientations
#define NIN 16
#define NH 128
#define NBD 32
#define NL 2
#define NHH 512   // WF*H
#define NSPLIT 8  // conv K-split

typedef __attribute__((ext_vector_type(8))) short bf16x8;
typedef __attribute__((ext_vector_type(4))) float f32x4;

// gelu (tanh approx) in sigmoid form, division-free
__device__ __forceinline__ float gelu_f(float x){
    float x2 = x*x;
    float t = x*(2.3022077f + 0.1029435f*x2);
    float e = __builtin_amdgcn_exp2f(t);
    float r = __builtin_amdgcn_rcpf(e + 1.0f);
    return __builtin_fmaf(-x, r, x);
}

__device__ __forceinline__ ushort f2b(float x){
    union { float f; uint u; } v; v.f = x;
    uint r = v.u + 0x7FFF + ((v.u >> 16) & 1);
    return (ushort)(r >> 16);
}

#define MFMA_BF16(A,B,C) __builtin_amdgcn_mfma_f32_16x16x32_bf16(A,B,C,0,0,0)

// ---------------------------------------------------------------------------
// k_setup: ori + w1ct/w2ct (combined spatial weights) + fiber basis via MFMA
// ---------------------------------------------------------------------------
__global__ __launch_bounds__(256) void k_setup(const float* __restrict__ W1r,
        const float* __restrict__ b1r, const float* __restrict__ W2r,
        const float* __restrict__ b2r, const float* __restrict__ W1s,
        const float* __restrict__ b1s, const float* __restrict__ W2s,
        float* __restrict__ ws_ori, float* __restrict__ ws_fiber,
        ushort* __restrict__ w1ct, ushort* __restrict__ w2ct){
    __shared__ float sori[NO*3];
    __shared__ float sb2r[NBD];
    __shared__ __align__(16) char sWT[8192];      // W2r bf16 swz [c 32][k 128]
    __shared__ __align__(16) char sHid[160*256];  // fiber hidden bf16 swz

    int tid = threadIdx.x;
    int w = tid >> 6, lane = tid & 63, lr = lane & 15, lg = lane >> 4;

    if (tid < NO){
        float fi = (float)tid;
        float th = fmodf(3.14159265358979323846f * fi * 3.23606797749979f,
                         6.28318530717958647692f);
        float ph = acosf(1.0f - 2.0f*(fi + 0.5f)/12.0f);
        float sp = sinf(ph);
        float ox = sp*cosf(th), oy = sp*sinf(th), oz = cosf(ph);
        sori[tid*3+0]=ox; sori[tid*3+1]=oy; sori[tid*3+2]=oz;
        ws_ori[tid*3+0]=ox; ws_ori[tid*3+1]=oy; ws_ori[tid*3+2]=oz;
    }
    if (tid < NBD) sb2r[tid] = b2r[tid];
    // combined spatial W1 (duplicate monomials summed), col-major bf16 [c][k32]
    if (tid < NH){
        int c = tid;
        float r0 = b1s[c];
        float r1 = W1s[c], r2 = W1s[NH+c], r3 = W1s[2*NH+c];
        float r4 = W1s[3*NH+c] + W1s[4*NH+c];
        float r5 = W1s[5*NH+c], r6 = W1s[6*NH+c];
        float r7 = W1s[7*NH+c] + W1s[8*NH+c] + W1s[10*NH+c];
        float r8 = W1s[9*NH+c] + W1s[11*NH+c] + W1s[12*NH+c];
        float r9 = W1s[13*NH+c];
        ushort* p = w1ct + c*32;
        p[0]=f2b(r0); p[1]=f2b(r1); p[2]=f2b(r2); p[3]=f2b(r3); p[4]=f2b(r4);
        p[5]=f2b(r5); p[6]=f2b(r6); p[7]=f2b(r7); p[8]=f2b(r8); p[9]=f2b(r9);
        #pragma unroll
        for (int k = 10; k < 32; ++k) p[k] = 0;
    }
    // spatial W2^T bf16 to global [c 32][k 128]
    for (int e = tid; e < NBD*NH; e += 256){
        int c = e >> 7, k = e & 127;
        w2ct[c*NH + k] = f2b(W2s[k*NBD + c]);
    }
    // rotation W2^T bf16 swizzled to LDS
    for (int e = tid; e < NBD*NH; e += 256){
        int c = e >> 7, k = e & 127;
        *(ushort*)(sWT + c*256 + ((k*2) ^ ((c & 7) << 4))) = f2b(W2r[k*NBD + c]);
    }
    // zero pad rows 144..159 of sHid
    for (int e = tid; e < 16*64; e += 256){
        int row = 144 + (e >> 6), k2 = e & 63;
        *(uint*)(sHid + row*256 + ((k2*4) ^ ((row & 7) << 4))) = 0u;
    }
    __syncthreads();
    // fiber hidden: 144 rows x 128, bf16 swizzled
    for (int e = tid; e < 144*NH; e += 256){
        int t = e & 127, row = e >> 7;
        int p = row / NO, q = row - (row/NO)*NO;
        float xv = sori[p*3]*sori[q*3] + sori[p*3+1]*sori[q*3+1] + sori[p*3+2]*sori[q*3+2];
        float acc = b1r[t] + xv*(W1r[t] + xv*(W1r[NH+t] + xv*W1r[2*NH+t]));
        *(ushort*)(sHid + row*256 + ((t*2) ^ ((row & 7) << 4))) = f2b(gelu_f(acc));
    }
    __syncthreads();
    // fiber L2 MFMA: 5 row-tiles of 32; wave w -> tiles w, w+4
    for (int tile = w; tile < 5; tile += 4){
        float bv0 = sb2r[lr], bv1 = sb2r[16 + lr];
        f32x4 acc2[2][2];
        acc2[0][0] = (f32x4){bv0,bv0,bv0,bv0}; acc2[0][1] = (f32x4){bv1,bv1,bv1,bv1};
        acc2[1][0] = acc2[0][0]; acc2[1][1] = acc2[0][1];
        #pragma unroll
        for (int kk = 0; kk < 4; ++kk){
            int kbyte = (kk*32 + lg*8)*2;
            int r0 = tile*32 + lr, r1 = r0 + 16;
            bf16x8 a0 = *(const bf16x8*)(sHid + r0*256 + (kbyte ^ ((r0 & 7) << 4)));
            bf16x8 a1 = *(const bf16x8*)(sHid + r1*256 + (kbyte ^ ((r1 & 7) << 4)));
            bf16x8 b0 = *(const bf16x8*)(sWT + lr*256 + (kbyte ^ ((lr & 7) << 4)));
            bf16x8 b1 = *(const bf16x8*)(sWT + (16+lr)*256 + (kbyte ^ ((lr & 7) << 4)));
            acc2[0][0] = MFMA_BF16(a0, b0, acc2[0][0]);
            acc2[0][1] = MFMA_BF16(a0, b1, acc2[0][1]);
            acc2[1][0] = MFMA_BF16(a1, b0, acc2[1][0]);
            acc2[1][1] = MFMA_BF16(a1, b1, acc2[1][1]);
        }
        #pragma unroll
        for (int i = 0; i < 2; ++i)
            #pragma unroll
            for (int j = 0; j < 2; ++j)
                #pragma unroll
                for (int r = 0; r < 4; ++r){
                    int row = tile*32 + i*16 + lg*4 + r, d = j*16 + lr;
                    if (row < 144) ws_fiber[row*NBD + d] = gelu_f(acc2[i][j][r]);
                }
    }
}

// ---------------------------------------------------------------------------
// k_rot
// ---------------------------------------------------------------------------
__global__ __launch_bounds__(256) void k_rot(const float* __restrict__ fiber,
        const float* __restrict__ Wrot, float* __restrict__ rot){
    int g = blockIdx.x*256 + threadIdx.x;
    int c = g & 127; int rest = g >> 7;
    int o = rest % NO; rest /= NO;
    int p = rest % NO; int i = rest / NO;
    const float* f = fiber + (p*NO + o)*NBD;
    const float* w = Wrot + (size_t)i*NBD*NH + c;
    float acc = 0.f;
    #pragma unroll
    for (int d = 0; d < NBD; ++d) acc += f[d]*w[d*NH];
    rot[g] = acc;
}

// ---------------------------------------------------------------------------
// k_embed: compact hE[b][n][c] (no o-broadcast)
// ---------------------------------------------------------------------------
__global__ __launch_bounds__(256) void k_embed(const float* __restrict__ x,
        const float* __restrict__ We, float* __restrict__ hE){
    int g = blockIdx.x*256 + threadIdx.x;      // NB*NN*NH = 32768
    int c = g & 127; int n = (g >> 7) & 127; int b = g >> 14;
    const float* xp = x + ((size_t)b*NN + n)*NIN;
    float acc = 0.f;
    #pragma unroll
    for (int k = 0; k < NIN; ++k) acc += xp[k]*We[k*NH + c];
    hE[g] = acc;
}

// ---------------------------------------------------------------------------
// k_kb: block=(b,o,m), both MLP layers via MFMA.
// ---------------------------------------------------------------------------
__global__ __launch_bounds__(256) void k_kb(const float* __restrict__ pos,
        const ushort* __restrict__ w1ct, const ushort* __restrict__ w2ct,
        const float* __restrict__ b2s, const float* __restrict__ ori,
        ushort* __restrict__ kb){
    __shared__ __align__(16) char smem[49152];
    ushort* sF  = (ushort*)smem;            // 8KB features / later sOut
    char*  sWT  = smem + 8192;              // 8KB weights swz
    char*  sH   = smem + 16384;             // 32KB hidden swz

    int tid = threadIdx.x;
    int bid = blockIdx.x;                 // 3072
    int m = bid & 127; int t2 = bid >> 7;
    int o = t2 % NO, b = t2 / NO;
    int w = tid >> 6, lane = tid & 63, lr = lane & 15, lg = lane >> 4;

    {
        const uint* src = (const uint*)w1ct;
        for (int e = tid; e < 2048; e += 256){
            int c = e >> 4, kk = e & 15;
            *(uint*)(sWT + c*64 + ((kk*4) ^ ((c & 3) << 4))) = src[e];
        }
    }
    if (tid < NN){
        int n = tid;
        float rx = pos[((size_t)b*NN+n)*3+0] - pos[((size_t)b*NN+m)*3+0];
        float ry = pos[((size_t)b*NN+n)*3+1] - pos[((size_t)b*NN+m)*3+1];
        float rz = pos[((size_t)b*NN+n)*3+2] - pos[((size_t)b*NN+m)*3+2];
        float ox = ori[o*3+0], oy = ori[o*3+1], oz = ori[o*3+2];
        float a  = rx*ox + ry*oy + rz*oz;
        float bb = sqrtf(rx*rx+ry*ry+rz*rz) * fabsf(1.0f - a);
        float a2 = a*a, b2 = bb*bb, ab = a*bb;
        float fv[10] = {1.0f, a, bb, a2, ab, b2, a2*a, a2*bb, a*b2, b2*bb};
        char* rowp = (char*)sF + n*64;
        int sw = (n & 3) << 4;
        #pragma unroll
        for (int kk = 0; kk < 5; ++kk){
            uint pk = (uint)f2b(fv[kk*2]) | ((uint)f2b(fv[kk*2+1]) << 16);
            *(uint*)(rowp + ((kk*4) ^ sw)) = pk;
        }
        #pragma unroll
        for (int kk = 5; kk < 16; ++kk)
            *(uint*)(rowp + ((kk*4) ^ sw)) = 0u;
    }
    __syncthreads();
    f32x4 hacc[2][8];
    {
        int rA0 = w*32 + lr, rA1 = rA0 + 16;
        bf16x8 fa0 = *(const bf16x8*)((char*)sF + rA0*64 + ((lg*16) ^ ((rA0 & 3) << 4)));
        bf16x8 fa1 = *(const bf16x8*)((char*)sF + rA1*64 + ((lg*16) ^ ((rA1 & 3) << 4)));
        #pragma unroll
        for (int j = 0; j < 8; ++j){
            int cB = j*16 + lr;
            bf16x8 fb = *(const bf16x8*)(sWT + cB*64 + ((lg*16) ^ ((cB & 3) << 4)));
            f32x4 z = (f32x4){0.f,0.f,0.f,0.f};
            hacc[0][j] = MFMA_BF16(fa0, fb, z);
            hacc[1][j] = MFMA_BF16(fa1, fb, z);
        }
    }
    #pragma unroll
    for (int i = 0; i < 2; ++i)
        #pragma unroll
        for (int j = 0; j < 8; ++j)
            #pragma unroll
            for (int r = 0; r < 4; ++r){
                int n = w*32 + i*16 + lg*4 + r;
                int c = j*16 + lr;
                *(ushort*)(sH + n*256 + ((c*2) ^ ((n & 7) << 4))) = f2b(gelu_f(hacc[i][j][r]));
            }
    __syncthreads();
    {
        const uint* src = (const uint*)w2ct;
        for (int e = tid; e < 2048; e += 256){
            int c = e >> 6, kk = e & 63;
            *(uint*)(sWT + c*256 + ((kk*4) ^ ((c & 7) << 4))) = src[e];
        }
    }
    __syncthreads();
    float bv0 = b2s[lr], bv1 = b2s[16 + lr];
    f32x4 acc2[2][2];
    acc2[0][0] = (f32x4){bv0,bv0,bv0,bv0}; acc2[0][1] = (f32x4){bv1,bv1,bv1,bv1};
    acc2[1][0] = acc2[0][0]; acc2[1][1] = acc2[0][1];
    #pragma unroll
    for (int kk = 0; kk < 4; ++kk){
        int kbyte = (kk*32 + lg*8)*2;
        int r0 = w*32 + lr, r1 = r0 + 16;
        bf16x8 a0 = *(const bf16x8*)(sH + r0*256 + (kbyte ^ ((r0 & 7) << 4)));
        bf16x8 a1 = *(const bf16x8*)(sH + r1*256 + (kbyte ^ ((r1 & 7) << 4)));
        bf16x8 b0 = *(const bf16x8*)(sWT + lr*256 + (kbyte ^ ((lr & 7) << 4)));
        bf16x8 b1 = *(const bf16x8*)(sWT + (16+lr)*256 + (kbyte ^ ((lr & 7) << 4)));
        acc2[0][0] = MFMA_BF16(a0, b0, acc2[0][0]);
        acc2[0][1] = MFMA_BF16(a0, b1, acc2[0][1]);
        acc2[1][0] = MFMA_BF16(a1, b0, acc2[1][0]);
        acc2[1][1] = MFMA_BF16(a1, b1, acc2[1][1]);
    }
    ushort* sOut = (ushort*)smem;
    #pragma unroll
    for (int i = 0; i < 2; ++i)
        #pragma unroll
        for (int j = 0; j < 2; ++j)
            #pragma unroll
            for (int r = 0; r < 4; ++r){
                int n = w*32 + i*16 + lg*4 + r, d = j*16 + lr;
                sOut[n*NBD + d] = f2b(gelu_f(acc2[i][j][r]));
            }
    __syncthreads();
    size_t base = ((size_t)((b*NO + o)*NN + m))*(NN*NBD);
    uint4* dst = (uint4*)(kb + base);
    const uint4* src = (const uint4*)sOut;
    dst[tid] = src[tid];
    dst[256 + tid] = src[256 + tid];
}

// ---------------------------------------------------------------------------
// k_wbuild: Wt[b,o][c][k=(n*32+d)] = h[b,(o),n,c]*mask[b,n]*Wsp[d,c]
// h index: b*sB + o*sP + n*NH + c  (sP=0 for o-broadcast input)
// ---------------------------------------------------------------------------
__global__ __launch_bounds__(256) void k_wbuild(const float* __restrict__ h,
        const float* __restrict__ wsp_i, const float* __restrict__ mask,
        ushort* __restrict__ Wt, int sB, int sP){
    __shared__ float sWspT[NH*33];
    __shared__ float sg[8*130];
    int tid = threadIdx.x;
    int bid = blockIdx.x;              // 384
    int ns = bid & 15; int rest = bid >> 4;
    int o = rest % NO, b = rest / NO;

    for (int e = tid; e < NBD*NH; e += 256){
        int c = e & 127, d = e >> 7;
        sWspT[c*33 + d] = wsp_i[d*NH + c];
    }
    for (int e = tid; e < 8*NH; e += 256){
        int n = e >> 7, c = e & 127;
        int ng = ns*8 + n;
        sg[n*130 + c] = h[(size_t)b*sB + (size_t)o*sP + (size_t)ng*NH + c] * mask[b*NN + ng];
    }
    __syncthreads();
    size_t obase = ((size_t)(b*NO + o)*NH)*(NN*NBD);
    #pragma unroll
    for (int it = 0; it < 16; ++it){
        int flat = it*256 + tid;
        int o8 = flat & 3, n = (flat >> 2) & 7, c = flat >> 5;
        float gv = sg[n*130 + c];
        ushort pk[8];
        #pragma unroll
        for (int dd = 0; dd < 8; ++dd)
            pk[dd] = f2b(gv * sWspT[c*33 + o8*8 + dd]);
        uint4 v;
        v.x = (uint)pk[0] | ((uint)pk[1] << 16);
        v.y = (uint)pk[2] | ((uint)pk[3] << 16);
        v.z = (uint)pk[4] | ((uint)pk[5] << 16);
        v.w = (uint)pk[6] | ((uint)pk[7] << 16);
        *(uint4*)(Wt + obase + (size_t)c*(NN*NBD) + (ns*8 + n)*NBD + o8*8) = v;
    }
}

// ---------------------------------------------------------------------------
// k_convg: partial[s][b][o][m][c] = A[m,k-slice] @ Wt[c,k-slice]^T
// ---------------------------------------------------------------------------
__global__ __launch_bounds__(256) void k_convg(const ushort* __restrict__ kb,
        const ushort* __restrict__ Wt, float* __restrict__ part){
    __shared__ __align__(16) ushort sA[64*NH];
    __shared__ __align__(16) ushort sW[NH*NH];
    int tid = threadIdx.x;
    int bid = blockIdx.x;              // 384
    int s = bid & 7, mh = (bid >> 3) & 1;
    int rest = bid >> 4;
    int o = rest % NO, b = rest / NO;

    int w = tid >> 6, lane = tid & 63, lr = lane & 15, lg = lane >> 4;
    int wm = (w >> 1)*32, wc = (w & 1)*64;

    const ushort* abase = kb + ((size_t)(b*NO + o)*NN + mh*64)*(NN*NBD) + s*512;
    const ushort* wbase = Wt + ((size_t)(b*NO + o)*NH)*(NN*NBD) + s*512;

    f32x4 acc[2][4];
    #pragma unroll
    for (int i = 0; i < 2; ++i)
        #pragma unroll
        for (int j = 0; j < 4; ++j)
            acc[i][j] = (f32x4){0.f,0.f,0.f,0.f};

    for (int ch = 0; ch < 4; ++ch){
        #pragma unroll
        for (int it = 0; it < 4; ++it){
            int flat = it*256 + tid;
            int row = flat >> 4, seg = flat & 15;
            uint4 v = *(const uint4*)(abase + (size_t)row*(NN*NBD) + ch*128 + seg*8);
            *(uint4*)((char*)sA + row*256 + ((seg*16) ^ ((row & 7) << 4))) = v;
        }
        #pragma unroll
        for (int it = 0; it < 8; ++it){
            int flat = it*256 + tid;
            int row = flat >> 4, seg = flat & 15;
            uint4 v = *(const uint4*)(wbase + (size_t)row*(NN*NBD) + ch*128 + seg*8);
            *(uint4*)((char*)sW + row*256 + ((seg*16) ^ ((row & 7) << 4))) = v;
        }
        __syncthreads();
        #pragma unroll
        for (int kk = 0; kk < 4; ++kk){
            int kbyte = (kk*32 + lg*8)*2;
            int r0 = wm + lr, r1 = wm + 16 + lr;
            bf16x8 a0 = *(const bf16x8*)((const char*)sA + r0*256 + (kbyte ^ ((r0 & 7) << 4)));
            bf16x8 a1 = *(const bf16x8*)((const char*)sA + r1*256 + (kbyte ^ ((r1 & 7) << 4)));
            bf16x8 bf[4];
            #pragma unroll
            for (int j = 0; j < 4; ++j){
                int c = wc + j*16 + lr;
                bf[j] = *(const bf16x8*)((const char*)sW + c*256 + (kbyte ^ ((c & 7) << 4)));
            }
            #pragma unroll
            for (int j = 0; j < 4; ++j){
                acc[0][j] = MFMA_BF16(a0, bf[j], acc[0][j]);
                acc[1][j] = MFMA_BF16(a1, bf[j], acc[1][j]);
            }
        }
        __syncthreads();
    }
    float* pbase = part + ((size_t)((s*NB + b)*NO + o)*NN + mh*64)*NH;
    #pragma unroll
    for (int i = 0; i < 2; ++i)
        #pragma unroll
        for (int j = 0; j < 4; ++j)
            #pragma unroll
            for (int r = 0; r < 4; ++r){
                int mm = wm + i*16 + lg*4 + r;
                int c = wc + j*16 + lr;
                pbase[(size_t)mm*NH + c] = acc[i][j][r];
            }
}

// ---------------------------------------------------------------------------
// k_mlp: partial-reduce + rot-mix + conv bias + LN + MLP + residual
// hIn index: b*sB + p*sP + m*NH + c
// ---------------------------------------------------------------------------
__global__ __launch_bounds__(512) void k_mlp(const float* __restrict__ part,
        const float* __restrict__ hIn, float* __restrict__ hOut,
        const float* __restrict__ rot_i, const float* __restrict__ convb_i,
        const float* __restrict__ lns_i, const float* __restrict__ lnb_i,
        const float* __restrict__ Wl1_i, const float* __restrict__ bl1_i,
        const float* __restrict__ Wl2_i, const float* __restrict__ bl2_i,
        int sB, int sP){
    __shared__ float shcv[NO*NH];
    __shared__ float sy[NO*NH];
    __shared__ float sU[NO*NHH];
    __shared__ float sred[4*NO*NH];
    int tid = threadIdx.x;
    int bid = blockIdx.x;
    int m = bid & 127, b = bid >> 7;
    for (int e = tid; e < NO*NH; e += 512){
        int o = e >> 7, c = e & 127;
        float sv = 0.f;
        #pragma unroll
        for (int sl = 0; sl < NSPLIT; ++sl)
            sv += part[((size_t)((sl*NB + b)*NO + o)*NN + m)*NH + c];
        shcv[e] = sv;
    }
    __syncthreads();
    for (int e = tid; e < NO*NH; e += 512){
        int p = e >> 7, c = e & 127;
        float acc = 0.f;
        #pragma unroll
        for (int o = 0; o < NO; ++o)
            acc += shcv[o*NH + c]*rot_i[(p*NO + o)*NH + c];
        sy[e] = acc*(1.0f/12.0f) + convb_i[c];
    }
    __syncthreads();
    int wid = tid >> 6, lane = tid & 63;
    for (int row = wid; row < NO; row += 8){
        float x0 = sy[row*NH + lane], x1 = sy[row*NH + 64 + lane];
        float s = x0 + x1, ss = x0*x0 + x1*x1;
        for (int off = 32; off; off >>= 1){
            s  += __shfl_xor(s,  off);
            ss += __shfl_xor(ss, off);
        }
        float mn  = s*(1.0f/128.0f);
        float var = ss*(1.0f/128.0f) - mn*mn;
        float r = rsqrtf(var + 1e-6f);
        sy[row*NH + lane]      = (x0 - mn)*r*lns_i[lane]      + lnb_i[lane];
        sy[row*NH + 64 + lane] = (x1 - mn)*r*lns_i[64 + lane] + lnb_i[64 + lane];
    }
    __syncthreads();
    {
        int j = tid;
        float acc[NO];
        float bj = bl1_i[j];
        #pragma unroll
        for (int p = 0; p < NO; ++p) acc[p] = bj;
        for (int c0 = 0; c0 < NH; c0 += 4){
            f32x4 syv[NO];
            #pragma unroll
            for (int p = 0; p < NO; ++p) syv[p] = *(const f32x4*)&sy[p*NH + c0];
            #pragma unroll
            for (int cc = 0; cc < 4; ++cc){
                float wv = Wl1_i[(size_t)(c0+cc)*NHH + j];
                #pragma unroll
                for (int p = 0; p < NO; ++p) acc[p] += syv[p][cc]*wv;
            }
        }
        #pragma unroll
        for (int p = 0; p < NO; ++p) sU[p*NHH + j] = gelu_f(acc[p]);
    }
    __syncthreads();
    {
        int q = tid >> 7, c = tid & 127;
        float acc[NO];
        #pragma unroll
        for (int p = 0; p < NO; ++p) acc[p] = 0.f;
        for (int j0 = q*128; j0 < q*128 + 128; j0 += 4){
            f32x4 uv[NO];
            #pragma unroll
            for (int p = 0; p < NO; ++p) uv[p] = *(const f32x4*)&sU[p*NHH + j0];
            #pragma unroll
            for (int jj = 0; jj < 4; ++jj){
                float wv = Wl2_i[(size_t)(j0+jj)*NH + c];
                #pragma unroll
                for (int p = 0; p < NO; ++p) acc[p] += uv[p][jj]*wv;
            }
        }
        #pragma unroll
        for (int p = 0; p < NO; ++p) sred[(q*NO + p)*NH + c] = acc[p];
    }
    __syncthreads();
    for (int e = tid; e < NO*NH; e += 512){
        int p = e >> 7, c = e & 127;
        float v = sred[(0*NO+p)*NH + c] + sred[(1*NO+p)*NH + c]
                + sred[(2*NO+p)*NH + c] + sred[(3*NO+p)*NH + c];
        size_t gi = (((size_t)b*NO + p)*NN + m)*NH + c;
        size_t ri = (size_t)b*sB + (size_t)p*sP + (size_t)m*NH + c;
        hOut[gi] = v + bl2_i[c] + hIn[ri];
    }
}

// ---------------------------------------------------------------------------
// k_readout
// ---------------------------------------------------------------------------
__global__ __launch_bounds__(1024) void k_readout(const float* __restrict__ h,
        const float* __restrict__ Wro, const float* __restrict__ bro,
        const float* __restrict__ mask, float* __restrict__ out){
    __shared__ float sw[NH];
    __shared__ float sacc[16], smsk[16];
    int tid = threadIdx.x, b = blockIdx.x;
    if (tid < NH) sw[tid] = Wro[tid];
    __syncthreads();
    float br = bro[0];
    float acc = 0.f;
    for (int e = tid; e < NN*NO; e += 1024){
        int o = e % NO, mm = e / NO;
        const float4* hp = (const float4*)(h + (((size_t)b*NO + o)*NN + mm)*NH);
        const float4* swp = (const float4*)sw;
        float dot = 0.f;
        #pragma unroll
        for (int c = 0; c < NH/4; ++c){
            float4 hv = hp[c], wv = swp[c];
            dot += hv.x*wv.x + hv.y*wv.y + hv.z*wv.z + hv.w*wv.w;
        }
        acc += (dot + br)*mask[b*NN + mm];
    }
    float msum = (tid < NN) ? mask[b*NN + tid] : 0.f;
    for (int off = 32; off; off >>= 1){
        acc  += __shfl_xor(acc,  off);
        msum += __shfl_xor(msum, off);
    }
    if ((tid & 63) == 0){ sacc[tid>>6] = acc; smsk[tid>>6] = msum; }
    __syncthreads();
    if (tid == 0){
        float a = 0.f, mm2 = 0.f;
        #pragma unroll
        for (int i = 0; i < 16; ++i){ a += sacc[i]; mm2 += smsk[i]; }
        out[b] = a/(12.0f*mm2);
    }
}

// ---------------------------------------------------------------------------
extern "C" void kernel_launch(void* const* d_in, const int* in_sizes, int n_in,
                              void* d_out, int out_size, void* d_ws, size_t ws_size,
                              hipStream_t stream){
    const float* pos  = (const float*)d_in[0];
    const float* x    = (const float*)d_in[1];
    const float* mask = (const float*)d_in[2];
    const float* W1s  = (const float*)d_in[3];
    const float* b1s  = (const float*)d_in[4];
    const float* W2s  = (const float*)d_in[5];
    const float* b2s  = (const float*)d_in[6];
    const float* W1r  = (const float*)d_in[7];
    const float* b1r  = (const float*)d_in[8];
    const float* W2r  = (const float*)d_in[9];
    const float* b2r  = (const float*)d_in[10];
    const float* We   = (const float*)d_in[11];
    const float* Wsp  = (const float*)d_in[12];
    const float* Wrot = (const float*)d_in[13];
    const float* convb= (const float*)d_in[14];
    const float* lns  = (const float*)d_in[15];
    const float* lnb  = (const float*)d_in[16];
    const float* Wl1  = (const float*)d_in[17];
    const float* bl1  = (const float*)d_in[18];
    const float* Wl2  = (const float*)d_in[19];
    const float* bl2  = (const float*)d_in[20];
    const float* Wro  = (const float*)d_in[21];
    const float* bro  = (const float*)d_in[22];

    float* ws = (float*)d_ws;
    float* ws_ori = ws;                         // 64
    float* ws_fib = ws + 64;                    // 4608
    float* ws_rot = ws + 64 + 4608;             // 36864, ends 41536
    ushort* w1ct = (ushort*)(ws + 41536);       // 4096 ushort
    ushort* w2ct = (ushort*)(ws + 43584);       // 4096 ushort
    float* hE   = ws + 45632;                   // 32768 (compact embed)
    float* hB   = hE + NB*NN*NH;                // 393216 (layer0 out)
    float* hF   = hB + NB*NO*NN*NH;             // 393216 (layer1 out)
    float* part = hF + NB*NO*NN*NH;             // NSPLIT*393216
    ushort* kb  = (ushort*)(part + NSPLIT*NB*NO*NN*NH);
    ushort* Wt  = kb + (size_t)NB*NO*NN*NN*NBD;

    k_setup<<<1, 256, 0, stream>>>(W1r, b1r, W2r, b2r, W1s, b1s, W2s,
                                   ws_ori, ws_fib, w1ct, w2ct);
    k_rot<<<NL*NO*NO*NH/256, 256, 0, stream>>>(ws_fib, Wrot, ws_rot);
    k_embed<<<NB*NN*NH/256, 256, 0, stream>>>(x, We, hE);
    k_kb<<<NB*NO*NN, 256, 0, stream>>>(pos, w1ct, w2ct, b2s, ws_ori, kb);

    // layer 0 (o-broadcast input hE: sP=0)
    k_wbuild<<<NB*NO*16, 256, 0, stream>>>(hE, Wsp, mask, Wt, NN*NH, 0);
    k_convg<<<NB*NO*2*NSPLIT, 256, 0, stream>>>(kb, Wt, part);
    k_mlp<<<NB*NN, 512, 0, stream>>>(part, hE, hB,
            ws_rot, convb, lns, lnb,
            Wl1, bl1, Wl2, bl2, NN*NH, 0);
    // layer 1
    k_wbuild<<<NB*NO*16, 256, 0, stream>>>(hB, Wsp + NBD*NH, mask, Wt,
            NO*NN*NH, NN*NH);
    k_convg<<<NB*NO*2*NSPLIT, 256, 0, stream>>>(kb, Wt, part);
    k_mlp<<<NB*NN, 512, 0, stream>>>(part, hB, hF,
            ws_rot + NO*NO*NH, convb + NH, lns + NH, lnb + NH,
            Wl1 + NH*NHH, bl1 + NHH, Wl2 + NHH*NH, bl2 + NH,
            NO*NN*NH, NN*NH);

    k_readout<<<NB, 1024, 0, stream>>>(hF, Wro, bro, mask, (float*)d_out);
}

// Round 6
// 261.178 us; speedup vs baseline: 2.3225x; 1.0664x over previous
//
#include <hip/hip_runtime.h>
#include <math.h>

#define NB 2      // batch
#define NN 128    // points
#define NO 12     // orientations
#define NIN 16
#define NH 128
#define NBD 32
#define NL 2
#define NHH 512   // WF*H
#define NSPLIT 8  // conv K-split

typedef __attribute__((ext_vector_type(8))) short bf16x8;
typedef __attribute__((ext_vector_type(4))) float f32x4;

// gelu (tanh approx) in sigmoid form, division-free
__device__ __forceinline__ float gelu_f(float x){
    float x2 = x*x;
    float t = x*(2.3022077f + 0.1029435f*x2);
    float e = __builtin_amdgcn_exp2f(t);
    float r = __builtin_amdgcn_rcpf(e + 1.0f);
    return __builtin_fmaf(-x, r, x);
}

__device__ __forceinline__ ushort f2b(float x){
    union { float f; uint u; } v; v.f = x;
    uint r = v.u + 0x7FFF + ((v.u >> 16) & 1);
    return (ushort)(r >> 16);
}

#define MFMA_BF16(A,B,C) __builtin_amdgcn_mfma_f32_16x16x32_bf16(A,B,C,0,0,0)

// ---------------------------------------------------------------------------
// k_setup: ori + w1ct/w2ct + rmask + fiber basis (MFMA) + rot kernels (MFMA)
// ---------------------------------------------------------------------------
__global__ __launch_bounds__(256) void k_setup(const float* __restrict__ W1r,
        const float* __restrict__ b1r, const float* __restrict__ W2r,
        const float* __restrict__ b2r, const float* __restrict__ W1s,
        const float* __restrict__ b1s, const float* __restrict__ W2s,
        const float* __restrict__ Wrot, const float* __restrict__ mask,
        float* __restrict__ ws_ori, float* __restrict__ ws_rot,
        float* __restrict__ ws_rmask,
        ushort* __restrict__ w1ct, ushort* __restrict__ w2ct){
    __shared__ float sori[NO*3];
    __shared__ float sb2r[NBD];
    __shared__ __align__(16) char sWT[8192];       // W2r^T bf16 swz [c32][k128]
    __shared__ __align__(16) char sHid[160*256];   // fiber hidden bf16 swz
    __shared__ __align__(16) char sFib[160*64];    // fiber bf16 swz [r][k32]
    __shared__ __align__(16) char sWrotT[2][8192]; // Wrot^T bf16 swz [c128][k32]

    int tid = threadIdx.x;
    int w = tid >> 6, lane = tid & 63, lr = lane & 15, lg = lane >> 4;

    if (tid < NO){
        float fi = (float)tid;
        float th = fmodf(3.14159265358979323846f * fi * 3.23606797749979f,
                         6.28318530717958647692f);
        float ph = acosf(1.0f - 2.0f*(fi + 0.5f)/12.0f);
        float sp = sinf(ph);
        float ox = sp*cosf(th), oy = sp*sinf(th), oz = cosf(ph);
        sori[tid*3+0]=ox; sori[tid*3+1]=oy; sori[tid*3+2]=oz;
        ws_ori[tid*3+0]=ox; ws_ori[tid*3+1]=oy; ws_ori[tid*3+2]=oz;
    }
    if (tid < NBD) sb2r[tid] = b2r[tid];
    if (tid >= 32 && tid < 32 + NB){
        int b = tid - 32;
        float s = 0.f;
        for (int mm = 0; mm < NN; ++mm) s += mask[b*NN + mm];
        ws_rmask[b] = 1.0f/(12.0f*s);
    }
    if (tid < NH){
        int c = tid;
        float r0 = b1s[c];
        float r1 = W1s[c], r2 = W1s[NH+c], r3 = W1s[2*NH+c];
        float r4 = W1s[3*NH+c] + W1s[4*NH+c];
        float r5 = W1s[5*NH+c], r6 = W1s[6*NH+c];
        float r7 = W1s[7*NH+c] + W1s[8*NH+c] + W1s[10*NH+c];
        float r8 = W1s[9*NH+c] + W1s[11*NH+c] + W1s[12*NH+c];
        float r9 = W1s[13*NH+c];
        ushort* p = w1ct + c*32;
        p[0]=f2b(r0); p[1]=f2b(r1); p[2]=f2b(r2); p[3]=f2b(r3); p[4]=f2b(r4);
        p[5]=f2b(r5); p[6]=f2b(r6); p[7]=f2b(r7); p[8]=f2b(r8); p[9]=f2b(r9);
        #pragma unroll
        for (int k = 10; k < 32; ++k) p[k] = 0;
    }
    for (int e = tid; e < NBD*NH; e += 256){
        int c = e >> 7, k = e & 127;
        w2ct[c*NH + k] = f2b(W2s[k*NBD + c]);
    }
    for (int e = tid; e < NBD*NH; e += 256){
        int c = e >> 7, k = e & 127;
        *(ushort*)(sWT + c*256 + ((k*2) ^ ((c & 7) << 4))) = f2b(W2r[k*NBD + c]);
    }
    for (int e = tid; e < 2*NH*16; e += 256){
        int i = e >> 11, c = (e >> 4) & 127, kk = e & 15;
        const float* wp = Wrot + (size_t)i*NBD*NH + c;
        uint pk = (uint)f2b(wp[(size_t)(2*kk)*NH]) | ((uint)f2b(wp[(size_t)(2*kk+1)*NH]) << 16);
        *(uint*)(sWrotT[i] + c*64 + ((kk*4) ^ ((c & 3) << 4))) = pk;
    }
    for (int e = tid; e < 16*64; e += 256){
        int row = 144 + (e >> 6), k2 = e & 63;
        *(uint*)(sHid + row*256 + ((k2*4) ^ ((row & 7) << 4))) = 0u;
    }
    for (int e = tid; e < 16*16; e += 256){
        int row = 144 + (e >> 4), k2 = e & 15;
        *(uint*)(sFib + row*64 + ((k2*4) ^ ((row & 3) << 4))) = 0u;
    }
    __syncthreads();
    for (int e = tid; e < 144*NH; e += 256){
        int t = e & 127, row = e >> 7;
        int p = row / NO, q = row - (row/NO)*NO;
        float xv = sori[p*3]*sori[q*3] + sori[p*3+1]*sori[q*3+1] + sori[p*3+2]*sori[q*3+2];
        float acc = b1r[t] + xv*(W1r[t] + xv*(W1r[NH+t] + xv*W1r[2*NH+t]));
        *(ushort*)(sHid + row*256 + ((t*2) ^ ((row & 7) << 4))) = f2b(gelu_f(acc));
    }
    __syncthreads();
    for (int tile = w; tile < 5; tile += 4){
        float bv0 = sb2r[lr], bv1 = sb2r[16 + lr];
        f32x4 acc2[2][2];
        acc2[0][0] = (f32x4){bv0,bv0,bv0,bv0}; acc2[0][1] = (f32x4){bv1,bv1,bv1,bv1};
        acc2[1][0] = acc2[0][0]; acc2[1][1] = acc2[0][1];
        #pragma unroll
        for (int kk = 0; kk < 4; ++kk){
            int kbyte = (kk*32 + lg*8)*2;
            int r0 = tile*32 + lr, r1 = r0 + 16;
            bf16x8 a0 = *(const bf16x8*)(sHid + r0*256 + (kbyte ^ ((r0 & 7) << 4)));
            bf16x8 a1 = *(const bf16x8*)(sHid + r1*256 + (kbyte ^ ((r1 & 7) << 4)));
            bf16x8 b0 = *(const bf16x8*)(sWT + lr*256 + (kbyte ^ ((lr & 7) << 4)));
            bf16x8 b1 = *(const bf16x8*)(sWT + (16+lr)*256 + (kbyte ^ ((lr & 7) << 4)));
            acc2[0][0] = MFMA_BF16(a0, b0, acc2[0][0]);
            acc2[0][1] = MFMA_BF16(a0, b1, acc2[0][1]);
            acc2[1][0] = MFMA_BF16(a1, b0, acc2[1][0]);
            acc2[1][1] = MFMA_BF16(a1, b1, acc2[1][1]);
        }
        #pragma unroll
        for (int i = 0; i < 2; ++i)
            #pragma unroll
            for (int j = 0; j < 2; ++j)
                #pragma unroll
                for (int r = 0; r < 4; ++r){
                    int row = tile*32 + i*16 + lg*4 + r, d = j*16 + lr;
                    if (row < 144)
                        *(ushort*)(sFib + row*64 + ((d*2) ^ ((row & 3) << 4)))
                            = f2b(gelu_f(acc2[i][j][r]));
                }
    }
    __syncthreads();
    for (int job = w; job < 20; job += 4){
        int i = job / 10, rt = job - (job/10)*10;
        int rA = rt*16 + lr;
        bf16x8 fa = *(const bf16x8*)(sFib + rA*64 + ((lg*16) ^ ((rA & 3) << 4)));
        #pragma unroll
        for (int j = 0; j < 8; ++j){
            int cB = j*16 + lr;
            bf16x8 fb = *(const bf16x8*)(sWrotT[i] + cB*64 + ((lg*16) ^ ((cB & 3) << 4)));
            f32x4 z = (f32x4){0.f,0.f,0.f,0.f};
            f32x4 acc = MFMA_BF16(fa, fb, z);
            #pragma unroll
            for (int r = 0; r < 4; ++r){
                int row = rt*16 + lg*4 + r;
                if (row < 144)
                    ws_rot[(size_t)i*(144*NH) + (size_t)row*NH + j*16 + lr] = acc[r];
            }
        }
    }
}

// ---------------------------------------------------------------------------
__global__ __launch_bounds__(256) void k_embed(const float* __restrict__ x,
        const float* __restrict__ We, float* __restrict__ hE){
    int g = blockIdx.x*256 + threadIdx.x;
    int c = g & 127; int n = (g >> 7) & 127; int b = g >> 14;
    const float* xp = x + ((size_t)b*NN + n)*NIN;
    float acc = 0.f;
    #pragma unroll
    for (int k = 0; k < NIN; ++k) acc += xp[k]*We[k*NH + c];
    hE[g] = acc;
}

// ---------------------------------------------------------------------------
__global__ __launch_bounds__(256) void k_kb(const float* __restrict__ pos,
        const ushort* __restrict__ w1ct, const ushort* __restrict__ w2ct,
        const float* __restrict__ b2s, const float* __restrict__ ori,
        ushort* __restrict__ kb){
    __shared__ __align__(16) char smem[49152];
    ushort* sF  = (ushort*)smem;
    char*  sWT  = smem + 8192;
    char*  sH   = smem + 16384;

    int tid = threadIdx.x;
    int bid = blockIdx.x;                 // 3072
    int m = bid & 127; int t2 = bid >> 7;
    int o = t2 % NO, b = t2 / NO;
    int w = tid >> 6, lane = tid & 63, lr = lane & 15, lg = lane >> 4;

    {
        const uint* src = (const uint*)w1ct;
        for (int e = tid; e < 2048; e += 256){
            int c = e >> 4, kk = e & 15;
            *(uint*)(sWT + c*64 + ((kk*4) ^ ((c & 3) << 4))) = src[e];
        }
    }
    if (tid < NN){
        int n = tid;
        float rx = pos[((size_t)b*NN+n)*3+0] - pos[((size_t)b*NN+m)*3+0];
        float ry = pos[((size_t)b*NN+n)*3+1] - pos[((size_t)b*NN+m)*3+1];
        float rz = pos[((size_t)b*NN+n)*3+2] - pos[((size_t)b*NN+m)*3+2];
        float ox = ori[o*3+0], oy = ori[o*3+1], oz = ori[o*3+2];
        float a  = rx*ox + ry*oy + rz*oz;
        float bb = sqrtf(rx*rx+ry*ry+rz*rz) * fabsf(1.0f - a);
        float a2 = a*a, b2 = bb*bb, ab = a*bb;
        float fv[10] = {1.0f, a, bb, a2, ab, b2, a2*a, a2*bb, a*b2, b2*bb};
        char* rowp = (char*)sF + n*64;
        int sw = (n & 3) << 4;
        #pragma unroll
        for (int kk = 0; kk < 5; ++kk){
            uint pk = (uint)f2b(fv[kk*2]) | ((uint)f2b(fv[kk*2+1]) << 16);
            *(uint*)(rowp + ((kk*4) ^ sw)) = pk;
        }
        #pragma unroll
        for (int kk = 5; kk < 16; ++kk)
            *(uint*)(rowp + ((kk*4) ^ sw)) = 0u;
    }
    __syncthreads();
    f32x4 hacc[2][8];
    {
        int rA0 = w*32 + lr, rA1 = rA0 + 16;
        bf16x8 fa0 = *(const bf16x8*)((char*)sF + rA0*64 + ((lg*16) ^ ((rA0 & 3) << 4)));
        bf16x8 fa1 = *(const bf16x8*)((char*)sF + rA1*64 + ((lg*16) ^ ((rA1 & 3) << 4)));
        #pragma unroll
        for (int j = 0; j < 8; ++j){
            int cB = j*16 + lr;
            bf16x8 fb = *(const bf16x8*)(sWT + cB*64 + ((lg*16) ^ ((cB & 3) << 4)));
            f32x4 z = (f32x4){0.f,0.f,0.f,0.f};
            hacc[0][j] = MFMA_BF16(fa0, fb, z);
            hacc[1][j] = MFMA_BF16(fa1, fb, z);
        }
    }
    #pragma unroll
    for (int i = 0; i < 2; ++i)
        #pragma unroll
        for (int j = 0; j < 8; ++j)
            #pragma unroll
            for (int r = 0; r < 4; ++r){
                int n = w*32 + i*16 + lg*4 + r;
                int c = j*16 + lr;
                *(ushort*)(sH + n*256 + ((c*2) ^ ((n & 7) << 4))) = f2b(gelu_f(hacc[i][j][r]));
            }
    __syncthreads();
    {
        const uint* src = (const uint*)w2ct;
        for (int e = tid; e < 2048; e += 256){
            int c = e >> 6, kk = e & 63;
            *(uint*)(sWT + c*256 + ((kk*4) ^ ((c & 7) << 4))) = src[e];
        }
    }
    __syncthreads();
    float bv0 = b2s[lr], bv1 = b2s[16 + lr];
    f32x4 acc2[2][2];
    acc2[0][0] = (f32x4){bv0,bv0,bv0,bv0}; acc2[0][1] = (f32x4){bv1,bv1,bv1,bv1};
    acc2[1][0] = acc2[0][0]; acc2[1][1] = acc2[0][1];
    #pragma unroll
    for (int kk = 0; kk < 4; ++kk){
        int kbyte = (kk*32 + lg*8)*2;
        int r0 = w*32 + lr, r1 = r0 + 16;
        bf16x8 a0 = *(const bf16x8*)(sH + r0*256 + (kbyte ^ ((r0 & 7) << 4)));
        bf16x8 a1 = *(const bf16x8*)(sH + r1*256 + (kbyte ^ ((r1 & 7) << 4)));
        bf16x8 b0 = *(const bf16x8*)(sWT + lr*256 + (kbyte ^ ((lr & 7) << 4)));
        bf16x8 b1 = *(const bf16x8*)(sWT + (16+lr)*256 + (kbyte ^ ((lr & 7) << 4)));
        acc2[0][0] = MFMA_BF16(a0, b0, acc2[0][0]);
        acc2[0][1] = MFMA_BF16(a0, b1, acc2[0][1]);
        acc2[1][0] = MFMA_BF16(a1, b0, acc2[1][0]);
        acc2[1][1] = MFMA_BF16(a1, b1, acc2[1][1]);
    }
    ushort* sOut = (ushort*)smem;
    #pragma unroll
    for (int i = 0; i < 2; ++i)
        #pragma unroll
        for (int j = 0; j < 2; ++j)
            #pragma unroll
            for (int r = 0; r < 4; ++r){
                int n = w*32 + i*16 + lg*4 + r, d = j*16 + lr;
                sOut[n*NBD + d] = f2b(gelu_f(acc2[i][j][r]));
            }
    __syncthreads();
    size_t base = ((size_t)((b*NO + o)*NN + m))*(NN*NBD);
    uint4* dst = (uint4*)(kb + base);
    const uint4* src = (const uint4*)sOut;
    dst[tid] = src[tid];
    dst[256 + tid] = src[256 + tid];
}

// ---------------------------------------------------------------------------
// k_convg (fused W-build): block=(b,o,mh,s)
// ---------------------------------------------------------------------------
__global__ __launch_bounds__(256) void k_convg(const ushort* __restrict__ kb,
        const float* __restrict__ h, const float* __restrict__ wsp_i,
        const float* __restrict__ mask, float* __restrict__ part,
        int sB, int sP){
    __shared__ __align__(16) ushort sA[64*NH];
    __shared__ __align__(16) ushort sW[NH*NH];
    int tid = threadIdx.x;
    int bid = blockIdx.x;              // 384
    int s = bid & 7, mh = (bid >> 3) & 1;
    int rest = bid >> 4;
    int o = rest % NO, b = rest / NO;

    int w = tid >> 6, lane = tid & 63, lr = lane & 15, lg = lane >> 4;
    int wm = (w >> 1)*32, wc = (w & 1)*64;

    int c_w = tid & 127, kh = tid >> 7;
    float wv[NBD];
    #pragma unroll
    for (int d = 0; d < NBD; ++d) wv[d] = wsp_i[d*NH + c_w];

    const ushort* abase = kb + ((size_t)(b*NO + o)*NN + mh*64)*(NN*NBD) + s*512;
    const float* hbase = h + (size_t)b*sB + (size_t)o*sP;
    const float* mbase = mask + b*NN;

    f32x4 acc[2][4];
    #pragma unroll
    for (int i = 0; i < 2; ++i)
        #pragma unroll
        for (int j = 0; j < 4; ++j)
            acc[i][j] = (f32x4){0.f,0.f,0.f,0.f};

    for (int ch = 0; ch < 4; ++ch){
        #pragma unroll
        for (int it = 0; it < 4; ++it){
            int flat = it*256 + tid;
            int row = flat >> 4, seg = flat & 15;
            uint4 v = *(const uint4*)(abase + (size_t)row*(NN*NBD) + ch*128 + seg*8);
            *(uint4*)((char*)sA + row*256 + ((seg*16) ^ ((row & 7) << 4))) = v;
        }
        #pragma unroll
        for (int u = 0; u < 2; ++u){
            int n_loc = kh*2 + u;
            int n = s*16 + ch*4 + n_loc;
            float g = hbase[(size_t)n*NH + c_w] * mbase[n];
            #pragma unroll
            for (int q = 0; q < 4; ++q){
                uint4 v;
                v.x = (uint)f2b(g*wv[q*8+0]) | ((uint)f2b(g*wv[q*8+1]) << 16);
                v.y = (uint)f2b(g*wv[q*8+2]) | ((uint)f2b(g*wv[q*8+3]) << 16);
                v.z = (uint)f2b(g*wv[q*8+4]) | ((uint)f2b(g*wv[q*8+5]) << 16);
                v.w = (uint)f2b(g*wv[q*8+6]) | ((uint)f2b(g*wv[q*8+7]) << 16);
                int kbyte = (n_loc*32 + q*8)*2;
                *(uint4*)((char*)sW + c_w*256 + (kbyte ^ ((c_w & 7) << 4))) = v;
            }
        }
        __syncthreads();
        #pragma unroll
        for (int kk = 0; kk < 4; ++kk){
            int kbyte = (kk*32 + lg*8)*2;
            int r0 = wm + lr, r1 = wm + 16 + lr;
            bf16x8 a0 = *(const bf16x8*)((const char*)sA + r0*256 + (kbyte ^ ((r0 & 7) << 4)));
            bf16x8 a1 = *(const bf16x8*)((const char*)sA + r1*256 + (kbyte ^ ((r1 & 7) << 4)));
            bf16x8 bf[4];
            #pragma unroll
            for (int j = 0; j < 4; ++j){
                int c = wc + j*16 + lr;
                bf[j] = *(const bf16x8*)((const char*)sW + c*256 + (kbyte ^ ((c & 7) << 4)));
            }
            #pragma unroll
            for (int j = 0; j < 4; ++j){
                acc[0][j] = MFMA_BF16(a0, bf[j], acc[0][j]);
                acc[1][j] = MFMA_BF16(a1, bf[j], acc[1][j]);
            }
        }
        __syncthreads();
    }
    float* pbase = part + ((size_t)((s*NB + b)*NO + o)*NN + mh*64)*NH;
    #pragma unroll
    for (int i = 0; i < 2; ++i)
        #pragma unroll
        for (int j = 0; j < 4; ++j)
            #pragma unroll
            for (int r = 0; r < 4; ++r){
                int mm = wm + i*16 + lg*4 + r;
                int c = wc + j*16 + lr;
                pbase[(size_t)mm*NH + c] = acc[i][j][r];
            }
}

// ---------------------------------------------------------------------------
// k_mlp: reduce + rot-mix + bias + LN + MLP + residual (+fused readout)
// ---------------------------------------------------------------------------
__global__ __launch_bounds__(512) void k_mlp(const float* __restrict__ part,
        const float* __restrict__ hIn, float* __restrict__ hOut,
        const float* __restrict__ rot_i, const float* __restrict__ convb_i,
        const float* __restrict__ lns_i, const float* __restrict__ lnb_i,
        const float* __restrict__ Wl1_i, const float* __restrict__ bl1_i,
        const float* __restrict__ Wl2_i, const float* __restrict__ bl2_i,
        const float* __restrict__ Wro, const float* __restrict__ bro,
        const float* __restrict__ mask, const float* __restrict__ rmask,
        float* __restrict__ outp, int sB, int sP, int final){
    __shared__ float shcv[NO*NH];
    __shared__ float sy[NO*NH];
    __shared__ float sU[NO*NHH];
    __shared__ float sred[4*NO*NH];
    __shared__ float swred[8];
    int tid = threadIdx.x;
    int bid = blockIdx.x;
    int m = bid & 127, b = bid >> 7;
    for (int e = tid; e < NO*NH; e += 512){
        int o = e >> 7, c = e & 127;
        float sv = 0.f;
        #pragma unroll
        for (int sl = 0; sl < NSPLIT; ++sl)
            sv += part[((size_t)((sl*NB + b)*NO + o)*NN + m)*NH + c];
        shcv[e] = sv;
    }
    __syncthreads();
    for (int e = tid; e < NO*NH; e += 512){
        int p = e >> 7, c = e & 127;
        float acc = 0.f;
        #pragma unroll
        for (int o = 0; o < NO; ++o)
            acc += shcv[o*NH + c]*rot_i[(p*NO + o)*NH + c];
        sy[e] = acc*(1.0f/12.0f) + convb_i[c];
    }
    __syncthreads();
    int wid = tid >> 6, lane = tid & 63;
    for (int row = wid; row < NO; row += 8){
        float x0 = sy[row*NH + lane], x1 = sy[row*NH + 64 + lane];
        float s = x0 + x1, ss = x0*x0 + x1*x1;
        for (int off = 32; off; off >>= 1){
            s  += __shfl_xor(s,  off);
            ss += __shfl_xor(ss, off);
        }
        float mn  = s*(1.0f/128.0f);
        float var = ss*(1.0f/128.0f) - mn*mn;
        float r = rsqrtf(var + 1e-6f);
        sy[row*NH + lane]      = (x0 - mn)*r*lns_i[lane]      + lnb_i[lane];
        sy[row*NH + 64 + lane] = (x1 - mn)*r*lns_i[64 + lane] + lnb_i[64 + lane];
    }
    __syncthreads();
    {
        int j = tid;
        float acc[NO];
        float bj = bl1_i[j];
        #pragma unroll
        for (int p = 0; p < NO; ++p) acc[p] = bj;
        for (int c0 = 0; c0 < NH; c0 += 4){
            f32x4 syv[NO];
            #pragma unroll
            for (int p = 0; p < NO; ++p) syv[p] = *(const f32x4*)&sy[p*NH + c0];
            #pragma unroll
            for (int cc = 0; cc < 4; ++cc){
                float wv = Wl1_i[(size_t)(c0+cc)*NHH + j];
                #pragma unroll
                for (int p = 0; p < NO; ++p) acc[p] += syv[p][cc]*wv;
            }
        }
        #pragma unroll
        for (int p = 0; p < NO; ++p) sU[p*NHH + j] = gelu_f(acc[p]);
    }
    __syncthreads();
    {
        int q = tid >> 7, c = tid & 127;
        float acc[NO];
        #pragma unroll
        for (int p = 0; p < NO; ++p) acc[p] = 0.f;
        for (int j0 = q*128; j0 < q*128 + 128; j0 += 4){
            f32x4 uv[NO];
            #pragma unroll
            for (int p = 0; p < NO; ++p) uv[p] = *(const f32x4*)&sU[p*NHH + j0];
            #pragma unroll
            for (int jj = 0; jj < 4; ++jj){
                float wv = Wl2_i[(size_t)(j0+jj)*NH + c];
                #pragma unroll
                for (int p = 0; p < NO; ++p) acc[p] += uv[p][jj]*wv;
            }
        }
        #pragma unroll
        for (int p = 0; p < NO; ++p) sred[(q*NO + p)*NH + c] = acc[p];
    }
    __syncthreads();
    float ro_part = 0.f;
    for (int e = tid; e < NO*NH; e += 512){
        int p = e >> 7, c = e & 127;
        float v = sred[(0*NO+p)*NH + c] + sred[(1*NO+p)*NH + c]
                + sred[(2*NO+p)*NH + c] + sred[(3*NO+p)*NH + c];
        size_t ri = (size_t)b*sB + (size_t)p*sP + (size_t)m*NH + c;
        float vf = v + bl2_i[c] + hIn[ri];
        if (!final){
            size_t gi = (((size_t)b*NO + p)*NN + m)*NH + c;
            hOut[gi] = vf;
        } else {
            ro_part += vf*Wro[c];
        }
    }
    if (final){
        for (int off = 32; off; off >>= 1) ro_part += __shfl_xor(ro_part, off);
        if (lane == 0) swred[wid] = ro_part;
        __syncthreads();
        if (tid == 0){
            float s = 0.f;
            #pragma unroll
            for (int i = 0; i < 8; ++i) s += swred[i];
            float contrib = (s + 12.0f*bro[0]) * mask[b*NN + m] * rmask[b];
            atomicAdd(&outp[b], contrib);
        }
    }
}

// ---------------------------------------------------------------------------
extern "C" void kernel_launch(void* const* d_in, const int* in_sizes, int n_in,
                              void* d_out, int out_size, void* d_ws, size_t ws_size,
                              hipStream_t stream){
    const float* pos  = (const float*)d_in[0];
    const float* x    = (const float*)d_in[1];
    const float* mask = (const float*)d_in[2];
    const float* W1s  = (const float*)d_in[3];
    const float* b1s  = (const float*)d_in[4];
    const float* W2s  = (const float*)d_in[5];
    const float* b2s  = (const float*)d_in[6];
    const float* W1r  = (const float*)d_in[7];
    const float* b1r  = (const float*)d_in[8];
    const float* W2r  = (const float*)d_in[9];
    const float* b2r  = (const float*)d_in[10];
    const float* We   = (const float*)d_in[11];
    const float* Wsp  = (const float*)d_in[12];
    const float* Wrot = (const float*)d_in[13];
    const float* convb= (const float*)d_in[14];
    const float* lns  = (const float*)d_in[15];
    const float* lnb  = (const float*)d_in[16];
    const float* Wl1  = (const float*)d_in[17];
    const float* bl1  = (const float*)d_in[18];
    const float* Wl2  = (const float*)d_in[19];
    const float* bl2  = (const float*)d_in[20];
    const float* Wro  = (const float*)d_in[21];
    const float* bro  = (const float*)d_in[22];

    float* ws = (float*)d_ws;
    float* ws_ori   = ws;                       // 64
    float* ws_rot   = ws + 64;                  // 2*144*128 = 36864
    float* ws_rmask = ws + 64 + 36864;          // 16
    ushort* w1ct = (ushort*)(ws + 36944);       // 4096 ushort (2048 fl)
    ushort* w2ct = (ushort*)(ws + 38992);       // 4096 ushort (2048 fl)
    float* hE   = ws + 41040;                   // 32768
    float* hB   = hE + NB*NN*NH;                // 393216
    float* part = hB + NB*NO*NN*NH;             // NSPLIT*393216
    ushort* kb  = (ushort*)(part + NSPLIT*NB*NO*NN*NH);

    hipMemsetAsync(d_out, 0, (size_t)out_size*sizeof(float), stream);

    k_setup<<<1, 256, 0, stream>>>(W1r, b1r, W2r, b2r, W1s, b1s, W2s,
                                   Wrot, mask, ws_ori, ws_rot, ws_rmask,
                                   w1ct, w2ct);
    k_embed<<<NB*NN*NH/256, 256, 0, stream>>>(x, We, hE);
    k_kb<<<NB*NO*NN, 256, 0, stream>>>(pos, w1ct, w2ct, b2s, ws_ori, kb);

    // layer 0 (o-broadcast input hE: sP=0)
    k_convg<<<NB*NO*2*NSPLIT, 256, 0, stream>>>(kb, hE, Wsp, mask, part,
            NN*NH, 0);
    k_mlp<<<NB*NN, 512, 0, stream>>>(part, hE, hB,
            ws_rot, convb, lns, lnb, Wl1, bl1, Wl2, bl2,
            Wro, bro, mask, ws_rmask, (float*)d_out, NN*NH, 0, 0);
    // layer 1 (fused readout; hOut unused)
    k_convg<<<NB*NO*2*NSPLIT, 256, 0, stream>>>(kb, hB, Wsp + NBD*NH, mask, part,
            NO*NN*NH, NN*NH);
    k_mlp<<<NB*NN, 512, 0, stream>>>(part, hB, hB,
            ws_rot + 144*NH, convb + NH, lns + NH, lnb + NH,
            Wl1 + NH*NHH, bl1 + NHH, Wl2 + NHH*NH, bl2 + NH,
            Wro, bro, mask, ws_rmask, (float*)d_out, NO*NN*NH, NN*NH, 1);
}

// Round 7
// 258.073 us; speedup vs baseline: 2.3504x; 1.0120x over previous
//
#include <hip/hip_runtime.h>
#include <math.h>

#define NB 2      // batch
#define NN 128    // points
#define NO 12     // orientations
#define NIN 16
#define NH 128
#define NBD 32
#define NL 2
#define NHH 512   // WF*H
#define NSPLIT 8  // conv K-split

typedef __attribute__((ext_vector_type(8))) short bf16x8;
typedef __attribute__((ext_vector_type(4))) float f32x4;

// gelu (tanh approx) in sigmoid form, division-free
__device__ __forceinline__ float gelu_f(float x){
    float x2 = x*x;
    float t = x*(2.3022077f + 0.1029435f*x2);
    float e = __builtin_amdgcn_exp2f(t);
    float r = __builtin_amdgcn_rcpf(e + 1.0f);
    return __builtin_fmaf(-x, r, x);
}

__device__ __forceinline__ ushort f2b(float x){
    union { float f; uint u; } v; v.f = x;
    uint r = v.u + 0x7FFF + ((v.u >> 16) & 1);
    return (ushort)(r >> 16);
}

#define MFMA_BF16(A,B,C) __builtin_amdgcn_mfma_f32_16x16x32_bf16(A,B,C,0,0,0)

// ---------------------------------------------------------------------------
// k_setup: ori + w1ct/w2ct + rmask + fiber basis (MFMA) + rot kernels (MFMA)
// ---------------------------------------------------------------------------
__global__ __launch_bounds__(256) void k_setup(const float* __restrict__ W1r,
        const float* __restrict__ b1r, const float* __restrict__ W2r,
        const float* __restrict__ b2r, const float* __restrict__ W1s,
        const float* __restrict__ b1s, const float* __restrict__ W2s,
        const float* __restrict__ Wrot, const float* __restrict__ mask,
        float* __restrict__ ws_ori, float* __restrict__ ws_rot,
        float* __restrict__ ws_rmask,
        ushort* __restrict__ w1ct, ushort* __restrict__ w2ct){
    __shared__ float sori[NO*3];
    __shared__ float sb2r[NBD];
    __shared__ __align__(16) char sWT[8192];       // W2r^T bf16 swz [c32][k128]
    __shared__ __align__(16) char sHid[160*256];   // fiber hidden bf16 swz
    __shared__ __align__(16) char sFib[160*64];    // fiber bf16 swz [r][k32]
    __shared__ __align__(16) char sWrotT[2][8192]; // Wrot^T bf16 swz [c128][k32]

    int tid = threadIdx.x;
    int w = tid >> 6, lane = tid & 63, lr = lane & 15, lg = lane >> 4;

    if (tid < NO){
        float fi = (float)tid;
        float th = fmodf(3.14159265358979323846f * fi * 3.23606797749979f,
                         6.28318530717958647692f);
        float ph = acosf(1.0f - 2.0f*(fi + 0.5f)/12.0f);
        float sp = sinf(ph);
        float ox = sp*cosf(th), oy = sp*sinf(th), oz = cosf(ph);
        sori[tid*3+0]=ox; sori[tid*3+1]=oy; sori[tid*3+2]=oz;
        ws_ori[tid*3+0]=ox; ws_ori[tid*3+1]=oy; ws_ori[tid*3+2]=oz;
    }
    if (tid < NBD) sb2r[tid] = b2r[tid];
    if (tid >= 32 && tid < 32 + NB){
        int b = tid - 32;
        float s = 0.f;
        for (int mm = 0; mm < NN; ++mm) s += mask[b*NN + mm];
        ws_rmask[b] = 1.0f/(12.0f*s);
    }
    if (tid < NH){
        int c = tid;
        float r0 = b1s[c];
        float r1 = W1s[c], r2 = W1s[NH+c], r3 = W1s[2*NH+c];
        float r4 = W1s[3*NH+c] + W1s[4*NH+c];
        float r5 = W1s[5*NH+c], r6 = W1s[6*NH+c];
        float r7 = W1s[7*NH+c] + W1s[8*NH+c] + W1s[10*NH+c];
        float r8 = W1s[9*NH+c] + W1s[11*NH+c] + W1s[12*NH+c];
        float r9 = W1s[13*NH+c];
        ushort* p = w1ct + c*32;
        p[0]=f2b(r0); p[1]=f2b(r1); p[2]=f2b(r2); p[3]=f2b(r3); p[4]=f2b(r4);
        p[5]=f2b(r5); p[6]=f2b(r6); p[7]=f2b(r7); p[8]=f2b(r8); p[9]=f2b(r9);
        #pragma unroll
        for (int k = 10; k < 32; ++k) p[k] = 0;
    }
    for (int e = tid; e < NBD*NH; e += 256){
        int c = e >> 7, k = e & 127;
        w2ct[c*NH + k] = f2b(W2s[k*NBD + c]);
    }
    for (int e = tid; e < NBD*NH; e += 256){
        int c = e >> 7, k = e & 127;
        *(ushort*)(sWT + c*256 + ((k*2) ^ ((c & 7) << 4))) = f2b(W2r[k*NBD + c]);
    }
    for (int e = tid; e < 2*NH*16; e += 256){
        int i = e >> 11, c = (e >> 4) & 127, kk = e & 15;
        const float* wp = Wrot + (size_t)i*NBD*NH + c;
        uint pk = (uint)f2b(wp[(size_t)(2*kk)*NH]) | ((uint)f2b(wp[(size_t)(2*kk+1)*NH]) << 16);
        *(uint*)(sWrotT[i] + c*64 + ((kk*4) ^ ((c & 3) << 4))) = pk;
    }
    for (int e = tid; e < 16*64; e += 256){
        int row = 144 + (e >> 6), k2 = e & 63;
        *(uint*)(sHid + row*256 + ((k2*4) ^ ((row & 7) << 4))) = 0u;
    }
    for (int e = tid; e < 16*16; e += 256){
        int row = 144 + (e >> 4), k2 = e & 15;
        *(uint*)(sFib + row*64 + ((k2*4) ^ ((row & 3) << 4))) = 0u;
    }
    __syncthreads();
    for (int e = tid; e < 144*NH; e += 256){
        int t = e & 127, row = e >> 7;
        int p = row / NO, q = row - (row/NO)*NO;
        float xv = sori[p*3]*sori[q*3] + sori[p*3+1]*sori[q*3+1] + sori[p*3+2]*sori[q*3+2];
        float acc = b1r[t] + xv*(W1r[t] + xv*(W1r[NH+t] + xv*W1r[2*NH+t]));
        *(ushort*)(sHid + row*256 + ((t*2) ^ ((row & 7) << 4))) = f2b(gelu_f(acc));
    }
    __syncthreads();
    for (int tile = w; tile < 5; tile += 4){
        float bv0 = sb2r[lr], bv1 = sb2r[16 + lr];
        f32x4 acc2[2][2];
        acc2[0][0] = (f32x4){bv0,bv0,bv0,bv0}; acc2[0][1] = (f32x4){bv1,bv1,bv1,bv1};
        acc2[1][0] = acc2[0][0]; acc2[1][1] = acc2[0][1];
        #pragma unroll
        for (int kk = 0; kk < 4; ++kk){
            int kbyte = (kk*32 + lg*8)*2;
            int r0 = tile*32 + lr, r1 = r0 + 16;
            bf16x8 a0 = *(const bf16x8*)(sHid + r0*256 + (kbyte ^ ((r0 & 7) << 4)));
            bf16x8 a1 = *(const bf16x8*)(sHid + r1*256 + (kbyte ^ ((r1 & 7) << 4)));
            bf16x8 b0 = *(const bf16x8*)(sWT + lr*256 + (kbyte ^ ((lr & 7) << 4)));
            bf16x8 b1 = *(const bf16x8*)(sWT + (16+lr)*256 + (kbyte ^ ((lr & 7) << 4)));
            acc2[0][0] = MFMA_BF16(a0, b0, acc2[0][0]);
            acc2[0][1] = MFMA_BF16(a0, b1, acc2[0][1]);
            acc2[1][0] = MFMA_BF16(a1, b0, acc2[1][0]);
            acc2[1][1] = MFMA_BF16(a1, b1, acc2[1][1]);
        }
        #pragma unroll
        for (int i = 0; i < 2; ++i)
            #pragma unroll
            for (int j = 0; j < 2; ++j)
                #pragma unroll
                for (int r = 0; r < 4; ++r){
                    int row = tile*32 + i*16 + lg*4 + r, d = j*16 + lr;
                    if (row < 144)
                        *(ushort*)(sFib + row*64 + ((d*2) ^ ((row & 3) << 4)))
                            = f2b(gelu_f(acc2[i][j][r]));
                }
    }
    __syncthreads();
    for (int job = w; job < 20; job += 4){
        int i = job / 10, rt = job - (job/10)*10;
        int rA = rt*16 + lr;
        bf16x8 fa = *(const bf16x8*)(sFib + rA*64 + ((lg*16) ^ ((rA & 3) << 4)));
        #pragma unroll
        for (int j = 0; j < 8; ++j){
            int cB = j*16 + lr;
            bf16x8 fb = *(const bf16x8*)(sWrotT[i] + cB*64 + ((lg*16) ^ ((cB & 3) << 4)));
            f32x4 z = (f32x4){0.f,0.f,0.f,0.f};
            f32x4 acc = MFMA_BF16(fa, fb, z);
            #pragma unroll
            for (int r = 0; r < 4; ++r){
                int row = rt*16 + lg*4 + r;
                if (row < 144)
                    ws_rot[(size_t)i*(144*NH) + (size_t)row*NH + j*16 + lr] = acc[r];
            }
        }
    }
}

// ---------------------------------------------------------------------------
__global__ __launch_bounds__(256) void k_embed(const float* __restrict__ x,
        const float* __restrict__ We, float* __restrict__ hE){
    int g = blockIdx.x*256 + threadIdx.x;
    int c = g & 127; int n = (g >> 7) & 127; int b = g >> 14;
    const float* xp = x + ((size_t)b*NN + n)*NIN;
    float acc = 0.f;
    #pragma unroll
    for (int k = 0; k < NIN; ++k) acc += xp[k]*We[k*NH + c];
    hE[g] = acc;
}

// ---------------------------------------------------------------------------
__global__ __launch_bounds__(256) void k_kb(const float* __restrict__ pos,
        const ushort* __restrict__ w1ct, const ushort* __restrict__ w2ct,
        const float* __restrict__ b2s, const float* __restrict__ ori,
        ushort* __restrict__ kb){
    __shared__ __align__(16) char smem[49152];
    ushort* sF  = (ushort*)smem;
    char*  sWT  = smem + 8192;
    char*  sH   = smem + 16384;

    int tid = threadIdx.x;
    int bid = blockIdx.x;                 // 3072
    int m = bid & 127; int t2 = bid >> 7;
    int o = t2 % NO, b = t2 / NO;
    int w = tid >> 6, lane = tid & 63, lr = lane & 15, lg = lane >> 4;

    {
        const uint* src = (const uint*)w1ct;
        for (int e = tid; e < 2048; e += 256){
            int c = e >> 4, kk = e & 15;
            *(uint*)(sWT + c*64 + ((kk*4) ^ ((c & 3) << 4))) = src[e];
        }
    }
    if (tid < NN){
        int n = tid;
        float rx = pos[((size_t)b*NN+n)*3+0] - pos[((size_t)b*NN+m)*3+0];
        float ry = pos[((size_t)b*NN+n)*3+1] - pos[((size_t)b*NN+m)*3+1];
        float rz = pos[((size_t)b*NN+n)*3+2] - pos[((size_t)b*NN+m)*3+2];
        float ox = ori[o*3+0], oy = ori[o*3+1], oz = ori[o*3+2];
        float a  = rx*ox + ry*oy + rz*oz;
        float bb = sqrtf(rx*rx+ry*ry+rz*rz) * fabsf(1.0f - a);
        float a2 = a*a, b2 = bb*bb, ab = a*bb;
        float fv[10] = {1.0f, a, bb, a2, ab, b2, a2*a, a2*bb, a*b2, b2*bb};
        char* rowp = (char*)sF + n*64;
        int sw = (n & 3) << 4;
        #pragma unroll
        for (int kk = 0; kk < 5; ++kk){
            uint pk = (uint)f2b(fv[kk*2]) | ((uint)f2b(fv[kk*2+1]) << 16);
            *(uint*)(rowp + ((kk*4) ^ sw)) = pk;
        }
        #pragma unroll
        for (int kk = 5; kk < 16; ++kk)
            *(uint*)(rowp + ((kk*4) ^ sw)) = 0u;
    }
    __syncthreads();
    f32x4 hacc[2][8];
    {
        int rA0 = w*32 + lr, rA1 = rA0 + 16;
        bf16x8 fa0 = *(const bf16x8*)((char*)sF + rA0*64 + ((lg*16) ^ ((rA0 & 3) << 4)));
        bf16x8 fa1 = *(const bf16x8*)((char*)sF + rA1*64 + ((lg*16) ^ ((rA1 & 3) << 4)));
        #pragma unroll
        for (int j = 0; j < 8; ++j){
            int cB = j*16 + lr;
            bf16x8 fb = *(const bf16x8*)(sWT + cB*64 + ((lg*16) ^ ((cB & 3) << 4)));
            f32x4 z = (f32x4){0.f,0.f,0.f,0.f};
            hacc[0][j] = MFMA_BF16(fa0, fb, z);
            hacc[1][j] = MFMA_BF16(fa1, fb, z);
        }
    }
    #pragma unroll
    for (int i = 0; i < 2; ++i)
        #pragma unroll
        for (int j = 0; j < 8; ++j)
            #pragma unroll
            for (int r = 0; r < 4; ++r){
                int n = w*32 + i*16 + lg*4 + r;
                int c = j*16 + lr;
                *(ushort*)(sH + n*256 + ((c*2) ^ ((n & 7) << 4))) = f2b(gelu_f(hacc[i][j][r]));
            }
    __syncthreads();
    {
        const uint* src = (const uint*)w2ct;
        for (int e = tid; e < 2048; e += 256){
            int c = e >> 6, kk = e & 63;
            *(uint*)(sWT + c*256 + ((kk*4) ^ ((c & 7) << 4))) = src[e];
        }
    }
    __syncthreads();
    float bv0 = b2s[lr], bv1 = b2s[16 + lr];
    f32x4 acc2[2][2];
    acc2[0][0] = (f32x4){bv0,bv0,bv0,bv0}; acc2[0][1] = (f32x4){bv1,bv1,bv1,bv1};
    acc2[1][0] = acc2[0][0]; acc2[1][1] = acc2[0][1];
    #pragma unroll
    for (int kk = 0; kk < 4; ++kk){
        int kbyte = (kk*32 + lg*8)*2;
        int r0 = w*32 + lr, r1 = r0 + 16;
        bf16x8 a0 = *(const bf16x8*)(sH + r0*256 + (kbyte ^ ((r0 & 7) << 4)));
        bf16x8 a1 = *(const bf16x8*)(sH + r1*256 + (kbyte ^ ((r1 & 7) << 4)));
        bf16x8 b0 = *(const bf16x8*)(sWT + lr*256 + (kbyte ^ ((lr & 7) << 4)));
        bf16x8 b1 = *(const bf16x8*)(sWT + (16+lr)*256 + (kbyte ^ ((lr & 7) << 4)));
        acc2[0][0] = MFMA_BF16(a0, b0, acc2[0][0]);
        acc2[0][1] = MFMA_BF16(a0, b1, acc2[0][1]);
        acc2[1][0] = MFMA_BF16(a1, b0, acc2[1][0]);
        acc2[1][1] = MFMA_BF16(a1, b1, acc2[1][1]);
    }
    ushort* sOut = (ushort*)smem;
    #pragma unroll
    for (int i = 0; i < 2; ++i)
        #pragma unroll
        for (int j = 0; j < 2; ++j)
            #pragma unroll
            for (int r = 0; r < 4; ++r){
                int n = w*32 + i*16 + lg*4 + r, d = j*16 + lr;
                sOut[n*NBD + d] = f2b(gelu_f(acc2[i][j][r]));
            }
    __syncthreads();
    size_t base = ((size_t)((b*NO + o)*NN + m))*(NN*NBD);
    uint4* dst = (uint4*)(kb + base);
    const uint4* src = (const uint4*)sOut;
    dst[tid] = src[tid];
    dst[256 + tid] = src[256 + tid];
}

// ---------------------------------------------------------------------------
// k_convg (fused W-build, atomic s-reduction): block=(b,o,mh,s)
// hconv[b,o,m,c] += A[m,ks] @ W[ks,c]   (hconv pre-zeroed)
// ---------------------------------------------------------------------------
__global__ __launch_bounds__(256) void k_convg(const ushort* __restrict__ kb,
        const float* __restrict__ h, const float* __restrict__ wsp_i,
        const float* __restrict__ mask, float* __restrict__ hconv,
        int sB, int sP){
    __shared__ __align__(16) ushort sA[64*NH];
    __shared__ __align__(16) ushort sW[NH*NH];
    int tid = threadIdx.x;
    int bid = blockIdx.x;              // 384
    int s = bid & 7, mh = (bid >> 3) & 1;
    int rest = bid >> 4;
    int o = rest % NO, b = rest / NO;

    int w = tid >> 6, lane = tid & 63, lr = lane & 15, lg = lane >> 4;
    int wm = (w >> 1)*32, wc = (w & 1)*64;

    int c_w = tid & 127, kh = tid >> 7;
    float wv[NBD];
    #pragma unroll
    for (int d = 0; d < NBD; ++d) wv[d] = wsp_i[d*NH + c_w];

    const ushort* abase = kb + ((size_t)(b*NO + o)*NN + mh*64)*(NN*NBD) + s*512;
    const float* hbase = h + (size_t)b*sB + (size_t)o*sP;
    const float* mbase = mask + b*NN;

    f32x4 acc[2][4];
    #pragma unroll
    for (int i = 0; i < 2; ++i)
        #pragma unroll
        for (int j = 0; j < 4; ++j)
            acc[i][j] = (f32x4){0.f,0.f,0.f,0.f};

    for (int ch = 0; ch < 4; ++ch){
        #pragma unroll
        for (int it = 0; it < 4; ++it){
            int flat = it*256 + tid;
            int row = flat >> 4, seg = flat & 15;
            uint4 v = *(const uint4*)(abase + (size_t)row*(NN*NBD) + ch*128 + seg*8);
            *(uint4*)((char*)sA + row*256 + ((seg*16) ^ ((row & 7) << 4))) = v;
        }
        #pragma unroll
        for (int u = 0; u < 2; ++u){
            int n_loc = kh*2 + u;
            int n = s*16 + ch*4 + n_loc;
            float g = hbase[(size_t)n*NH + c_w] * mbase[n];
            #pragma unroll
            for (int q = 0; q < 4; ++q){
                uint4 v;
                v.x = (uint)f2b(g*wv[q*8+0]) | ((uint)f2b(g*wv[q*8+1]) << 16);
                v.y = (uint)f2b(g*wv[q*8+2]) | ((uint)f2b(g*wv[q*8+3]) << 16);
                v.z = (uint)f2b(g*wv[q*8+4]) | ((uint)f2b(g*wv[q*8+5]) << 16);
                v.w = (uint)f2b(g*wv[q*8+6]) | ((uint)f2b(g*wv[q*8+7]) << 16);
                int kbyte = (n_loc*32 + q*8)*2;
                *(uint4*)((char*)sW + c_w*256 + (kbyte ^ ((c_w & 7) << 4))) = v;
            }
        }
        __syncthreads();
        #pragma unroll
        for (int kk = 0; kk < 4; ++kk){
            int kbyte = (kk*32 + lg*8)*2;
            int r0 = wm + lr, r1 = wm + 16 + lr;
            bf16x8 a0 = *(const bf16x8*)((const char*)sA + r0*256 + (kbyte ^ ((r0 & 7) << 4)));
            bf16x8 a1 = *(const bf16x8*)((const char*)sA + r1*256 + (kbyte ^ ((r1 & 7) << 4)));
            bf16x8 bf[4];
            #pragma unroll
            for (int j = 0; j < 4; ++j){
                int c = wc + j*16 + lr;
                bf[j] = *(const bf16x8*)((const char*)sW + c*256 + (kbyte ^ ((c & 7) << 4)));
            }
            #pragma unroll
            for (int j = 0; j < 4; ++j){
                acc[0][j] = MFMA_BF16(a0, bf[j], acc[0][j]);
                acc[1][j] = MFMA_BF16(a1, bf[j], acc[1][j]);
            }
        }
        __syncthreads();
    }
    float* obase = hconv + ((size_t)(b*NO + o)*NN + mh*64)*NH;
    #pragma unroll
    for (int i = 0; i < 2; ++i)
        #pragma unroll
        for (int j = 0; j < 4; ++j)
            #pragma unroll
            for (int r = 0; r < 4; ++r){
                int mm = wm + i*16 + lg*4 + r;
                int c = wc + j*16 + lr;
                atomicAdd(&obase[(size_t)mm*NH + c], acc[i][j][r]);
            }
}

// ---------------------------------------------------------------------------
// k_mlp (1024 thr): rot-mix + bias + LN + MLP + residual (+fused readout)
// hconv is pre-reduced (no NSPLIT dim).
// ---------------------------------------------------------------------------
__global__ __launch_bounds__(1024) void k_mlp(const float* __restrict__ hconv,
        const float* __restrict__ hIn, float* __restrict__ hOut,
        const float* __restrict__ rot_i, const float* __restrict__ convb_i,
        const float* __restrict__ lns_i, const float* __restrict__ lnb_i,
        const float* __restrict__ Wl1_i, const float* __restrict__ bl1_i,
        const float* __restrict__ Wl2_i, const float* __restrict__ bl2_i,
        const float* __restrict__ Wro, const float* __restrict__ bro,
        const float* __restrict__ mask, const float* __restrict__ rmask,
        float* __restrict__ outp, int sB, int sP, int final){
    __shared__ float shcv[NO*NH];       // 6KB
    __shared__ float sy[NO*NH];         // 6KB
    __shared__ float sU[NO*NHH];        // 24KB
    __shared__ float sred[4*NO*NH];     // 24KB
    __shared__ float swred[16];
    int tid = threadIdx.x;
    int bid = blockIdx.x;
    int m = bid & 127, b = bid >> 7;
    int wid = tid >> 6, lane = tid & 63;

    // load pre-reduced conv output, float4
    if (tid < NO*NH/4){
        int o = tid >> 5, c4 = tid & 31;
        ((f32x4*)shcv)[tid] =
            ((const f32x4*)hconv)[((size_t)(b*NO + o)*NN + m)*(NH/4) + c4];
    }
    __syncthreads();
    // rot-mix + conv bias (float4)
    if (tid < NO*NH/4){
        int p = tid >> 5, c4 = tid & 31;
        f32x4 acc = (f32x4){0.f,0.f,0.f,0.f};
        #pragma unroll
        for (int o = 0; o < NO; ++o){
            f32x4 hv = ((const f32x4*)shcv)[o*(NH/4) + c4];
            f32x4 rv = ((const f32x4*)rot_i)[(p*NO + o)*(NH/4) + c4];
            acc += hv*rv;
        }
        f32x4 cb = ((const f32x4*)convb_i)[c4];
        ((f32x4*)sy)[tid] = acc*(1.0f/12.0f) + cb;
    }
    __syncthreads();
    // layernorm (waves 0..11, one row each)
    if (wid < NO){
        int row = wid;
        float x0 = sy[row*NH + lane], x1 = sy[row*NH + 64 + lane];
        float s = x0 + x1, ss = x0*x0 + x1*x1;
        for (int off = 32; off; off >>= 1){
            s  += __shfl_xor(s,  off);
            ss += __shfl_xor(ss, off);
        }
        float mn  = s*(1.0f/128.0f);
        float var = ss*(1.0f/128.0f) - mn*mn;
        float r = rsqrtf(var + 1e-6f);
        sy[row*NH + lane]      = (x0 - mn)*r*lns_i[lane]      + lnb_i[lane];
        sy[row*NH + 64 + lane] = (x1 - mn)*r*lns_i[64 + lane] + lnb_i[64 + lane];
    }
    __syncthreads();
    // layer1: thread (j, p-half); 6 rows each
    {
        int j = tid & 511, ph = tid >> 9;
        int p0 = ph*6;
        float acc[6];
        float bj = bl1_i[j];
        #pragma unroll
        for (int p = 0; p < 6; ++p) acc[p] = bj;
        for (int c0 = 0; c0 < NH; c0 += 4){
            f32x4 syv[6];
            #pragma unroll
            for (int p = 0; p < 6; ++p)
                syv[p] = *(const f32x4*)&sy[(p0 + p)*NH + c0];
            #pragma unroll
            for (int cc = 0; cc < 4; ++cc){
                float wv = Wl1_i[(size_t)(c0+cc)*NHH + j];
                #pragma unroll
                for (int p = 0; p < 6; ++p) acc[p] += syv[p][cc]*wv;
            }
        }
        #pragma unroll
        for (int p = 0; p < 6; ++p) sU[(p0 + p)*NHH + j] = gelu_f(acc[p]);
    }
    __syncthreads();
    // layer2: 8 j-slices of 64; two-step sred reduce
    {
        int q = tid >> 7, c = tid & 127;
        float acc[NO];
        #pragma unroll
        for (int p = 0; p < NO; ++p) acc[p] = 0.f;
        for (int j0 = q*64; j0 < q*64 + 64; j0 += 4){
            f32x4 uv[NO];
            #pragma unroll
            for (int p = 0; p < NO; ++p) uv[p] = *(const f32x4*)&sU[p*NHH + j0];
            #pragma unroll
            for (int jj = 0; jj < 4; ++jj){
                float wv = Wl2_i[(size_t)(j0+jj)*NH + c];
                #pragma unroll
                for (int p = 0; p < NO; ++p) acc[p] += uv[p][jj]*wv;
            }
        }
        if (q >= 4){
            #pragma unroll
            for (int p = 0; p < NO; ++p) sred[((q-4)*NO + p)*NH + c] = acc[p];
        }
        __syncthreads();
        if (q < 4){
            #pragma unroll
            for (int p = 0; p < NO; ++p) sred[(q*NO + p)*NH + c] += acc[p];
        }
    }
    __syncthreads();
    // final: residual + store or fused readout
    float ro_part = 0.f;
    if (tid < NO*NH/4){
        int p = tid >> 5, c4 = tid & 31;
        f32x4 v = ((const f32x4*)sred)[(0*NO + p)*(NH/4) + c4]
                + ((const f32x4*)sred)[(1*NO + p)*(NH/4) + c4]
                + ((const f32x4*)sred)[(2*NO + p)*(NH/4) + c4]
                + ((const f32x4*)sred)[(3*NO + p)*(NH/4) + c4];
        f32x4 bv = ((const f32x4*)bl2_i)[c4];
        size_t ri4 = ((size_t)b*sB + (size_t)p*sP + (size_t)m*NH)/4 + c4;
        f32x4 hv = ((const f32x4*)hIn)[ri4];
        f32x4 vf = v + bv + hv;
        if (!final){
            size_t gi4 = (((size_t)b*NO + p)*NN + m)*(NH/4) + c4;
            ((f32x4*)hOut)[gi4] = vf;
        } else {
            f32x4 wr = ((const f32x4*)Wro)[c4];
            ro_part = vf.x*wr.x + vf.y*wr.y + vf.z*wr.z + vf.w*wr.w;
        }
    }
    if (final){
        for (int off = 32; off; off >>= 1) ro_part += __shfl_xor(ro_part, off);
        if (lane == 0) swred[wid] = ro_part;
        __syncthreads();
        if (tid == 0){
            float s = 0.f;
            #pragma unroll
            for (int i = 0; i < 16; ++i) s += swred[i];
            float contrib = (s + 12.0f*bro[0]) * mask[b*NN + m] * rmask[b];
            atomicAdd(&outp[b], contrib);
        }
    }
}

// ---------------------------------------------------------------------------
extern "C" void kernel_launch(void* const* d_in, const int* in_sizes, int n_in,
                              void* d_out, int out_size, void* d_ws, size_t ws_size,
                              hipStream_t stream){
    const float* pos  = (const float*)d_in[0];
    const float* x    = (const float*)d_in[1];
    const float* mask = (const float*)d_in[2];
    const float* W1s  = (const float*)d_in[3];
    const float* b1s  = (const float*)d_in[4];
    const float* W2s  = (const float*)d_in[5];
    const float* b2s  = (const float*)d_in[6];
    const float* W1r  = (const float*)d_in[7];
    const float* b1r  = (const float*)d_in[8];
    const float* W2r  = (const float*)d_in[9];
    const float* b2r  = (const float*)d_in[10];
    const float* We   = (const float*)d_in[11];
    const float* Wsp  = (const float*)d_in[12];
    const float* Wrot = (const float*)d_in[13];
    const float* convb= (const float*)d_in[14];
    const float* lns  = (const float*)d_in[15];
    const float* lnb  = (const float*)d_in[16];
    const float* Wl1  = (const float*)d_in[17];
    const float* bl1  = (const float*)d_in[18];
    const float* Wl2  = (const float*)d_in[19];
    const float* bl2  = (const float*)d_in[20];
    const float* Wro  = (const float*)d_in[21];
    const float* bro  = (const float*)d_in[22];

    float* ws = (float*)d_ws;
    float* ws_ori   = ws;                       // 64
    float* ws_rot   = ws + 64;                  // 2*144*128 = 36864
    float* ws_rmask = ws + 64 + 36864;          // 16
    ushort* w1ct = (ushort*)(ws + 36944);       // 4096 ushort (2048 fl)
    ushort* w2ct = (ushort*)(ws + 38992);       // 4096 ushort (2048 fl)
    float* hE    = ws + 41040;                  // 32768
    float* hB    = hE + NB*NN*NH;               // 393216
    float* hconv = hB + NB*NO*NN*NH;            // 393216
    ushort* kb   = (ushort*)(hconv + NB*NO*NN*NH);

    hipMemsetAsync(d_out, 0, (size_t)out_size*sizeof(float), stream);

    k_setup<<<1, 256, 0, stream>>>(W1r, b1r, W2r, b2r, W1s, b1s, W2s,
                                   Wrot, mask, ws_ori, ws_rot, ws_rmask,
                                   w1ct, w2ct);
    k_embed<<<NB*NN*NH/256, 256, 0, stream>>>(x, We, hE);
    k_kb<<<NB*NO*NN, 256, 0, stream>>>(pos, w1ct, w2ct, b2s, ws_ori, kb);

    // layer 0 (o-broadcast input hE: sP=0)
    hipMemsetAsync(hconv, 0, (size_t)NB*NO*NN*NH*sizeof(float), stream);
    k_convg<<<NB*NO*2*NSPLIT, 256, 0, stream>>>(kb, hE, Wsp, mask, hconv,
            NN*NH, 0);
    k_mlp<<<NB*NN, 1024, 0, stream>>>(hconv, hE, hB,
            ws_rot, convb, lns, lnb, Wl1, bl1, Wl2, bl2,
            Wro, bro, mask, ws_rmask, (float*)d_out, NN*NH, 0, 0);
    // layer 1 (fused readout)
    hipMemsetAsync(hconv, 0, (size_t)NB*NO*NN*NH*sizeof(float), stream);
    k_convg<<<NB*NO*2*NSPLIT, 256, 0, stream>>>(kb, hB, Wsp + NBD*NH, mask, hconv,
            NO*NN*NH, NN*NH);
    k_mlp<<<NB*NN, 1024, 0, stream>>>(hconv, hB, hB,
            ws_rot + 144*NH, convb + NH, lns + NH, lnb + NH,
            Wl1 + NH*NHH, bl1 + NHH, Wl2 + NHH*NH, bl2 + NH,
            Wro, bro, mask, ws_rmask, (float*)d_out, NO*NN*NH, NN*NH, 1);
}

// Round 11
// 244.608 us; speedup vs baseline: 2.4798x; 1.0551x over previous
//
#include <hip/hip_runtime.h>
#include <math.h>

#define NB 2      // batch
#define NN 128    // points
#define NO 12     // orientations
#define NIN 16
#define NH 128
#define NBD 32
#define NL 2
#define NHH 512   // WF*H
#define NSPLIT 8  // conv K-split

typedef __attribute__((ext_vector_type(8))) short bf16x8;
typedef __attribute__((ext_vector_type(4))) float f32x4;

// gelu (tanh approx) in sigmoid form, division-free
__device__ __forceinline__ float gelu_f(float x){
    float x2 = x*x;
    float t = x*(2.3022077f + 0.1029435f*x2);
    float e = __builtin_amdgcn_exp2f(t);
    float r = __builtin_amdgcn_rcpf(e + 1.0f);
    return __builtin_fmaf(-x, r, x);
}

__device__ __forceinline__ ushort f2b(float x){
    union { float f; uint u; } v; v.f = x;
    uint r = v.u + 0x7FFF + ((v.u >> 16) & 1);
    return (ushort)(r >> 16);
}

#define MFMA_BF16(A,B,C) __builtin_amdgcn_mfma_f32_16x16x32_bf16(A,B,C,0,0,0)

// ---------------------------------------------------------------------------
// k_setup: ori + w1ct/w2ct + rmask + fiber basis (MFMA) + rot kernels (MFMA)
// ---------------------------------------------------------------------------
__global__ __launch_bounds__(256) void k_setup(const float* __restrict__ W1r,
        const float* __restrict__ b1r, const float* __restrict__ W2r,
        const float* __restrict__ b2r, const float* __restrict__ W1s,
        const float* __restrict__ b1s, const float* __restrict__ W2s,
        const float* __restrict__ Wrot, const float* __restrict__ mask,
        float* __restrict__ ws_ori, float* __restrict__ ws_rot,
        float* __restrict__ ws_rmask,
        ushort* __restrict__ w1ct, ushort* __restrict__ w2ct){
    __shared__ float sori[NO*3];
    __shared__ float sb2r[NBD];
    __shared__ __align__(16) char sWT[8192];       // W2r^T bf16 swz [c32][k128]
    __shared__ __align__(16) char sHid[160*256];   // fiber hidden bf16 swz
    __shared__ __align__(16) char sFib[160*64];    // fiber bf16 swz [r][k32]
    __shared__ __align__(16) char sWrotT[2][8192]; // Wrot^T bf16 swz [c128][k32]

    int tid = threadIdx.x;
    int w = tid >> 6, lane = tid & 63, lr = lane & 15, lg = lane >> 4;

    if (tid < NO){
        float fi = (float)tid;
        float th = fmodf(3.14159265358979323846f * fi * 3.23606797749979f,
                         6.28318530717958647692f);
        float ph = acosf(1.0f - 2.0f*(fi + 0.5f)/12.0f);
        float sp = sinf(ph);
        float ox = sp*cosf(th), oy = sp*sinf(th), oz = cosf(ph);
        sori[tid*3+0]=ox; sori[tid*3+1]=oy; sori[tid*3+2]=oz;
        ws_ori[tid*3+0]=ox; ws_ori[tid*3+1]=oy; ws_ori[tid*3+2]=oz;
    }
    if (tid < NBD) sb2r[tid] = b2r[tid];
    if (tid >= 32 && tid < 32 + NB){
        int b = tid - 32;
        float s = 0.f;
        for (int mm = 0; mm < NN; ++mm) s += mask[b*NN + mm];
        ws_rmask[b] = 1.0f/(12.0f*s);
    }
    if (tid < NH){
        int c = tid;
        float r0 = b1s[c];
        float r1 = W1s[c], r2 = W1s[NH+c], r3 = W1s[2*NH+c];
        float r4 = W1s[3*NH+c] + W1s[4*NH+c];
        float r5 = W1s[5*NH+c], r6 = W1s[6*NH+c];
        float r7 = W1s[7*NH+c] + W1s[8*NH+c] + W1s[10*NH+c];
        float r8 = W1s[9*NH+c] + W1s[11*NH+c] + W1s[12*NH+c];
        float r9 = W1s[13*NH+c];
        ushort* p = w1ct + c*32;
        p[0]=f2b(r0); p[1]=f2b(r1); p[2]=f2b(r2); p[3]=f2b(r3); p[4]=f2b(r4);
        p[5]=f2b(r5); p[6]=f2b(r6); p[7]=f2b(r7); p[8]=f2b(r8); p[9]=f2b(r9);
        #pragma unroll
        for (int k = 10; k < 32; ++k) p[k] = 0;
    }
    for (int e = tid; e < NBD*NH; e += 256){
        int c = e >> 7, k = e & 127;
        w2ct[c*NH + k] = f2b(W2s[k*NBD + c]);
    }
    for (int e = tid; e < NBD*NH; e += 256){
        int c = e >> 7, k = e & 127;
        *(ushort*)(sWT + c*256 + ((k*2) ^ ((c & 7) << 4))) = f2b(W2r[k*NBD + c]);
    }
    for (int e = tid; e < 2*NH*16; e += 256){
        int i = e >> 11, c = (e >> 4) & 127, kk = e & 15;
        const float* wp = Wrot + (size_t)i*NBD*NH + c;
        uint pk = (uint)f2b(wp[(size_t)(2*kk)*NH]) | ((uint)f2b(wp[(size_t)(2*kk+1)*NH]) << 16);
        *(uint*)(sWrotT[i] + c*64 + ((kk*4) ^ ((c & 3) << 4))) = pk;
    }
    for (int e = tid; e < 16*64; e += 256){
        int row = 144 + (e >> 6), k2 = e & 63;
        *(uint*)(sHid + row*256 + ((k2*4) ^ ((row & 7) << 4))) = 0u;
    }
    for (int e = tid; e < 16*16; e += 256){
        int row = 144 + (e >> 4), k2 = e & 15;
        *(uint*)(sFib + row*64 + ((k2*4) ^ ((row & 3) << 4))) = 0u;
    }
    __syncthreads();
    for (int e = tid; e < 144*NH; e += 256){
        int t = e & 127, row = e >> 7;
        int p = row / NO, q = row - (row/NO)*NO;
        float xv = sori[p*3]*sori[q*3] + sori[p*3+1]*sori[q*3+1] + sori[p*3+2]*sori[q*3+2];
        float acc = b1r[t] + xv*(W1r[t] + xv*(W1r[NH+t] + xv*W1r[2*NH+t]));
        *(ushort*)(sHid + row*256 + ((t*2) ^ ((row & 7) << 4))) = f2b(gelu_f(acc));
    }
    __syncthreads();
    for (int tile = w; tile < 5; tile += 4){
        float bv0 = sb2r[lr], bv1 = sb2r[16 + lr];
        f32x4 acc2[2][2];
        acc2[0][0] = (f32x4){bv0,bv0,bv0,bv0}; acc2[0][1] = (f32x4){bv1,bv1,bv1,bv1};
        acc2[1][0] = acc2[0][0]; acc2[1][1] = acc2[0][1];
        #pragma unroll
        for (int kk = 0; kk < 4; ++kk){
            int kbyte = (kk*32 + lg*8)*2;
            int r0 = tile*32 + lr, r1 = r0 + 16;
            bf16x8 a0 = *(const bf16x8*)(sHid + r0*256 + (kbyte ^ ((r0 & 7) << 4)));
            bf16x8 a1 = *(const bf16x8*)(sHid + r1*256 + (kbyte ^ ((r1 & 7) << 4)));
            bf16x8 b0 = *(const bf16x8*)(sWT + lr*256 + (kbyte ^ ((lr & 7) << 4)));
            bf16x8 b1 = *(const bf16x8*)(sWT + (16+lr)*256 + (kbyte ^ ((lr & 7) << 4)));
            acc2[0][0] = MFMA_BF16(a0, b0, acc2[0][0]);
            acc2[0][1] = MFMA_BF16(a0, b1, acc2[0][1]);
            acc2[1][0] = MFMA_BF16(a1, b0, acc2[1][0]);
            acc2[1][1] = MFMA_BF16(a1, b1, acc2[1][1]);
        }
        #pragma unroll
        for (int i = 0; i < 2; ++i)
            #pragma unroll
            for (int j = 0; j < 2; ++j)
                #pragma unroll
                for (int r = 0; r < 4; ++r){
                    int row = tile*32 + i*16 + lg*4 + r, d = j*16 + lr;
                    if (row < 144)
                        *(ushort*)(sFib + row*64 + ((d*2) ^ ((row & 3) << 4)))
                            = f2b(gelu_f(acc2[i][j][r]));
                }
    }
    __syncthreads();
    for (int job = w; job < 20; job += 4){
        int i = job / 10, rt = job - (job/10)*10;
        int rA = rt*16 + lr;
        bf16x8 fa = *(const bf16x8*)(sFib + rA*64 + ((lg*16) ^ ((rA & 3) << 4)));
        #pragma unroll
        for (int j = 0; j < 8; ++j){
            int cB = j*16 + lr;
            bf16x8 fb = *(const bf16x8*)(sWrotT[i] + cB*64 + ((lg*16) ^ ((cB & 3) << 4)));
            f32x4 z = (f32x4){0.f,0.f,0.f,0.f};
            f32x4 acc = MFMA_BF16(fa, fb, z);
            #pragma unroll
            for (int r = 0; r < 4; ++r){
                int row = rt*16 + lg*4 + r;
                if (row < 144)
                    ws_rot[(size_t)i*(144*NH) + (size_t)row*NH + j*16 + lr] = acc[r];
            }
        }
    }
}

// ---------------------------------------------------------------------------
__global__ __launch_bounds__(256) void k_embed(const float* __restrict__ x,
        const float* __restrict__ We, float* __restrict__ hE){
    int g = blockIdx.x*256 + threadIdx.x;
    int c = g & 127; int n = (g >> 7) & 127; int b = g >> 14;
    const float* xp = x + ((size_t)b*NN + n)*NIN;
    float acc = 0.f;
    #pragma unroll
    for (int k = 0; k < NIN; ++k) acc += xp[k]*We[k*NH + c];
    hE[g] = acc;
}

// ---------------------------------------------------------------------------
__global__ __launch_bounds__(256) void k_kb(const float* __restrict__ pos,
        const ushort* __restrict__ w1ct, const ushort* __restrict__ w2ct,
        const float* __restrict__ b2s, const float* __restrict__ ori,
        ushort* __restrict__ kb){
    __shared__ __align__(16) char smem[49152];
    ushort* sF  = (ushort*)smem;
    char*  sWT  = smem + 8192;
    char*  sH   = smem + 16384;

    int tid = threadIdx.x;
    int bid = blockIdx.x;                 // 3072
    int m = bid & 127; int t2 = bid >> 7;
    int o = t2 % NO, b = t2 / NO;
    int w = tid >> 6, lane = tid & 63, lr = lane & 15, lg = lane >> 4;

    {
        const uint* src = (const uint*)w1ct;
        for (int e = tid; e < 2048; e += 256){
            int c = e >> 4, kk = e & 15;
            *(uint*)(sWT + c*64 + ((kk*4) ^ ((c & 3) << 4))) = src[e];
        }
    }
    if (tid < NN){
        int n = tid;
        float rx = pos[((size_t)b*NN+n)*3+0] - pos[((size_t)b*NN+m)*3+0];
        float ry = pos[((size_t)b*NN+n)*3+1] - pos[((size_t)b*NN+m)*3+1];
        float rz = pos[((size_t)b*NN+n)*3+2] - pos[((size_t)b*NN+m)*3+2];
        float ox = ori[o*3+0], oy = ori[o*3+1], oz = ori[o*3+2];
        float a  = rx*ox + ry*oy + rz*oz;
        float bb = sqrtf(rx*rx+ry*ry+rz*rz) * fabsf(1.0f - a);
        float a2 = a*a, b2 = bb*bb, ab = a*bb;
        float fv[10] = {1.0f, a, bb, a2, ab, b2, a2*a, a2*bb, a*b2, b2*bb};
        char* rowp = (char*)sF + n*64;
        int sw = (n & 3) << 4;
        #pragma unroll
        for (int kk = 0; kk < 5; ++kk){
            uint pk = (uint)f2b(fv[kk*2]) | ((uint)f2b(fv[kk*2+1]) << 16);
            *(uint*)(rowp + ((kk*4) ^ sw)) = pk;
        }
        #pragma unroll
        for (int kk = 5; kk < 16; ++kk)
            *(uint*)(rowp + ((kk*4) ^ sw)) = 0u;
    }
    __syncthreads();
    f32x4 hacc[2][8];
    {
        int rA0 = w*32 + lr, rA1 = rA0 + 16;
        bf16x8 fa0 = *(const bf16x8*)((char*)sF + rA0*64 + ((lg*16) ^ ((rA0 & 3) << 4)));
        bf16x8 fa1 = *(const bf16x8*)((char*)sF + rA1*64 + ((lg*16) ^ ((rA1 & 3) << 4)));
        #pragma unroll
        for (int j = 0; j < 8; ++j){
            int cB = j*16 + lr;
            bf16x8 fb = *(const bf16x8*)(sWT + cB*64 + ((lg*16) ^ ((cB & 3) << 4)));
            f32x4 z = (f32x4){0.f,0.f,0.f,0.f};
            hacc[0][j] = MFMA_BF16(fa0, fb, z);
            hacc[1][j] = MFMA_BF16(fa1, fb, z);
        }
    }
    #pragma unroll
    for (int i = 0; i < 2; ++i)
        #pragma unroll
        for (int j = 0; j < 8; ++j)
            #pragma unroll
            for (int r = 0; r < 4; ++r){
                int n = w*32 + i*16 + lg*4 + r;
                int c = j*16 + lr;
                *(ushort*)(sH + n*256 + ((c*2) ^ ((n & 7) << 4))) = f2b(gelu_f(hacc[i][j][r]));
            }
    __syncthreads();
    {
        const uint* src = (const uint*)w2ct;
        for (int e = tid; e < 2048; e += 256){
            int c = e >> 6, kk = e & 63;
            *(uint*)(sWT + c*256 + ((kk*4) ^ ((c & 7) << 4))) = src[e];
        }
    }
    __syncthreads();
    float bv0 = b2s[lr], bv1 = b2s[16 + lr];
    f32x4 acc2[2][2];
    acc2[0][0] = (f32x4){bv0,bv0,bv0,bv0}; acc2[0][1] = (f32x4){bv1,bv1,bv1,bv1};
    acc2[1][0] = acc2[0][0]; acc2[1][1] = acc2[0][1];
    #pragma unroll
    for (int kk = 0; kk < 4; ++kk){
        int kbyte = (kk*32 + lg*8)*2;
        int r0 = w*32 + lr, r1 = r0 + 16;
        bf16x8 a0 = *(const bf16x8*)(sH + r0*256 + (kbyte ^ ((r0 & 7) << 4)));
        bf16x8 a1 = *(const bf16x8*)(sH + r1*256 + (kbyte ^ ((r1 & 7) << 4)));
        bf16x8 b0 = *(const bf16x8*)(sWT + lr*256 + (kbyte ^ ((lr & 7) << 4)));
        bf16x8 b1 = *(const bf16x8*)(sWT + (16+lr)*256 + (kbyte ^ ((lr & 7) << 4)));
        acc2[0][0] = MFMA_BF16(a0, b0, acc2[0][0]);
        acc2[0][1] = MFMA_BF16(a0, b1, acc2[0][1]);
        acc2[1][0] = MFMA_BF16(a1, b0, acc2[1][0]);
        acc2[1][1] = MFMA_BF16(a1, b1, acc2[1][1]);
    }
    ushort* sOut = (ushort*)smem;
    #pragma unroll
    for (int i = 0; i < 2; ++i)
        #pragma unroll
        for (int j = 0; j < 2; ++j)
            #pragma unroll
            for (int r = 0; r < 4; ++r){
                int n = w*32 + i*16 + lg*4 + r, d = j*16 + lr;
                sOut[n*NBD + d] = f2b(gelu_f(acc2[i][j][r]));
            }
    __syncthreads();
    size_t base = ((size_t)((b*NO + o)*NN + m))*(NN*NBD);
    uint4* dst = (uint4*)(kb + base);
    const uint4* src = (const uint4*)sOut;
    dst[tid] = src[tid];
    dst[256 + tid] = src[256 + tid];
}

// ---------------------------------------------------------------------------
// k_convg (fused W-build): block=(b,o,mh,s), plain partial stores
// ---------------------------------------------------------------------------
__global__ __launch_bounds__(256) void k_convg(const ushort* __restrict__ kb,
        const float* __restrict__ h, const float* __restrict__ wsp_i,
        const float* __restrict__ mask, float* __restrict__ part,
        int sB, int sP){
    __shared__ __align__(16) ushort sA[64*NH];
    __shared__ __align__(16) ushort sW[NH*NH];
    int tid = threadIdx.x;
    int bid = blockIdx.x;              // 384
    int s = bid & 7, mh = (bid >> 3) & 1;
    int rest = bid >> 4;
    int o = rest % NO, b = rest / NO;

    int w = tid >> 6, lane = tid & 63, lr = lane & 15, lg = lane >> 4;
    int wm = (w >> 1)*32, wc = (w & 1)*64;

    int c_w = tid & 127, kh = tid >> 7;
    float wv[NBD];
    #pragma unroll
    for (int d = 0; d < NBD; ++d) wv[d] = wsp_i[d*NH + c_w];

    const ushort* abase = kb + ((size_t)(b*NO + o)*NN + mh*64)*(NN*NBD) + s*512;
    const float* hbase = h + (size_t)b*sB + (size_t)o*sP;
    const float* mbase = mask + b*NN;

    f32x4 acc[2][4];
    #pragma unroll
    for (int i = 0; i < 2; ++i)
        #pragma unroll
        for (int j = 0; j < 4; ++j)
            acc[i][j] = (f32x4){0.f,0.f,0.f,0.f};

    for (int ch = 0; ch < 4; ++ch){
        #pragma unroll
        for (int it = 0; it < 4; ++it){
            int flat = it*256 + tid;
            int row = flat >> 4, seg = flat & 15;
            uint4 v = *(const uint4*)(abase + (size_t)row*(NN*NBD) + ch*128 + seg*8);
            *(uint4*)((char*)sA + row*256 + ((seg*16) ^ ((row & 7) << 4))) = v;
        }
        #pragma unroll
        for (int u = 0; u < 2; ++u){
            int n_loc = kh*2 + u;
            int n = s*16 + ch*4 + n_loc;
            float g = hbase[(size_t)n*NH + c_w] * mbase[n];
            #pragma unroll
            for (int q = 0; q < 4; ++q){
                uint4 v;
                v.x = (uint)f2b(g*wv[q*8+0]) | ((uint)f2b(g*wv[q*8+1]) << 16);
                v.y = (uint)f2b(g*wv[q*8+2]) | ((uint)f2b(g*wv[q*8+3]) << 16);
                v.z = (uint)f2b(g*wv[q*8+4]) | ((uint)f2b(g*wv[q*8+5]) << 16);
                v.w = (uint)f2b(g*wv[q*8+6]) | ((uint)f2b(g*wv[q*8+7]) << 16);
                int kbyte = (n_loc*32 + q*8)*2;
                *(uint4*)((char*)sW + c_w*256 + (kbyte ^ ((c_w & 7) << 4))) = v;
            }
        }
        __syncthreads();
        #pragma unroll
        for (int kk = 0; kk < 4; ++kk){
            int kbyte = (kk*32 + lg*8)*2;
            int r0 = wm + lr, r1 = wm + 16 + lr;
            bf16x8 a0 = *(const bf16x8*)((const char*)sA + r0*256 + (kbyte ^ ((r0 & 7) << 4)));
            bf16x8 a1 = *(const bf16x8*)((const char*)sA + r1*256 + (kbyte ^ ((r1 & 7) << 4)));
            bf16x8 bf[4];
            #pragma unroll
            for (int j = 0; j < 4; ++j){
                int c = wc + j*16 + lr;
                bf[j] = *(const bf16x8*)((const char*)sW + c*256 + (kbyte ^ ((c & 7) << 4)));
            }
            #pragma unroll
            for (int j = 0; j < 4; ++j){
                acc[0][j] = MFMA_BF16(a0, bf[j], acc[0][j]);
                acc[1][j] = MFMA_BF16(a1, bf[j], acc[1][j]);
            }
        }
        __syncthreads();
    }
    float* pbase = part + ((size_t)((s*NB + b)*NO + o)*NN + mh*64)*NH;
    #pragma unroll
    for (int i = 0; i < 2; ++i)
        #pragma unroll
        for (int j = 0; j < 4; ++j)
            #pragma unroll
            for (int r = 0; r < 4; ++r){
                int mm = wm + i*16 + lg*4 + r;
                int c = wc + j*16 + lr;
                pbase[(size_t)mm*NH + c] = acc[i][j][r];
            }
}

// ---------------------------------------------------------------------------
// k_mlp (1024 thr): vectorized 8-slice partial reduce + rot-mix + bias + LN
// + MLP + residual (+fused readout)
// ---------------------------------------------------------------------------
__global__ __launch_bounds__(1024) void k_mlp(const float* __restrict__ part,
        const float* __restrict__ hIn, float* __restrict__ hOut,
        const float* __restrict__ rot_i, const float* __restrict__ convb_i,
        const float* __restrict__ lns_i, const float* __restrict__ lnb_i,
        const float* __restrict__ Wl1_i, const float* __restrict__ bl1_i,
        const float* __restrict__ Wl2_i, const float* __restrict__ bl2_i,
        const float* __restrict__ Wro, const float* __restrict__ bro,
        const float* __restrict__ mask, const float* __restrict__ rmask,
        float* __restrict__ outp, int sB, int sP, int final){
    __shared__ float shcv[NO*NH];       // 6KB
    __shared__ float sy[NO*NH];         // 6KB
    __shared__ float sU[NO*NHH];        // 24KB
    __shared__ float sred[4*NO*NH];     // 24KB
    __shared__ float swred[16];
    int tid = threadIdx.x;
    int bid = blockIdx.x;
    int m = bid & 127, b = bid >> 7;
    int wid = tid >> 6, lane = tid & 63;

    // reduce 8 partial slices, f32x4 coalesced
    if (tid < NO*NH/4){
        int o = tid >> 5, c4 = tid & 31;
        f32x4 sv = (f32x4){0.f,0.f,0.f,0.f};
        #pragma unroll
        for (int sl = 0; sl < NSPLIT; ++sl)
            sv += ((const f32x4*)part)[((size_t)((sl*NB + b)*NO + o)*NN + m)*(NH/4) + c4];
        ((f32x4*)shcv)[tid] = sv;
    }
    __syncthreads();
    // rot-mix + conv bias (float4)
    if (tid < NO*NH/4){
        int p = tid >> 5, c4 = tid & 31;
        f32x4 acc = (f32x4){0.f,0.f,0.f,0.f};
        #pragma unroll
        for (int o = 0; o < NO; ++o){
            f32x4 hv = ((const f32x4*)shcv)[o*(NH/4) + c4];
            f32x4 rv = ((const f32x4*)rot_i)[(p*NO + o)*(NH/4) + c4];
            acc += hv*rv;
        }
        f32x4 cb = ((const f32x4*)convb_i)[c4];
        ((f32x4*)sy)[tid] = acc*(1.0f/12.0f) + cb;
    }
    __syncthreads();
    // layernorm (waves 0..11, one row each)
    if (wid < NO){
        int row = wid;
        float x0 = sy[row*NH + lane], x1 = sy[row*NH + 64 + lane];
        float s = x0 + x1, ss = x0*x0 + x1*x1;
        for (int off = 32; off; off >>= 1){
            s  += __shfl_xor(s,  off);
            ss += __shfl_xor(ss, off);
        }
        float mn  = s*(1.0f/128.0f);
        float var = ss*(1.0f/128.0f) - mn*mn;
        float r = rsqrtf(var + 1e-6f);
        sy[row*NH + lane]      = (x0 - mn)*r*lns_i[lane]      + lnb_i[lane];
        sy[row*NH + 64 + lane] = (x1 - mn)*r*lns_i[64 + lane] + lnb_i[64 + lane];
    }
    __syncthreads();
    // layer1: thread (j, p-half); 6 rows each
    {
        int j = tid & 511, ph = tid >> 9;
        int p0 = ph*6;
        float acc[6];
        float bj = bl1_i[j];
        #pragma unroll
        for (int p = 0; p < 6; ++p) acc[p] = bj;
        for (int c0 = 0; c0 < NH; c0 += 4){
            f32x4 syv[6];
            #pragma unroll
            for (int p = 0; p < 6; ++p)
                syv[p] = *(const f32x4*)&sy[(p0 + p)*NH + c0];
            #pragma unroll
            for (int cc = 0; cc < 4; ++cc){
                float wv = Wl1_i[(size_t)(c0+cc)*NHH + j];
                #pragma unroll
                for (int p = 0; p < 6; ++p) acc[p] += syv[p][cc]*wv;
            }
        }
        #pragma unroll
        for (int p = 0; p < 6; ++p) sU[(p0 + p)*NHH + j] = gelu_f(acc[p]);
    }
    __syncthreads();
    // layer2: 8 j-slices of 64; two-step sred reduce
    {
        int q = tid >> 7, c = tid & 127;
        float acc[NO];
        #pragma unroll
        for (int p = 0; p < NO; ++p) acc[p] = 0.f;
        for (int j0 = q*64; j0 < q*64 + 64; j0 += 4){
            f32x4 uv[NO];
            #pragma unroll
            for (int p = 0; p < NO; ++p) uv[p] = *(const f32x4*)&sU[p*NHH + j0];
            #pragma unroll
            for (int jj = 0; jj < 4; ++jj){
                float wv = Wl2_i[(size_t)(j0+jj)*NH + c];
                #pragma unroll
                for (int p = 0; p < NO; ++p) acc[p] += uv[p][jj]*wv;
            }
        }
        if (q >= 4){
            #pragma unroll
            for (int p = 0; p < NO; ++p) sred[((q-4)*NO + p)*NH + c] = acc[p];
        }
        __syncthreads();
        if (q < 4){
            #pragma unroll
            for (int p = 0; p < NO; ++p) sred[(q*NO + p)*NH + c] += acc[p];
        }
    }
    __syncthreads();
    // final: residual + store or fused readout
    float ro_part = 0.f;
    if (tid < NO*NH/4){
        int p = tid >> 5, c4 = tid & 31;
        f32x4 v = ((const f32x4*)sred)[(0*NO + p)*(NH/4) + c4]
                + ((const f32x4*)sred)[(1*NO + p)*(NH/4) + c4]
                + ((const f32x4*)sred)[(2*NO + p)*(NH/4) + c4]
                + ((const f32x4*)sred)[(3*NO + p)*(NH/4) + c4];
        f32x4 bv = ((const f32x4*)bl2_i)[c4];
        size_t ri4 = ((size_t)b*sB + (size_t)p*sP + (size_t)m*NH)/4 + c4;
        f32x4 hv = ((const f32x4*)hIn)[ri4];
        f32x4 vf = v + bv + hv;
        if (!final){
            size_t gi4 = (((size_t)b*NO + p)*NN + m)*(NH/4) + c4;
            ((f32x4*)hOut)[gi4] = vf;
        } else {
            f32x4 wr = ((const f32x4*)Wro)[c4];
            ro_part = vf.x*wr.x + vf.y*wr.y + vf.z*wr.z + vf.w*wr.w;
        }
    }
    if (final){
        for (int off = 32; off; off >>= 1) ro_part += __shfl_xor(ro_part, off);
        if (lane == 0) swred[wid] = ro_part;
        __syncthreads();
        if (tid == 0){
            float s = 0.f;
            #pragma unroll
            for (int i = 0; i < 16; ++i) s += swred[i];
            float contrib = (s + 12.0f*bro[0]) * mask[b*NN + m] * rmask[b];
            atomicAdd(&outp[b], contrib);
        }
    }
}

// ---------------------------------------------------------------------------
extern "C" void kernel_launch(void* const* d_in, const int* in_sizes, int n_in,
                              void* d_out, int out_size, void* d_ws, size_t ws_size,
                              hipStream_t stream){
    const float* pos  = (const float*)d_in[0];
    const float* x    = (const float*)d_in[1];
    const float* mask = (const float*)d_in[2];
    const float* W1s  = (const float*)d_in[3];
    const float* b1s  = (const float*)d_in[4];
    const float* W2s  = (const float*)d_in[5];
    const float* b2s  = (const float*)d_in[6];
    const float* W1r  = (const float*)d_in[7];
    const float* b1r  = (const float*)d_in[8];
    const float* W2r  = (const float*)d_in[9];
    const float* b2r  = (const float*)d_in[10];
    const float* We   = (const float*)d_in[11];
    const float* Wsp  = (const float*)d_in[12];
    const float* Wrot = (const float*)d_in[13];
    const float* convb= (const float*)d_in[14];
    const float* lns  = (const float*)d_in[15];
    const float* lnb  = (const float*)d_in[16];
    const float* Wl1  = (const float*)d_in[17];
    const float* bl1  = (const float*)d_in[18];
    const float* Wl2  = (const float*)d_in[19];
    const float* bl2  = (const float*)d_in[20];
    const float* Wro  = (const float*)d_in[21];
    const float* bro  = (const float*)d_in[22];

    float* ws = (float*)d_ws;
    float* ws_ori   = ws;                       // 64
    float* ws_rot   = ws + 64;                  // 2*144*128 = 36864
    float* ws_rmask = ws + 64 + 36864;          // 16
    ushort* w1ct = (ushort*)(ws + 36944);       // 4096 ushort (2048 fl)
    ushort* w2ct = (ushort*)(ws + 38992);       // 4096 ushort (2048 fl)
    float* hE    = ws + 41040;                  // 32768
    float* hB    = hE + NB*NN*NH;               // 393216
    float* part  = hB + NB*NO*NN*NH;            // NSPLIT*393216
    ushort* kb   = (ushort*)(part + NSPLIT*NB*NO*NN*NH);

    hipMemsetAsync(d_out, 0, (size_t)out_size*sizeof(float), stream);

    k_setup<<<1, 256, 0, stream>>>(W1r, b1r, W2r, b2r, W1s, b1s, W2s,
                                   Wrot, mask, ws_ori, ws_rot, ws_rmask,
                                   w1ct, w2ct);
    k_embed<<<NB*NN*NH/256, 256, 0, stream>>>(x, We, hE);
    k_kb<<<NB*NO*NN, 256, 0, stream>>>(pos, w1ct, w2ct, b2s, ws_ori, kb);

    // layer 0 (o-broadcast input hE: sP=0)
    k_convg<<<NB*NO*2*NSPLIT, 256, 0, stream>>>(kb, hE, Wsp, mask, part,
            NN*NH, 0);
    k_mlp<<<NB*NN, 1024, 0, stream>>>(part, hE, hB,
            ws_rot, convb, lns, lnb, Wl1, bl1, Wl2, bl2,
            Wro, bro, mask, ws_rmask, (float*)d_out, NN*NH, 0, 0);
    // layer 1 (fused readout)
    k_convg<<<NB*NO*2*NSPLIT, 256, 0, stream>>>(kb, hB, Wsp + NBD*NH, mask, part,
            NO*NN*NH, NN*NH);
    k_mlp<<<NB*NN, 1024, 0, stream>>>(part, hB, hB,
            ws_rot + 144*NH, convb + NH, lns + NH, lnb + NH,
            Wl1 + NH*NHH, bl1 + NHH, Wl2 + NHH*NH, bl2 + NH,
            Wro, bro, mask, ws_rmask, (float*)d_out, NO*NN*NH, NN*NH, 1);
}

// Round 12
// 238.645 us; speedup vs baseline: 2.5418x; 1.0250x over previous
//
#include <hip/hip_runtime.h>
#include <math.h>

#define NB 2      // batch
#define NN 128    // points
#define NO 12     // orientations
#define NIN 16
#define NH 128
#define NBD 32
#define NL 2
#define NHH 512   // WF*H
#define NSPLIT 8  // conv K-split

typedef __attribute__((ext_vector_type(8))) short bf16x8;
typedef __attribute__((ext_vector_type(4))) float f32x4;

// gelu (tanh approx) in sigmoid form, division-free
__device__ __forceinline__ float gelu_f(float x){
    float x2 = x*x;
    float t = x*(2.3022077f + 0.1029435f*x2);
    float e = __builtin_amdgcn_exp2f(t);
    float r = __builtin_amdgcn_rcpf(e + 1.0f);
    return __builtin_fmaf(-x, r, x);
}

__device__ __forceinline__ ushort f2b(float x){
    union { float f; uint u; } v; v.f = x;
    uint r = v.u + 0x7FFF + ((v.u >> 16) & 1);
    return (ushort)(r >> 16);
}

// fast bf16 pair pack, round-half (2 insts/value); for LN-normalized paths
__device__ __forceinline__ uint pack2(float a, float b){
    union { float f; uint u; } ua, ub; ua.f = a; ub.f = b;
    return ((ua.u + 0x8000u) >> 16) | ((ub.u + 0x8000u) & 0xFFFF0000u);
}

#define MFMA_BF16(A,B,C) __builtin_amdgcn_mfma_f32_16x16x32_bf16(A,B,C,0,0,0)

// ---------------------------------------------------------------------------
// k_setup (block 0) + k_embed (blocks 1..128) fused; block 0 zeroes d_out
// ---------------------------------------------------------------------------
__global__ __launch_bounds__(256) void k_setup(const float* __restrict__ W1r,
        const float* __restrict__ b1r, const float* __restrict__ W2r,
        const float* __restrict__ b2r, const float* __restrict__ W1s,
        const float* __restrict__ b1s, const float* __restrict__ W2s,
        const float* __restrict__ Wrot, const float* __restrict__ mask,
        const float* __restrict__ x, const float* __restrict__ We,
        float* __restrict__ hE,
        float* __restrict__ ws_ori, float* __restrict__ ws_rot,
        float* __restrict__ ws_rmask,
        ushort* __restrict__ w1ct, ushort* __restrict__ w2ct,
        float* __restrict__ outp){
    __shared__ float sori[NO*3];
    __shared__ float sb2r[NBD];
    __shared__ __align__(16) char sWT[8192];       // W2r^T bf16 swz [c32][k128]
    __shared__ __align__(16) char sHid[160*256];   // fiber hidden bf16 swz
    __shared__ __align__(16) char sFib[160*64];    // fiber bf16 swz [r][k32]
    __shared__ __align__(16) char sWrotT[2][8192]; // Wrot^T bf16 swz [c128][k32]

    int tid = threadIdx.x;
    int bidx = blockIdx.x;

    if (bidx > 0){
        // embed: hE[b][n][c]
        int g = (bidx - 1)*256 + tid;          // 0..32767
        int c = g & 127; int n = (g >> 7) & 127; int b = g >> 14;
        const float* xp = x + ((size_t)b*NN + n)*NIN;
        float acc = 0.f;
        #pragma unroll
        for (int k = 0; k < NIN; ++k) acc += xp[k]*We[k*NH + c];
        hE[g] = acc;
        return;
    }

    int w = tid >> 6, lane = tid & 63, lr = lane & 15, lg = lane >> 4;

    if (tid < NO){
        float fi = (float)tid;
        float th = fmodf(3.14159265358979323846f * fi * 3.23606797749979f,
                         6.28318530717958647692f);
        float ph = acosf(1.0f - 2.0f*(fi + 0.5f)/12.0f);
        float sp = sinf(ph);
        float ox = sp*cosf(th), oy = sp*sinf(th), oz = cosf(ph);
        sori[tid*3+0]=ox; sori[tid*3+1]=oy; sori[tid*3+2]=oz;
        ws_ori[tid*3+0]=ox; ws_ori[tid*3+1]=oy; ws_ori[tid*3+2]=oz;
    }
    if (tid < NB) outp[tid] = 0.f;
    if (tid < NBD) sb2r[tid] = b2r[tid];
    if (tid >= 32 && tid < 32 + NB){
        int b = tid - 32;
        float s = 0.f;
        for (int mm = 0; mm < NN; ++mm) s += mask[b*NN + mm];
        ws_rmask[b] = 1.0f/(12.0f*s);
    }
    if (tid < NH){
        int c = tid;
        float r0 = b1s[c];
        float r1 = W1s[c], r2 = W1s[NH+c], r3 = W1s[2*NH+c];
        float r4 = W1s[3*NH+c] + W1s[4*NH+c];
        float r5 = W1s[5*NH+c], r6 = W1s[6*NH+c];
        float r7 = W1s[7*NH+c] + W1s[8*NH+c] + W1s[10*NH+c];
        float r8 = W1s[9*NH+c] + W1s[11*NH+c] + W1s[12*NH+c];
        float r9 = W1s[13*NH+c];
        ushort* p = w1ct + c*32;
        p[0]=f2b(r0); p[1]=f2b(r1); p[2]=f2b(r2); p[3]=f2b(r3); p[4]=f2b(r4);
        p[5]=f2b(r5); p[6]=f2b(r6); p[7]=f2b(r7); p[8]=f2b(r8); p[9]=f2b(r9);
        #pragma unroll
        for (int k = 10; k < 32; ++k) p[k] = 0;
    }
    for (int e = tid; e < NBD*NH; e += 256){
        int c = e >> 7, k = e & 127;
        w2ct[c*NH + k] = f2b(W2s[k*NBD + c]);
    }
    for (int e = tid; e < NBD*NH; e += 256){
        int c = e >> 7, k = e & 127;
        *(ushort*)(sWT + c*256 + ((k*2) ^ ((c & 7) << 4))) = f2b(W2r[k*NBD + c]);
    }
    for (int e = tid; e < 2*NH*16; e += 256){
        int i = e >> 11, c = (e >> 4) & 127, kk = e & 15;
        const float* wp = Wrot + (size_t)i*NBD*NH + c;
        uint pk = (uint)f2b(wp[(size_t)(2*kk)*NH]) | ((uint)f2b(wp[(size_t)(2*kk+1)*NH]) << 16);
        *(uint*)(sWrotT[i] + c*64 + ((kk*4) ^ ((c & 3) << 4))) = pk;
    }
    for (int e = tid; e < 16*64; e += 256){
        int row = 144 + (e >> 6), k2 = e & 63;
        *(uint*)(sHid + row*256 + ((k2*4) ^ ((row & 7) << 4))) = 0u;
    }
    for (int e = tid; e < 16*16; e += 256){
        int row = 144 + (e >> 4), k2 = e & 15;
        *(uint*)(sFib + row*64 + ((k2*4) ^ ((row & 3) << 4))) = 0u;
    }
    __syncthreads();
    for (int e = tid; e < 144*NH; e += 256){
        int t = e & 127, row = e >> 7;
        int p = row / NO, q = row - (row/NO)*NO;
        float xv = sori[p*3]*sori[q*3] + sori[p*3+1]*sori[q*3+1] + sori[p*3+2]*sori[q*3+2];
        float acc = b1r[t] + xv*(W1r[t] + xv*(W1r[NH+t] + xv*W1r[2*NH+t]));
        *(ushort*)(sHid + row*256 + ((t*2) ^ ((row & 7) << 4))) = f2b(gelu_f(acc));
    }
    __syncthreads();
    for (int tile = w; tile < 5; tile += 4){
        float bv0 = sb2r[lr], bv1 = sb2r[16 + lr];
        f32x4 acc2[2][2];
        acc2[0][0] = (f32x4){bv0,bv0,bv0,bv0}; acc2[0][1] = (f32x4){bv1,bv1,bv1,bv1};
        acc2[1][0] = acc2[0][0]; acc2[1][1] = acc2[0][1];
        #pragma unroll
        for (int kk = 0; kk < 4; ++kk){
            int kbyte = (kk*32 + lg*8)*2;
            int r0 = tile*32 + lr, r1 = r0 + 16;
            bf16x8 a0 = *(const bf16x8*)(sHid + r0*256 + (kbyte ^ ((r0 & 7) << 4)));
            bf16x8 a1 = *(const bf16x8*)(sHid + r1*256 + (kbyte ^ ((r1 & 7) << 4)));
            bf16x8 b0 = *(const bf16x8*)(sWT + lr*256 + (kbyte ^ ((lr & 7) << 4)));
            bf16x8 b1 = *(const bf16x8*)(sWT + (16+lr)*256 + (kbyte ^ ((lr & 7) << 4)));
            acc2[0][0] = MFMA_BF16(a0, b0, acc2[0][0]);
            acc2[0][1] = MFMA_BF16(a0, b1, acc2[0][1]);
            acc2[1][0] = MFMA_BF16(a1, b0, acc2[1][0]);
            acc2[1][1] = MFMA_BF16(a1, b1, acc2[1][1]);
        }
        #pragma unroll
        for (int i = 0; i < 2; ++i)
            #pragma unroll
            for (int j = 0; j < 2; ++j)
                #pragma unroll
                for (int r = 0; r < 4; ++r){
                    int row = tile*32 + i*16 + lg*4 + r, d = j*16 + lr;
                    if (row < 144)
                        *(ushort*)(sFib + row*64 + ((d*2) ^ ((row & 3) << 4)))
                            = f2b(gelu_f(acc2[i][j][r]));
                }
    }
    __syncthreads();
    for (int job = w; job < 20; job += 4){
        int i = job / 10, rt = job - (job/10)*10;
        int rA = rt*16 + lr;
        bf16x8 fa = *(const bf16x8*)(sFib + rA*64 + ((lg*16) ^ ((rA & 3) << 4)));
        #pragma unroll
        for (int j = 0; j < 8; ++j){
            int cB = j*16 + lr;
            bf16x8 fb = *(const bf16x8*)(sWrotT[i] + cB*64 + ((lg*16) ^ ((cB & 3) << 4)));
            f32x4 z = (f32x4){0.f,0.f,0.f,0.f};
            f32x4 acc = MFMA_BF16(fa, fb, z);
            #pragma unroll
            for (int r = 0; r < 4; ++r){
                int row = rt*16 + lg*4 + r;
                if (row < 144)
                    ws_rot[(size_t)i*(144*NH) + (size_t)row*NH + j*16 + lr] = acc[r];
            }
        }
    }
}

// ---------------------------------------------------------------------------
__global__ __launch_bounds__(256) void k_kb(const float* __restrict__ pos,
        const ushort* __restrict__ w1ct, const ushort* __restrict__ w2ct,
        const float* __restrict__ b2s, const float* __restrict__ ori,
        ushort* __restrict__ kb){
    __shared__ __align__(16) char smem[49152];
    ushort* sF  = (ushort*)smem;
    char*  sWT  = smem + 8192;
    char*  sH   = smem + 16384;

    int tid = threadIdx.x;
    int bid = blockIdx.x;                 // 3072
    int m = bid & 127; int t2 = bid >> 7;
    int o = t2 % NO, b = t2 / NO;
    int w = tid >> 6, lane = tid & 63, lr = lane & 15, lg = lane >> 4;

    {
        const uint* src = (const uint*)w1ct;
        for (int e = tid; e < 2048; e += 256){
            int c = e >> 4, kk = e & 15;
            *(uint*)(sWT + c*64 + ((kk*4) ^ ((c & 3) << 4))) = src[e];
        }
    }
    if (tid < NN){
        int n = tid;
        float rx = pos[((size_t)b*NN+n)*3+0] - pos[((size_t)b*NN+m)*3+0];
        float ry = pos[((size_t)b*NN+n)*3+1] - pos[((size_t)b*NN+m)*3+1];
        float rz = pos[((size_t)b*NN+n)*3+2] - pos[((size_t)b*NN+m)*3+2];
        float ox = ori[o*3+0], oy = ori[o*3+1], oz = ori[o*3+2];
        float a  = rx*ox + ry*oy + rz*oz;
        float bb = sqrtf(rx*rx+ry*ry+rz*rz) * fabsf(1.0f - a);
        float a2 = a*a, b2 = bb*bb, ab = a*bb;
        float fv[10] = {1.0f, a, bb, a2, ab, b2, a2*a, a2*bb, a*b2, b2*bb};
        char* rowp = (char*)sF + n*64;
        int sw = (n & 3) << 4;
        #pragma unroll
        for (int kk = 0; kk < 5; ++kk){
            uint pk = (uint)f2b(fv[kk*2]) | ((uint)f2b(fv[kk*2+1]) << 16);
            *(uint*)(rowp + ((kk*4) ^ sw)) = pk;
        }
        #pragma unroll
        for (int kk = 5; kk < 16; ++kk)
            *(uint*)(rowp + ((kk*4) ^ sw)) = 0u;
    }
    __syncthreads();
    f32x4 hacc[2][8];
    {
        int rA0 = w*32 + lr, rA1 = rA0 + 16;
        bf16x8 fa0 = *(const bf16x8*)((char*)sF + rA0*64 + ((lg*16) ^ ((rA0 & 3) << 4)));
        bf16x8 fa1 = *(const bf16x8*)((char*)sF + rA1*64 + ((lg*16) ^ ((rA1 & 3) << 4)));
        #pragma unroll
        for (int j = 0; j < 8; ++j){
            int cB = j*16 + lr;
            bf16x8 fb = *(const bf16x8*)(sWT + cB*64 + ((lg*16) ^ ((cB & 3) << 4)));
            f32x4 z = (f32x4){0.f,0.f,0.f,0.f};
            hacc[0][j] = MFMA_BF16(fa0, fb, z);
            hacc[1][j] = MFMA_BF16(fa1, fb, z);
        }
    }
    #pragma unroll
    for (int i = 0; i < 2; ++i)
        #pragma unroll
        for (int j = 0; j < 8; ++j)
            #pragma unroll
            for (int r = 0; r < 4; ++r){
                int n = w*32 + i*16 + lg*4 + r;
                int c = j*16 + lr;
                *(ushort*)(sH + n*256 + ((c*2) ^ ((n & 7) << 4))) = f2b(gelu_f(hacc[i][j][r]));
            }
    __syncthreads();
    {
        const uint* src = (const uint*)w2ct;
        for (int e = tid; e < 2048; e += 256){
            int c = e >> 6, kk = e & 63;
            *(uint*)(sWT + c*256 + ((kk*4) ^ ((c & 7) << 4))) = src[e];
        }
    }
    __syncthreads();
    float bv0 = b2s[lr], bv1 = b2s[16 + lr];
    f32x4 acc2[2][2];
    acc2[0][0] = (f32x4){bv0,bv0,bv0,bv0}; acc2[0][1] = (f32x4){bv1,bv1,bv1,bv1};
    acc2[1][0] = acc2[0][0]; acc2[1][1] = acc2[0][1];
    #pragma unroll
    for (int kk = 0; kk < 4; ++kk){
        int kbyte = (kk*32 + lg*8)*2;
        int r0 = w*32 + lr, r1 = r0 + 16;
        bf16x8 a0 = *(const bf16x8*)(sH + r0*256 + (kbyte ^ ((r0 & 7) << 4)));
        bf16x8 a1 = *(const bf16x8*)(sH + r1*256 + (kbyte ^ ((r1 & 7) << 4)));
        bf16x8 b0 = *(const bf16x8*)(sWT + lr*256 + (kbyte ^ ((lr & 7) << 4)));
        bf16x8 b1 = *(const bf16x8*)(sWT + (16+lr)*256 + (kbyte ^ ((lr & 7) << 4)));
        acc2[0][0] = MFMA_BF16(a0, b0, acc2[0][0]);
        acc2[0][1] = MFMA_BF16(a0, b1, acc2[0][1]);
        acc2[1][0] = MFMA_BF16(a1, b0, acc2[1][0]);
        acc2[1][1] = MFMA_BF16(a1, b1, acc2[1][1]);
    }
    ushort* sOut = (ushort*)smem;
    #pragma unroll
    for (int i = 0; i < 2; ++i)
        #pragma unroll
        for (int j = 0; j < 2; ++j)
            #pragma unroll
            for (int r = 0; r < 4; ++r){
                int n = w*32 + i*16 + lg*4 + r, d = j*16 + lr;
                sOut[n*NBD + d] = f2b(gelu_f(acc2[i][j][r]));
            }
    __syncthreads();
    size_t base = ((size_t)((b*NO + o)*NN + m))*(NN*NBD);
    uint4* dst = (uint4*)(kb + base);
    const uint4* src = (const uint4*)sOut;
    dst[tid] = src[tid];
    dst[256 + tid] = src[256 + tid];
}

// ---------------------------------------------------------------------------
// k_convg (fused W-build, fast pack): block=(b,o,mh,s), plain partial stores
// ---------------------------------------------------------------------------
__global__ __launch_bounds__(256) void k_convg(const ushort* __restrict__ kb,
        const float* __restrict__ h, const float* __restrict__ wsp_i,
        const float* __restrict__ mask, float* __restrict__ part,
        int sB, int sP){
    __shared__ __align__(16) ushort sA[64*NH];
    __shared__ __align__(16) ushort sW[NH*NH];
    int tid = threadIdx.x;
    int bid = blockIdx.x;              // 384
    int s = bid & 7, mh = (bid >> 3) & 1;
    int rest = bid >> 4;
    int o = rest % NO, b = rest / NO;

    int w = tid >> 6, lane = tid & 63, lr = lane & 15, lg = lane >> 4;
    int wm = (w >> 1)*32, wc = (w & 1)*64;

    int c_w = tid & 127, kh = tid >> 7;
    float wv[NBD];
    #pragma unroll
    for (int d = 0; d < NBD; ++d) wv[d] = wsp_i[d*NH + c_w];

    const ushort* abase = kb + ((size_t)(b*NO + o)*NN + mh*64)*(NN*NBD) + s*512;
    const float* hbase = h + (size_t)b*sB + (size_t)o*sP;
    const float* mbase = mask + b*NN;

    f32x4 acc[2][4];
    #pragma unroll
    for (int i = 0; i < 2; ++i)
        #pragma unroll
        for (int j = 0; j < 4; ++j)
            acc[i][j] = (f32x4){0.f,0.f,0.f,0.f};

    for (int ch = 0; ch < 4; ++ch){
        #pragma unroll
        for (int it = 0; it < 4; ++it){
            int flat = it*256 + tid;
            int row = flat >> 4, seg = flat & 15;
            uint4 v = *(const uint4*)(abase + (size_t)row*(NN*NBD) + ch*128 + seg*8);
            *(uint4*)((char*)sA + row*256 + ((seg*16) ^ ((row & 7) << 4))) = v;
        }
        #pragma unroll
        for (int u = 0; u < 2; ++u){
            int n_loc = kh*2 + u;
            int n = s*16 + ch*4 + n_loc;
            float g = hbase[(size_t)n*NH + c_w] * mbase[n];
            #pragma unroll
            for (int q = 0; q < 4; ++q){
                uint4 v;
                v.x = pack2(g*wv[q*8+0], g*wv[q*8+1]);
                v.y = pack2(g*wv[q*8+2], g*wv[q*8+3]);
                v.z = pack2(g*wv[q*8+4], g*wv[q*8+5]);
                v.w = pack2(g*wv[q*8+6], g*wv[q*8+7]);
                int kbyte = (n_loc*32 + q*8)*2;
                *(uint4*)((char*)sW + c_w*256 + (kbyte ^ ((c_w & 7) << 4))) = v;
            }
        }
        __syncthreads();
        #pragma unroll
        for (int kk = 0; kk < 4; ++kk){
            int kbyte = (kk*32 + lg*8)*2;
            int r0 = wm + lr, r1 = wm + 16 + lr;
            bf16x8 a0 = *(const bf16x8*)((const char*)sA + r0*256 + (kbyte ^ ((r0 & 7) << 4)));
            bf16x8 a1 = *(const bf16x8*)((const char*)sA + r1*256 + (kbyte ^ ((r1 & 7) << 4)));
            bf16x8 bf[4];
            #pragma unroll
            for (int j = 0; j < 4; ++j){
                int c = wc + j*16 + lr;
                bf[j] = *(const bf16x8*)((const char*)sW + c*256 + (kbyte ^ ((c & 7) << 4)));
            }
            #pragma unroll
            for (int j = 0; j < 4; ++j){
                acc[0][j] = MFMA_BF16(a0, bf[j], acc[0][j]);
                acc[1][j] = MFMA_BF16(a1, bf[j], acc[1][j]);
            }
        }
        __syncthreads();
    }
    float* pbase = part + ((size_t)((s*NB + b)*NO + o)*NN + mh*64)*NH;
    #pragma unroll
    for (int i = 0; i < 2; ++i)
        #pragma unroll
        for (int j = 0; j < 4; ++j)
            #pragma unroll
            for (int r = 0; r < 4; ++r){
                int mm = wm + i*16 + lg*4 + r;
                int c = wc + j*16 + lr;
                pbase[(size_t)mm*NH + c] = acc[i][j][r];
            }
}

// ---------------------------------------------------------------------------
// k_mlp (1024 thr): vectorized 8-slice partial reduce + rot-mix + bias + LN
// + MLP + residual (+fused readout)
// ---------------------------------------------------------------------------
__global__ __launch_bounds__(1024) void k_mlp(const float* __restrict__ part,
        const float* __restrict__ hIn, float* __restrict__ hOut,
        const float* __restrict__ rot_i, const float* __restrict__ convb_i,
        const float* __restrict__ lns_i, const float* __restrict__ lnb_i,
        const float* __restrict__ Wl1_i, const float* __restrict__ bl1_i,
        const float* __restrict__ Wl2_i, const float* __restrict__ bl2_i,
        const float* __restrict__ Wro, const float* __restrict__ bro,
        const float* __restrict__ mask, const float* __restrict__ rmask,
        float* __restrict__ outp, int sB, int sP, int final){
    __shared__ float shcv[NO*NH];       // 6KB
    __shared__ float sy[NO*NH];         // 6KB
    __shared__ float sU[NO*NHH];        // 24KB
    __shared__ float sred[4*NO*NH];     // 24KB
    __shared__ float swred[16];
    int tid = threadIdx.x;
    int bid = blockIdx.x;
    int m = bid & 127, b = bid >> 7;
    int wid = tid >> 6, lane = tid & 63;

    // reduce 8 partial slices, f32x4 coalesced
    if (tid < NO*NH/4){
        int o = tid >> 5, c4 = tid & 31;
        f32x4 sv = (f32x4){0.f,0.f,0.f,0.f};
        #pragma unroll
        for (int sl = 0; sl < NSPLIT; ++sl)
            sv += ((const f32x4*)part)[((size_t)((sl*NB + b)*NO + o)*NN + m)*(NH/4) + c4];
        ((f32x4*)shcv)[tid] = sv;
    }
    __syncthreads();
    // rot-mix + conv bias (float4)
    if (tid < NO*NH/4){
        int p = tid >> 5, c4 = tid & 31;
        f32x4 acc = (f32x4){0.f,0.f,0.f,0.f};
        #pragma unroll
        for (int o = 0; o < NO; ++o){
            f32x4 hv = ((const f32x4*)shcv)[o*(NH/4) + c4];
            f32x4 rv = ((const f32x4*)rot_i)[(p*NO + o)*(NH/4) + c4];
            acc += hv*rv;
        }
        f32x4 cb = ((const f32x4*)convb_i)[c4];
        ((f32x4*)sy)[tid] = acc*(1.0f/12.0f) + cb;
    }
    __syncthreads();
    // layernorm (waves 0..11, one row each)
    if (wid < NO){
        int row = wid;
        float x0 = sy[row*NH + lane], x1 = sy[row*NH + 64 + lane];
        float s = x0 + x1, ss = x0*x0 + x1*x1;
        for (int off = 32; off; off >>= 1){
            s  += __shfl_xor(s,  off);
            ss += __shfl_xor(ss, off);
        }
        float mn  = s*(1.0f/128.0f);
        float var = ss*(1.0f/128.0f) - mn*mn;
        float r = rsqrtf(var + 1e-6f);
        sy[row*NH + lane]      = (x0 - mn)*r*lns_i[lane]      + lnb_i[lane];
        sy[row*NH + 64 + lane] = (x1 - mn)*r*lns_i[64 + lane] + lnb_i[64 + lane];
    }
    __syncthreads();
    // layer1: thread (j, p-half); 6 rows each
    {
        int j = tid & 511, ph = tid >> 9;
        int p0 = ph*6;
        float acc[6];
        float bj = bl1_i[j];
        #pragma unroll
        for (int p = 0; p < 6; ++p) acc[p] = bj;
        for (int c0 = 0; c0 < NH; c0 += 4){
            f32x4 syv[6];
            #pragma unroll
            for (int p = 0; p < 6; ++p)
                syv[p] = *(const f32x4*)&sy[(p0 + p)*NH + c0];
            #pragma unroll
            for (int cc = 0; cc < 4; ++cc){
                float wv = Wl1_i[(size_t)(c0+cc)*NHH + j];
                #pragma unroll
                for (int p = 0; p < 6; ++p) acc[p] += syv[p][cc]*wv;
            }
        }
        #pragma unroll
        for (int p = 0; p < 6; ++p) sU[(p0 + p)*NHH + j] = gelu_f(acc[p]);
    }
    __syncthreads();
    // layer2: 8 j-slices of 64; two-step sred reduce
    {
        int q = tid >> 7, c = tid & 127;
        float acc[NO];
        #pragma unroll
        for (int p = 0; p < NO; ++p) acc[p] = 0.f;
        for (int j0 = q*64; j0 < q*64 + 64; j0 += 4){
            f32x4 uv[NO];
            #pragma unroll
            for (int p = 0; p < NO; ++p) uv[p] = *(const f32x4*)&sU[p*NHH + j0];
            #pragma unroll
            for (int jj = 0; jj < 4; ++jj){
                float wv = Wl2_i[(size_t)(j0+jj)*NH + c];
                #pragma unroll
                for (int p = 0; p < NO; ++p) acc[p] += uv[p][jj]*wv;
            }
        }
        if (q >= 4){
            #pragma unroll
            for (int p = 0; p < NO; ++p) sred[((q-4)*NO + p)*NH + c] = acc[p];
        }
        __syncthreads();
        if (q < 4){
            #pragma unroll
            for (int p = 0; p < NO; ++p) sred[(q*NO + p)*NH + c] += acc[p];
        }
    }
    __syncthreads();
    // final: residual + store or fused readout
    float ro_part = 0.f;
    if (tid < NO*NH/4){
        int p = tid >> 5, c4 = tid & 31;
        f32x4 v = ((const f32x4*)sred)[(0*NO + p)*(NH/4) + c4]
                + ((const f32x4*)sred)[(1*NO + p)*(NH/4) + c4]
                + ((const f32x4*)sred)[(2*NO + p)*(NH/4) + c4]
                + ((const f32x4*)sred)[(3*NO + p)*(NH/4) + c4];
        f32x4 bv = ((const f32x4*)bl2_i)[c4];
        size_t ri4 = ((size_t)b*sB + (size_t)p*sP + (size_t)m*NH)/4 + c4;
        f32x4 hv = ((const f32x4*)hIn)[ri4];
        f32x4 vf = v + bv + hv;
        if (!final){
            size_t gi4 = (((size_t)b*NO + p)*NN + m)*(NH/4) + c4;
            ((f32x4*)hOut)[gi4] = vf;
        } else {
            f32x4 wr = ((const f32x4*)Wro)[c4];
            ro_part = vf.x*wr.x + vf.y*wr.y + vf.z*wr.z + vf.w*wr.w;
        }
    }
    if (final){
        for (int off = 32; off; off >>= 1) ro_part += __shfl_xor(ro_part, off);
        if (lane == 0) swred[wid] = ro_part;
        __syncthreads();
        if (tid == 0){
            float s = 0.f;
            #pragma unroll
            for (int i = 0; i < 16; ++i) s += swred[i];
            float contrib = (s + 12.0f*bro[0]) * mask[b*NN + m] * rmask[b];
            atomicAdd(&outp[b], contrib);
        }
    }
}

// ---------------------------------------------------------------------------
extern "C" void kernel_launch(void* const* d_in, const int* in_sizes, int n_in,
                              void* d_out, int out_size, void* d_ws, size_t ws_size,
                              hipStream_t stream){
    const float* pos  = (const float*)d_in[0];
    const float* x    = (const float*)d_in[1];
    const float* mask = (const float*)d_in[2];
    const float* W1s  = (const float*)d_in[3];
    const float* b1s  = (const float*)d_in[4];
    const float* W2s  = (const float*)d_in[5];
    const float* b2s  = (const float*)d_in[6];
    const float* W1r  = (const float*)d_in[7];
    const float* b1r  = (const float*)d_in[8];
    const float* W2r  = (const float*)d_in[9];
    const float* b2r  = (const float*)d_in[10];
    const float* We   = (const float*)d_in[11];
    const float* Wsp  = (const float*)d_in[12];
    const float* Wrot = (const float*)d_in[13];
    const float* convb= (const float*)d_in[14];
    const float* lns  = (const float*)d_in[15];
    const float* lnb  = (const float*)d_in[16];
    const float* Wl1  = (const float*)d_in[17];
    const float* bl1  = (const float*)d_in[18];
    const float* Wl2  = (const float*)d_in[19];
    const float* bl2  = (const float*)d_in[20];
    const float* Wro  = (const float*)d_in[21];
    const float* bro  = (const float*)d_in[22];

    float* ws = (float*)d_ws;
    float* ws_ori   = ws;                       // 64
    float* ws_rot   = ws + 64;                  // 2*144*128 = 36864
    float* ws_rmask = ws + 64 + 36864;          // 16
    ushort* w1ct = (ushort*)(ws + 36944);       // 4096 ushort (2048 fl)
    ushort* w2ct = (ushort*)(ws + 38992);       // 4096 ushort (2048 fl)
    float* hE    = ws + 41040;                  // 32768
    float* hB    = hE + NB*NN*NH;               // 393216
    float* part  = hB + NB*NO*NN*NH;            // NSPLIT*393216
    ushort* kb   = (ushort*)(part + NSPLIT*NB*NO*NN*NH);

    // k_setup block 0: setup + d_out zero; blocks 1..128: embed
    k_setup<<<1 + NB*NN*NH/256, 256, 0, stream>>>(W1r, b1r, W2r, b2r,
            W1s, b1s, W2s, Wrot, mask, x, We, hE,
            ws_ori, ws_rot, ws_rmask, w1ct, w2ct, (float*)d_out);
    k_kb<<<NB*NO*NN, 256, 0, stream>>>(pos, w1ct, w2ct, b2s, ws_ori, kb);

    // layer 0 (o-broadcast input hE: sP=0)
    k_convg<<<NB*NO*2*NSPLIT, 256, 0, stream>>>(kb, hE, Wsp, mask, part,
            NN*NH, 0);
    k_mlp<<<NB*NN, 1024, 0, stream>>>(part, hE, hB,
            ws_rot, convb, lns, lnb, Wl1, bl1, Wl2, bl2,
            Wro, bro, mask, ws_rmask, (float*)d_out, NN*NH, 0, 0);
    // layer 1 (fused readout)
    k_convg<<<NB*NO*2*NSPLIT, 256, 0, stream>>>(kb, hB, Wsp + NBD*NH, mask, part,
            NO*NN*NH, NN*NH);
    k_mlp<<<NB*NN, 1024, 0, stream>>>(part, hB, hB,
            ws_rot + 144*NH, convb + NH, lns + NH, lnb + NH,
            Wl1 + NH*NHH, bl1 + NHH, Wl2 + NHH*NH, bl2 + NH,
            Wro, bro, mask, ws_rmask, (float*)d_out, NO*NN*NH, NN*NH, 1);
}